// Round 2
// baseline (7394.118 us; speedup 1.0000x reference)
//
#include <hip/hip_runtime.h>
#include <hip/hip_bf16.h>
#include <math.h>

typedef __hip_bfloat16 bf16;

#define LRELU(v) ((v) > 0.f ? (v) : 0.2f*(v))

__device__ __forceinline__ float sig_f(float x){ return 1.f/(1.f + __expf(-x)); }
__device__ __forceinline__ float tanh_f(float x){
  float ax = fabsf(x);
  float e = __expf(-2.f*ax);
  float t = (1.f - e)/(1.f + e);
  return x >= 0.f ? t : -t;
}

__global__ void k_zero(float* __restrict__ p, int n){
  int i = blockIdx.x*256 + threadIdx.x;
  if (i < n) p[i] = 0.f;
}

// ---------------- generic tiled transpose: src[R][C] -> dst[C][R]; R,C mult of 32; block(32,8)
__global__ void k_transpose(const float* __restrict__ src, float* __restrict__ dst, int R, int C){
  __shared__ float t[32][33];
  int c0 = blockIdx.x*32, r0 = blockIdx.y*32;
  int tx = threadIdx.x, ty = threadIdx.y;
  #pragma unroll
  for (int i = 0; i < 4; ++i)
    t[ty+8*i][tx] = src[(size_t)(r0+ty+8*i)*C + c0+tx];
  __syncthreads();
  #pragma unroll
  for (int i = 0; i < 4; ++i)
    dst[(size_t)(c0+ty+8*i)*R + r0+tx] = t[tx][ty+8*i];
}

// ---------------- LSTM weight pack: W4[k][j] = (W[j][k], W[256+j][k], W[512+j][k], W[768+j][k])
__global__ void k_w4prep(const float* __restrict__ Wih, const float* __restrict__ Whh,
                         float4* __restrict__ W4hh, float4* __restrict__ W4s){
  int k = blockIdx.x, j = threadIdx.x;
  float h0 = Whh[j*256+k],       h1 = Whh[(256+j)*256+k];
  float h2 = Whh[(512+j)*256+k], h3 = Whh[(768+j)*256+k];
  float i0 = Wih[j*256+k],       i1 = Wih[(256+j)*256+k];
  float i2 = Wih[(512+j)*256+k], i3 = Wih[(768+j)*256+k];
  W4hh[k*256+j] = make_float4(h0,h1,h2,h3);
  W4s [k*256+j] = make_float4(h0+i0, h1+i1, h2+i2, h3+i3);
}

// ---------------- xg4[j] = x0 @ W_ih^T (+bias), bias4[j] = b_ih+b_hh packed; one block per unit j
__global__ void k_xgbias(const float* __restrict__ Wih, const float* __restrict__ b_ih,
                         const float* __restrict__ b_hh, const float* __restrict__ init_in,
                         float4* __restrict__ xg4, float4* __restrict__ bias4){
  int b = blockIdx.x, t = threadIdx.x;
  float v = init_in[t];
  float p0 = v * Wih[b*256 + t];
  float p1 = v * Wih[(256+b)*256 + t];
  float p2 = v * Wih[(512+b)*256 + t];
  float p3 = v * Wih[(768+b)*256 + t];
  #pragma unroll
  for (int o = 32; o; o >>= 1) {
    p0 += __shfl_xor(p0, o); p1 += __shfl_xor(p1, o);
    p2 += __shfl_xor(p2, o); p3 += __shfl_xor(p3, o);
  }
  __shared__ float4 red[4];
  int lane = t & 63, wid = t >> 6;
  if (lane == 0) red[wid] = make_float4(p0,p1,p2,p3);
  __syncthreads();
  if (t == 0) {
    float4 bi = make_float4(b_ih[b]+b_hh[b], b_ih[256+b]+b_hh[256+b],
                            b_ih[512+b]+b_hh[512+b], b_ih[768+b]+b_hh[768+b]);
    bias4[b] = bi;
    float4 a = bi;
    #pragma unroll
    for (int w = 0; w < 4; ++w) { a.x += red[w].x; a.y += red[w].y; a.z += red[w].z; a.w += red[w].w; }
    xg4[b] = a;
  }
}

// ---------------- h0/c0: z=[zc|zm]; h0 = z@W_h^T+b_h (via transposed W)
__global__ __launch_bounds__(256) void k_h0c0(const float* __restrict__ zc, const float* __restrict__ zm,
                      const float* __restrict__ WhT, const float* __restrict__ WcT,
                      const float* __restrict__ b_h, const float* __restrict__ b_c,
                      float* __restrict__ h, float* __restrict__ c){
  __shared__ float zs[256];
  int b = blockIdx.x, j = threadIdx.x;
  zs[j] = (j < 128) ? zc[b*128 + j] : zm[b*128 + (j-128)];
  __syncthreads();
  float ah = b_h[j], ac = b_c[j];
  #pragma unroll 4
  for (int k = 0; k < 256; ++k) {
    float zv = zs[k];
    ah = fmaf(zv, WhT[k*256 + j], ah);
    ac = fmaf(zv, WcT[k*256 + j], ac);
  }
  h[b*256+j] = ah; c[b*256+j] = ac;
}

// ---------------- one LSTM step (in-place h,c), writes outs[b][t][:]
__global__ __launch_bounds__(256) void k_lstm(const float4* __restrict__ W4, const float4* __restrict__ base4,
                      float* __restrict__ h, float* __restrict__ c,
                      float* __restrict__ outs, int t){
  __shared__ float hs[256];
  int b = blockIdx.x, j = threadIdx.x;
  hs[j] = h[b*256 + j];
  __syncthreads();
  float4 a = base4[j];
  #pragma unroll 8
  for (int k = 0; k < 256; ++k) {
    float4 w = W4[k*256 + j];
    float hv = hs[k];
    a.x = fmaf(hv, w.x, a.x);
    a.y = fmaf(hv, w.y, a.y);
    a.z = fmaf(hv, w.z, a.z);
    a.w = fmaf(hv, w.w, a.w);
  }
  float cv = c[b*256 + j];
  float ig = sig_f(a.x), fg = sig_f(a.y), gg = tanh_f(a.z), og = sig_f(a.w);
  float cn = fmaf(fg, cv, ig*gg);
  float hn = og * tanh_f(cn);
  c[b*256+j] = cn;
  h[b*256+j] = hn;
  outs[(b*20 + t)*256 + j] = hn;
}

// ---------------- ff = lrelu(outs@W_f^T + b_f) into feat[:,0:512]; 4 rows per block
__global__ __launch_bounds__(256) void k_ff(const float* __restrict__ outs, const float* __restrict__ WfT,
                    const float* __restrict__ b_f, float* __restrict__ feat){
  __shared__ float rows[4][256];
  int r0 = blockIdx.x * 4, tid = threadIdx.x;
  #pragma unroll
  for (int i = 0; i < 4; ++i) rows[i][tid] = outs[(r0+i)*256 + tid];
  __syncthreads();
  #pragma unroll
  for (int half = 0; half < 2; ++half) {
    int j = tid + half*256;
    float bb = b_f[j];
    float a0 = bb, a1 = bb, a2 = bb, a3 = bb;
    #pragma unroll 4
    for (int k = 0; k < 256; ++k) {
      float w = WfT[k*512 + j];
      a0 = fmaf(rows[0][k], w, a0);
      a1 = fmaf(rows[1][k], w, a1);
      a2 = fmaf(rows[2][k], w, a2);
      a3 = fmaf(rows[3][k], w, a3);
    }
    feat[(r0+0)*640 + j] = LRELU(a0);
    feat[(r0+1)*640 + j] = LRELU(a1);
    feat[(r0+2)*640 + j] = LRELU(a2);
    feat[(r0+3)*640 + j] = LRELU(a3);
  }
}

// ---------------- feat[:,512:640] = z_content broadcast over T
__global__ void k_zc(const float* __restrict__ zc, float* __restrict__ feat){
  int e = blockIdx.x*256 + threadIdx.x;     // < 1280*128
  int r = e >> 7, c = e & 127;
  feat[r*640 + 512 + c] = zc[(r/20)*128 + c];
}

// ---------------- FC GEMM: C[1280][4096] = lrelu(A[1280][640] @ B[640][4096] + bias), bf16 out
__global__ __launch_bounds__(256) void k_gemm_fc(const float* __restrict__ A, const float* __restrict__ B,
                         const float* __restrict__ bias, bf16* __restrict__ C){
  constexpr int N = 4096, K = 640;
  __shared__ float As[16][68];
  __shared__ float Bs[16][68];
  int tid = threadIdx.x, tx = tid & 15, ty = tid >> 4;
  int col0 = blockIdx.x * 64, row0 = blockIdx.y * 64;
  float4 acc[4];
  #pragma unroll
  for (int i = 0; i < 4; ++i) acc[i] = make_float4(0,0,0,0);
  for (int k0 = 0; k0 < K; k0 += 16) {
    #pragma unroll
    for (int i = 0; i < 4; ++i) {
      int e = i*256 + tid;
      int ak = e & 15, am = e >> 4;
      As[ak][am] = A[(row0+am)*K + k0+ak];
      int bn = e & 63, bk = e >> 6;
      Bs[bk][bn] = B[(size_t)(k0+bk)*N + col0+bn];
    }
    __syncthreads();
    #pragma unroll
    for (int k = 0; k < 16; ++k) {
      float4 a = *(const float4*)&As[k][ty*4];
      float4 b = *(const float4*)&Bs[k][tx*4];
      acc[0].x = fmaf(a.x,b.x,acc[0].x); acc[0].y = fmaf(a.x,b.y,acc[0].y); acc[0].z = fmaf(a.x,b.z,acc[0].z); acc[0].w = fmaf(a.x,b.w,acc[0].w);
      acc[1].x = fmaf(a.y,b.x,acc[1].x); acc[1].y = fmaf(a.y,b.y,acc[1].y); acc[1].z = fmaf(a.y,b.z,acc[1].z); acc[1].w = fmaf(a.y,b.w,acc[1].w);
      acc[2].x = fmaf(a.z,b.x,acc[2].x); acc[2].y = fmaf(a.z,b.y,acc[2].y); acc[2].z = fmaf(a.z,b.z,acc[2].z); acc[2].w = fmaf(a.z,b.w,acc[2].w);
      acc[3].x = fmaf(a.w,b.x,acc[3].x); acc[3].y = fmaf(a.w,b.y,acc[3].y); acc[3].z = fmaf(a.w,b.z,acc[3].z); acc[3].w = fmaf(a.w,b.w,acc[3].w);
    }
    __syncthreads();
  }
  float4 bv = *(const float4*)&bias[col0 + tx*4];
  #pragma unroll
  for (int i = 0; i < 4; ++i) {
    int row = row0 + ty*4 + i;
    union { bf16 b[4]; uint2 u2; } pk;
    pk.b[0] = __float2bfloat16(LRELU(acc[i].x + bv.x));
    pk.b[1] = __float2bfloat16(LRELU(acc[i].y + bv.y));
    pk.b[2] = __float2bfloat16(LRELU(acc[i].z + bv.z));
    pk.b[3] = __float2bfloat16(LRELU(acc[i].w + bv.w));
    *(uint2*)&C[(size_t)row*N + col0 + tx*4] = pk.u2;
  }
}

// ---------------- deconv weight permute: w[ci][co][ky][kx] -> wT2[((cog*16+ky*4+kx)*CI+ci)*4+c], co=cog*4+c
template<int CI, int CO>
__global__ void k_wperm(const float* __restrict__ w, float* __restrict__ wT2){
  int e = blockIdx.x*256 + threadIdx.x;   // < CI*CO*16
  int c = e & 3; int t1 = e >> 2;
  int ci = t1 % CI; int t2 = t1 / CI;
  int tap = t2 & 15; int cog = t2 >> 4;
  int ky = tap >> 2, kx = tap & 3;
  int co = cog*4 + c;
  wT2[e] = w[((ci*CO + co)*4 + ky)*4 + kx];
}

__global__ void k_wfperm(const float* __restrict__ wf, float* __restrict__ wfT){
  int e = blockIdx.x*256 + threadIdx.x;   // < 512
  if (e < 512) {
    int tap = e >> 5, ci = e & 31;
    wfT[tap*32 + ci] = wf[ci*16 + tap];
  }
}

#define FMA4(accv, ivc, wv) \
  accv.x = fmaf((ivc),(wv).x,accv.x); accv.y = fmaf((ivc),(wv).y,accv.y); \
  accv.z = fmaf((ivc),(wv).z,accv.z); accv.w = fmaf((ivc),(wv).w,accv.w)

// ---------------- deconv (s=2,k=4,p=1) gather + batch-stat accumulation
// in [N][CI][HI][HI] bf16 (raw pre-BN unless BN=false), out [N][CO][2HI][2HI] bf16 raw.
template<int CI, int CO, int HI, int SPLIT, bool BN>
__global__ __launch_bounds__(256) void k_deconv(
    const bf16* __restrict__ in, const float* __restrict__ wT2,
    const float* __restrict__ scale, const float* __restrict__ shift,
    bf16* __restrict__ out, float* __restrict__ gsum, float* __restrict__ gsq)
{
  constexpr int WI = HI, HO = 2*HI, WO = HO;
  constexpr int HOq = HO / SPLIT;
  constexpr int SP = HOq * WO;
  constexpr int CIP = CI + 4;
  constexpr int SP_LANES = (SP < 256) ? SP : 256;
  constexpr int CQ = 256 / SP_LANES;
  constexpr int NCO_T = CO / CQ;
  constexpr int NCH = NCO_T / 4;          // float4 chunks per thread (8 everywhere)
  constexpr int SP_ITER = SP / SP_LANES;
  constexpr int RMAX = (HOq/2 + 2 < HI) ? (HOq/2 + 2) : HI;

  __shared__ float in_s[RMAX * WI * CIP];
  __shared__ float s_sum[CO];
  __shared__ float s_sq[CO];

  const int tid = threadIdx.x;
  const int bid = blockIdx.x;
  const int n = bid / SPLIT, q = bid % SPLIT;
  const int y0 = q * HOq;
  const int rows_lo = max(0, y0/2 - 1);
  const int rows_hi = min(HI-1, (y0 + HOq)/2);
  const int nrows = rows_hi - rows_lo + 1;

  if (tid < CO) { s_sum[tid] = 0.f; s_sq[tid] = 0.f; }

  const bf16* inb = in + (size_t)n * CI * HI * WI;
  const int NE = nrows * WI * CI;
  for (int e = tid; e < NE; e += 256) {
    int ci = e / (nrows * WI);
    int rr = e - ci * (nrows * WI);
    int rl = rr / WI;
    int ix = rr - rl * WI;
    float v = __bfloat162float(inb[(ci * HI + rows_lo + rl) * WI + ix]);
    if (BN) {
      v = fmaf(v, scale[ci], shift[ci]);
      v = LRELU(v);
    }
    in_s[(rl * WI + ix) * CIP + ci] = v;
  }
  __syncthreads();

  const int sp_l = tid % SP_LANES;
  const int cq = tid / SP_LANES;

  for (int si = 0; si < SP_ITER; ++si) {
    int sp = sp_l + si * SP_LANES;
    int y = y0 + sp / WO, x = sp % WO;
    int kya = (y + 1) & 1, iya = (y + 1) >> 1;
    int kxa = (x + 1) & 1, ixa = (x + 1) >> 1;

    float4 acc[NCH];
    #pragma unroll
    for (int ch = 0; ch < NCH; ++ch) acc[ch] = make_float4(0,0,0,0);

    #pragma unroll
    for (int dy = 0; dy < 2; ++dy) {
      int iy = iya - dy, ky = kya + 2*dy;
      if (iy < 0 || iy >= HI) continue;
      #pragma unroll
      for (int dx = 0; dx < 2; ++dx) {
        int ix = ixa - dx, kx = kxa + 2*dx;
        if (ix < 0 || ix >= WI) continue;
        const float* __restrict__ wp = wT2 + (size_t)((cq*NCH)*16 + ky*4 + kx) * CI * 4;
        const float* __restrict__ ib = &in_s[((iy - rows_lo) * WI + ix) * CIP];
        for (int ci = 0; ci < CI; ci += 4) {
          float4 iv = *(const float4*)&ib[ci];
          #pragma unroll
          for (int ch = 0; ch < NCH; ++ch) {
            const float* wc = wp + (size_t)ch * (16*CI*4) + ci*4;
            float4 w0 = *(const float4*)&wc[0];
            float4 w1 = *(const float4*)&wc[4];
            float4 w2 = *(const float4*)&wc[8];
            float4 w3 = *(const float4*)&wc[12];
            FMA4(acc[ch], iv.x, w0);
            FMA4(acc[ch], iv.y, w1);
            FMA4(acc[ch], iv.z, w2);
            FMA4(acc[ch], iv.w, w3);
          }
        }
      }
    }

    #pragma unroll
    for (int ch = 0; ch < NCH; ++ch) {
      int co0 = (cq*NCH + ch) * 4;
      float vals[4] = {acc[ch].x, acc[ch].y, acc[ch].z, acc[ch].w};
      #pragma unroll
      for (int cc = 0; cc < 4; ++cc) {
        out[((size_t)(n*CO + co0 + cc)*HO + y)*WO + x] = __float2bfloat16(vals[cc]);
        float s = vals[cc], s2 = vals[cc]*vals[cc];
        #pragma unroll
        for (int o = 32; o; o >>= 1) { s += __shfl_xor(s, o); s2 += __shfl_xor(s2, o); }
        if ((tid & 63) == 0) { atomicAdd(&s_sum[co0+cc], s); atomicAdd(&s_sq[co0+cc], s2); }
      }
    }
  }
  __syncthreads();
  for (int cc = tid; cc < CO; cc += 256) {
    atomicAdd(&gsum[cc], s_sum[cc]);
    atomicAdd(&gsq[cc], s_sq[cc]);
  }
}

// ---------------- BN finalize
__global__ void k_bnfin(const float* __restrict__ sum, const float* __restrict__ sq,
                        const float* __restrict__ g, const float* __restrict__ be,
                        float* __restrict__ scale, float* __restrict__ shift,
                        int CO, float invN){
  int c = threadIdx.x;
  if (c >= CO) return;
  float m = sum[c]*invN;
  float v = sq[c]*invN - m*m;
  float sc = g[c]*rsqrtf(v + 1e-5f);
  scale[c] = sc;
  shift[c] = be[c] - m*sc;
}

// ---------------- final deconv 32->1 + sigmoid
__global__ __launch_bounds__(256) void k_final(
    const bf16* __restrict__ in, const float* __restrict__ wfT,
    const float* __restrict__ scale, const float* __restrict__ shift,
    const float* __restrict__ bf, float* __restrict__ outp)
{
  constexpr int CI=32, HI=32, WI=32, HO=64, WO=64, SPLIT=4, HOq=HO/SPLIT, SP=HOq*WO;
  constexpr int CIP = CI+4;
  constexpr int RMAX = HOq/2 + 2;   // 10
  __shared__ float in_s[RMAX * WI * CIP];

  const int tid = threadIdx.x;
  const int bid = blockIdx.x;
  const int n = bid / SPLIT, q = bid % SPLIT;
  const int y0 = q * HOq;
  const int rows_lo = max(0, y0/2 - 1);
  const int rows_hi = min(HI-1, (y0 + HOq)/2);
  const int nrows = rows_hi - rows_lo + 1;

  const bf16* inb = in + (size_t)n * CI * HI * WI;
  const int NE = nrows * WI * CI;
  for (int e = tid; e < NE; e += 256) {
    int ci = e / (nrows * WI);
    int rr = e - ci * (nrows * WI);
    int rl = rr / WI;
    int ix = rr - rl * WI;
    float v = __bfloat162float(inb[(ci * HI + rows_lo + rl) * WI + ix]);
    v = fmaf(v, scale[ci], shift[ci]);
    v = LRELU(v);
    in_s[(rl * WI + ix) * CIP + ci] = v;
  }
  __syncthreads();

  float b0 = bf[0];
  for (int sp = tid; sp < SP; sp += 256) {
    int y = y0 + sp / WO, x = sp % WO;
    int kya = (y + 1) & 1, iya = (y + 1) >> 1;
    int kxa = (x + 1) & 1, ixa = (x + 1) >> 1;
    float acc = 0.f;
    #pragma unroll
    for (int dy = 0; dy < 2; ++dy) {
      int iy = iya - dy, ky = kya + 2*dy;
      if (iy < 0 || iy >= HI) continue;
      #pragma unroll
      for (int dx = 0; dx < 2; ++dx) {
        int ix = ixa - dx, kx = kxa + 2*dx;
        if (ix < 0 || ix >= WI) continue;
        const float* __restrict__ wp = wfT + (ky*4 + kx)*CI;
        const float* __restrict__ ib = &in_s[((iy - rows_lo)*WI + ix)*CIP];
        #pragma unroll
        for (int ci = 0; ci < CI; ci += 4) {
          float4 iv = *(const float4*)&ib[ci];
          float4 w  = *(const float4*)&wp[ci];
          acc = fmaf(iv.x, w.x, acc);
          acc = fmaf(iv.y, w.y, acc);
          acc = fmaf(iv.z, w.z, acc);
          acc = fmaf(iv.w, w.w, acc);
        }
      }
    }
    float v = acc + b0;
    outp[(size_t)n*HO*WO + y*WO + x] = 1.f/(1.f + __expf(-v));
  }
}

extern "C" void kernel_launch(void* const* d_in, const int* in_sizes, int n_in,
                              void* d_out, int out_size, void* d_ws, size_t ws_size,
                              hipStream_t stream) {
  const float* z_content = (const float*)d_in[0];
  const float* z_motion  = (const float*)d_in[1];
  const float* W_h  = (const float*)d_in[2];
  const float* b_h  = (const float*)d_in[3];
  const float* W_c  = (const float*)d_in[4];
  const float* b_c  = (const float*)d_in[5];
  const float* W_ih = (const float*)d_in[6];
  const float* W_hh = (const float*)d_in[7];
  const float* b_ih = (const float*)d_in[8];
  const float* b_hh = (const float*)d_in[9];
  const float* W_f  = (const float*)d_in[10];
  const float* b_f  = (const float*)d_in[11];
  const float* init_in = (const float*)d_in[12];
  const float* fc_W = (const float*)d_in[13];
  const float* fc_b = (const float*)d_in[14];
  const float* w0 = (const float*)d_in[15];
  const float* g0 = (const float*)d_in[16];
  const float* be0 = (const float*)d_in[17];
  const float* w1 = (const float*)d_in[18];
  const float* g1 = (const float*)d_in[19];
  const float* be1 = (const float*)d_in[20];
  const float* w2 = (const float*)d_in[21];
  const float* g2 = (const float*)d_in[22];
  const float* be2 = (const float*)d_in[23];
  const float* wf = (const float*)d_in[24];
  const float* bf = (const float*)d_in[25];

  // ---- workspace layout
  // Persistent f32 region P: 2,657,792 floats = 10,631,168 bytes
  // Region X (10,631,168 + 83,886,080 B): fcWT(f32,10.5MB) -> out0(bf16,21MB) -> out2(bf16,84MB)
  // Region Y (41,943,040 B):              h1(bf16,10.5MB)  -> out1(bf16,42MB)
  const size_t P_BYTES = 10631168;
  const size_t X_OFF   = P_BYTES;
  const size_t X_BYTES = 83886080;
  const size_t Y_OFF   = X_OFF + X_BYTES;
  const size_t NEED    = Y_OFF + 41943040;   // 136,460,288 bytes total
  if (ws_size < NEED) return;  // graceful failure signal (absmax fail, not abort)

  float* ws = (float*)d_ws;
  char*  wsb = (char*)d_ws;
  float* sum0 = ws + 0;        float* sq0 = ws + 128;
  float* sum1 = ws + 256;      float* sq1 = ws + 320;
  float* sum2 = ws + 384;      float* sq2 = ws + 416;   // stats end at 448
  float* scale0 = ws + 512;    float* shift0 = ws + 640;
  float* scale1 = ws + 768;    float* shift1 = ws + 832;
  float* scale2 = ws + 896;    float* shift2 = ws + 928;
  float4* xg4   = (float4*)(ws + 1024);
  float4* bias4 = (float4*)(ws + 2048);
  float* h    = ws + 3072;       // 16384
  float* c    = ws + 19456;      // 16384
  float* outs = ws + 35840;      // 327680
  float* WhT  = ws + 363520;     // 65536
  float* WcT  = ws + 429056;     // 65536
  float* WfT  = ws + 494592;     // 131072
  float4* W4hh = (float4*)(ws + 625664);   // 262144 floats
  float4* W4s  = (float4*)(ws + 887808);   // 262144 floats
  float* w0T2 = ws + 1149952;    // 524288
  float* w1T2 = ws + 1674240;    // 131072
  float* w2T2 = ws + 1805312;    // 32768
  float* wfT  = ws + 1838080;    // 512
  float* feat = ws + 1838592;    // 819200 -> ends at 2,657,792 floats

  float* fcWT = (float*)(wsb + X_OFF);   // 2,621,440 f32 (dead after gemm)
  bf16*  out0 = (bf16*) (wsb + X_OFF);   // 10,485,760 bf16 (dead after deconv1)
  bf16*  out2 = (bf16*) (wsb + X_OFF);   // 41,943,040 bf16
  bf16*  h1   = (bf16*) (wsb + Y_OFF);   //  5,242,880 bf16 (dead after deconv0)
  bf16*  out1 = (bf16*) (wsb + Y_OFF);   // 20,971,520 bf16

  // zero BN stat accumulators (deterministic per call)
  k_zero<<<2, 256, 0, stream>>>(ws, 448);

  // ---- prep: transposes / packs (recomputed every call; cheap)
  dim3 tb(32,8);
  k_transpose<<<dim3(8,8),   tb, 0, stream>>>(W_h,  WhT, 256, 256);
  k_transpose<<<dim3(8,8),   tb, 0, stream>>>(W_c,  WcT, 256, 256);
  k_transpose<<<dim3(8,16),  tb, 0, stream>>>(W_f,  WfT, 512, 256);
  k_transpose<<<dim3(20,128),tb, 0, stream>>>(fc_W, fcWT, 4096, 640);
  k_w4prep<<<256, 256, 0, stream>>>(W_ih, W_hh, W4hh, W4s);
  k_xgbias<<<256, 256, 0, stream>>>(W_ih, b_ih, b_hh, init_in, xg4, bias4);
  k_h0c0<<<64, 256, 0, stream>>>(z_content, z_motion, WhT, WcT, b_h, b_c, h, c);
  k_wperm<256,128><<<2048, 256, 0, stream>>>(w0, w0T2);
  k_wperm<128,64><<<512, 256, 0, stream>>>(w1, w1T2);
  k_wperm<64,32><<<128, 256, 0, stream>>>(w2, w2T2);
  k_wfperm<<<2, 256, 0, stream>>>(wf, wfT);

  // ---- LSTM (autoregressive: x==h after step 0, so steps>=1 use W_ih+W_hh)
  k_lstm<<<64, 256, 0, stream>>>(W4hh, xg4, h, c, outs, 0);
  for (int t = 1; t < 20; ++t)
    k_lstm<<<64, 256, 0, stream>>>(W4s, bias4, h, c, outs, t);

  // ---- ff + concat + fc
  k_ff<<<320, 256, 0, stream>>>(outs, WfT, b_f, feat);
  k_zc<<<640, 256, 0, stream>>>(z_content, feat);
  k_gemm_fc<<<dim3(64,20), 256, 0, stream>>>(feat, fcWT, fc_b, h1);

  // ---- deconv pipeline (BN applied on load of the following stage)
  k_deconv<256,128,4,1,false><<<1280, 256, 0, stream>>>(h1, w0T2, nullptr, nullptr, out0, sum0, sq0);
  k_bnfin<<<1, 128, 0, stream>>>(sum0, sq0, g0, be0, scale0, shift0, 128, 1.f/81920.f);
  k_deconv<128,64,8,2,true><<<2560, 256, 0, stream>>>(out0, w1T2, scale0, shift0, out1, sum1, sq1);
  k_bnfin<<<1, 64, 0, stream>>>(sum1, sq1, g1, be1, scale1, shift1, 64, 1.f/327680.f);
  k_deconv<64,32,16,2,true><<<2560, 256, 0, stream>>>(out1, w2T2, scale1, shift1, out2, sum2, sq2);
  k_bnfin<<<1, 32, 0, stream>>>(sum2, sq2, g2, be2, scale2, shift2, 32, 1.f/1310720.f);
  k_final<<<5120, 256, 0, stream>>>(out2, wfT, scale2, shift2, bf, (float*)d_out);
}

// Round 3
// 998.955 us; speedup vs baseline: 7.4019x; 7.4019x over previous
//
#include <hip/hip_runtime.h>
#include <hip/hip_bf16.h>
#include <math.h>

typedef __hip_bfloat16 bf16;
typedef __attribute__((ext_vector_type(8))) short bf16x8;
typedef __attribute__((ext_vector_type(4))) float f32x4;

#define LRELU(v) ((v) > 0.f ? (v) : 0.2f*(v))

__device__ __forceinline__ float sig_f(float x){ return 1.f/(1.f + __expf(-x)); }
__device__ __forceinline__ float tanh_f(float x){
  float ax = fabsf(x);
  float e = __expf(-2.f*ax);
  float t = (1.f - e)/(1.f + e);
  return x >= 0.f ? t : -t;
}
__device__ __forceinline__ ushort bfbits(float v){
  bf16 b = __float2bfloat16(v);
  return *(ushort*)&b;
}
__device__ __forceinline__ float bflo(uint u){ return __uint_as_float(u << 16); }
__device__ __forceinline__ float bfhi(uint u){ return __uint_as_float(u & 0xffff0000u); }

__global__ void k_zero(float* __restrict__ p, int n){
  int i = blockIdx.x*256 + threadIdx.x;
  if (i < n) p[i] = 0.f;
}

// ---------------- generic tiled transpose: src[R][C] -> dst[C][R]; R,C mult of 32; block(32,8)
__global__ void k_transpose(const float* __restrict__ src, float* __restrict__ dst, int R, int C){
  __shared__ float t[32][33];
  int c0 = blockIdx.x*32, r0 = blockIdx.y*32;
  int tx = threadIdx.x, ty = threadIdx.y;
  #pragma unroll
  for (int i = 0; i < 4; ++i)
    t[ty+8*i][tx] = src[(size_t)(r0+ty+8*i)*C + c0+tx];
  __syncthreads();
  #pragma unroll
  for (int i = 0; i < 4; ++i)
    dst[(size_t)(c0+ty+8*i)*R + r0+tx] = t[tx][ty+8*i];
}

// ---------------- LSTM weight pack
__global__ void k_w4prep(const float* __restrict__ Wih, const float* __restrict__ Whh,
                         float4* __restrict__ W4hh, float4* __restrict__ W4s){
  int k = blockIdx.x, j = threadIdx.x;
  float h0 = Whh[j*256+k],       h1 = Whh[(256+j)*256+k];
  float h2 = Whh[(512+j)*256+k], h3 = Whh[(768+j)*256+k];
  float i0 = Wih[j*256+k],       i1 = Wih[(256+j)*256+k];
  float i2 = Wih[(512+j)*256+k], i3 = Wih[(768+j)*256+k];
  W4hh[k*256+j] = make_float4(h0,h1,h2,h3);
  W4s [k*256+j] = make_float4(h0+i0, h1+i1, h2+i2, h3+i3);
}

__global__ void k_xgbias(const float* __restrict__ Wih, const float* __restrict__ b_ih,
                         const float* __restrict__ b_hh, const float* __restrict__ init_in,
                         float4* __restrict__ xg4, float4* __restrict__ bias4){
  int b = blockIdx.x, t = threadIdx.x;
  float v = init_in[t];
  float p0 = v * Wih[b*256 + t];
  float p1 = v * Wih[(256+b)*256 + t];
  float p2 = v * Wih[(512+b)*256 + t];
  float p3 = v * Wih[(768+b)*256 + t];
  #pragma unroll
  for (int o = 32; o; o >>= 1) {
    p0 += __shfl_xor(p0, o); p1 += __shfl_xor(p1, o);
    p2 += __shfl_xor(p2, o); p3 += __shfl_xor(p3, o);
  }
  __shared__ float4 red[4];
  int lane = t & 63, wid = t >> 6;
  if (lane == 0) red[wid] = make_float4(p0,p1,p2,p3);
  __syncthreads();
  if (t == 0) {
    float4 bi = make_float4(b_ih[b]+b_hh[b], b_ih[256+b]+b_hh[256+b],
                            b_ih[512+b]+b_hh[512+b], b_ih[768+b]+b_hh[768+b]);
    bias4[b] = bi;
    float4 a = bi;
    #pragma unroll
    for (int w = 0; w < 4; ++w) { a.x += red[w].x; a.y += red[w].y; a.z += red[w].z; a.w += red[w].w; }
    xg4[b] = a;
  }
}

__global__ __launch_bounds__(256) void k_h0c0(const float* __restrict__ zc, const float* __restrict__ zm,
                      const float* __restrict__ WhT, const float* __restrict__ WcT,
                      const float* __restrict__ b_h, const float* __restrict__ b_c,
                      float* __restrict__ h, float* __restrict__ c){
  __shared__ float zs[256];
  int b = blockIdx.x, j = threadIdx.x;
  zs[j] = (j < 128) ? zc[b*128 + j] : zm[b*128 + (j-128)];
  __syncthreads();
  float ah = b_h[j], ac = b_c[j];
  #pragma unroll 4
  for (int k = 0; k < 256; ++k) {
    float zv = zs[k];
    ah = fmaf(zv, WhT[k*256 + j], ah);
    ac = fmaf(zv, WcT[k*256 + j], ac);
  }
  h[b*256+j] = ah; c[b*256+j] = ac;
}

__global__ __launch_bounds__(256) void k_lstm(const float4* __restrict__ W4, const float4* __restrict__ base4,
                      float* __restrict__ h, float* __restrict__ c,
                      float* __restrict__ outs, int t){
  __shared__ float hs[256];
  int b = blockIdx.x, j = threadIdx.x;
  hs[j] = h[b*256 + j];
  __syncthreads();
  float4 a = base4[j];
  #pragma unroll 8
  for (int k = 0; k < 256; ++k) {
    float4 w = W4[k*256 + j];
    float hv = hs[k];
    a.x = fmaf(hv, w.x, a.x);
    a.y = fmaf(hv, w.y, a.y);
    a.z = fmaf(hv, w.z, a.z);
    a.w = fmaf(hv, w.w, a.w);
  }
  float cv = c[b*256 + j];
  float ig = sig_f(a.x), fg = sig_f(a.y), gg = tanh_f(a.z), og = sig_f(a.w);
  float cn = fmaf(fg, cv, ig*gg);
  float hn = og * tanh_f(cn);
  c[b*256+j] = cn;
  h[b*256+j] = hn;
  outs[(b*20 + t)*256 + j] = hn;
}

__global__ __launch_bounds__(256) void k_ff(const float* __restrict__ outs, const float* __restrict__ WfT,
                    const float* __restrict__ b_f, float* __restrict__ feat){
  __shared__ float rows[4][256];
  int r0 = blockIdx.x * 4, tid = threadIdx.x;
  #pragma unroll
  for (int i = 0; i < 4; ++i) rows[i][tid] = outs[(r0+i)*256 + tid];
  __syncthreads();
  #pragma unroll
  for (int half = 0; half < 2; ++half) {
    int j = tid + half*256;
    float bb = b_f[j];
    float a0 = bb, a1 = bb, a2 = bb, a3 = bb;
    #pragma unroll 4
    for (int k = 0; k < 256; ++k) {
      float w = WfT[k*512 + j];
      a0 = fmaf(rows[0][k], w, a0);
      a1 = fmaf(rows[1][k], w, a1);
      a2 = fmaf(rows[2][k], w, a2);
      a3 = fmaf(rows[3][k], w, a3);
    }
    feat[(r0+0)*640 + j] = LRELU(a0);
    feat[(r0+1)*640 + j] = LRELU(a1);
    feat[(r0+2)*640 + j] = LRELU(a2);
    feat[(r0+3)*640 + j] = LRELU(a3);
  }
}

__global__ void k_zc(const float* __restrict__ zc, float* __restrict__ feat){
  int e = blockIdx.x*256 + threadIdx.x;
  int r = e >> 7, c = e & 127;
  feat[r*640 + 512 + c] = zc[(r/20)*128 + c];
}

// ---------------- FC GEMM: lrelu(A[1280][640]@B[640][4096]+bias) -> h1 NHWC bf16 [r][y][x][co]
__global__ __launch_bounds__(256) void k_gemm_fc(const float* __restrict__ A, const float* __restrict__ B,
                         const float* __restrict__ bias, ushort* __restrict__ C){
  constexpr int N = 4096, K = 640;
  __shared__ float As[16][68];
  __shared__ float Bs[16][68];
  int tid = threadIdx.x, tx = tid & 15, ty = tid >> 4;
  int col0 = blockIdx.x * 64, row0 = blockIdx.y * 64;
  float4 acc[4];
  #pragma unroll
  for (int i = 0; i < 4; ++i) acc[i] = make_float4(0,0,0,0);
  for (int k0 = 0; k0 < K; k0 += 16) {
    #pragma unroll
    for (int i = 0; i < 4; ++i) {
      int e = i*256 + tid;
      int ak = e & 15, am = e >> 4;
      As[ak][am] = A[(row0+am)*K + k0+ak];
      int bn = e & 63, bk = e >> 6;
      Bs[bk][bn] = B[(size_t)(k0+bk)*N + col0+bn];
    }
    __syncthreads();
    #pragma unroll
    for (int k = 0; k < 16; ++k) {
      float4 a = *(const float4*)&As[k][ty*4];
      float4 b = *(const float4*)&Bs[k][tx*4];
      acc[0].x = fmaf(a.x,b.x,acc[0].x); acc[0].y = fmaf(a.x,b.y,acc[0].y); acc[0].z = fmaf(a.x,b.z,acc[0].z); acc[0].w = fmaf(a.x,b.w,acc[0].w);
      acc[1].x = fmaf(a.y,b.x,acc[1].x); acc[1].y = fmaf(a.y,b.y,acc[1].y); acc[1].z = fmaf(a.y,b.z,acc[1].z); acc[1].w = fmaf(a.y,b.w,acc[1].w);
      acc[2].x = fmaf(a.z,b.x,acc[2].x); acc[2].y = fmaf(a.z,b.y,acc[2].y); acc[2].z = fmaf(a.z,b.z,acc[2].z); acc[2].w = fmaf(a.z,b.w,acc[2].w);
      acc[3].x = fmaf(a.w,b.x,acc[3].x); acc[3].y = fmaf(a.w,b.y,acc[3].y); acc[3].z = fmaf(a.w,b.z,acc[3].z); acc[3].w = fmaf(a.w,b.w,acc[3].w);
    }
    __syncthreads();
  }
  float4 bv = *(const float4*)&bias[col0 + tx*4];
  #pragma unroll
  for (int i = 0; i < 4; ++i) {
    int row = row0 + ty*4 + i;
    float vv[4] = {acc[i].x + bv.x, acc[i].y + bv.y, acc[i].z + bv.z, acc[i].w + bv.w};
    #pragma unroll
    for (int jj = 0; jj < 4; ++jj) {
      int j = col0 + tx*4 + jj;      // j = co*16 + s  ->  NHWC idx = (row*16 + s)*256 + co
      C[((size_t)row << 12) + ((size_t)(j & 15) << 8) + (j >> 4)] = bfbits(LRELU(vv[jj]));
    }
  }
}

// ---------------- deconv weight prep: w[ci][co][ky][kx] f32 -> wp[p][co][t*CI+ci] bf16
template<int CI, int CO>
__global__ void k_wprep(const float* __restrict__ w, ushort* __restrict__ wp){
  int e = blockIdx.x*256 + threadIdx.x;     // total 16*CI*CO
  if (e >= 16*CI*CO) return;
  int ci = e % CI; int t1 = e / CI;
  int t = t1 & 3;  int t2 = t1 >> 2;
  int co = t2 % CO; int pp = t2 / CO;
  int py = pp >> 1, px = pp & 1, dy = t >> 1, dx = t & 1;
  int ky = (py ? 0 : 1) + 2*dy;
  int kx = (px ? 0 : 1) + 2*dx;
  wp[e] = bfbits(w[((ci*CO + co)*4 + ky)*4 + kx]);
}

__global__ void k_wfperm(const float* __restrict__ wf, float* __restrict__ wfT){
  int e = blockIdx.x*256 + threadIdx.x;
  if (e < 512) {
    int tap = e >> 5, ci = e & 31;
    wfT[tap*32 + ci] = wf[ci*16 + tap];
  }
}

// ---------------- in-place BN+LReLU on NHWC bf16 activations
__global__ __launch_bounds__(256) void k_bnact(ushort* __restrict__ io,
                        const float* __restrict__ scale, const float* __restrict__ shift,
                        int total8, int comask){
  int i = blockIdx.x*256 + threadIdx.x;
  if (i >= total8) return;
  uint4 u = *(uint4*)&io[(size_t)i*8];
  int co0 = (i*8) & comask;
  float4 sc0 = *(const float4*)&scale[co0];
  float4 sc1 = *(const float4*)&scale[co0+4];
  float4 sh0 = *(const float4*)&shift[co0];
  float4 sh1 = *(const float4*)&shift[co0+4];
  float v0 = LRELU(fmaf(bflo(u.x), sc0.x, sh0.x));
  float v1 = LRELU(fmaf(bfhi(u.x), sc0.y, sh0.y));
  float v2 = LRELU(fmaf(bflo(u.y), sc0.z, sh0.z));
  float v3 = LRELU(fmaf(bfhi(u.y), sc0.w, sh0.w));
  float v4 = LRELU(fmaf(bflo(u.z), sc1.x, sh1.x));
  float v5 = LRELU(fmaf(bfhi(u.z), sc1.y, sh1.y));
  float v6 = LRELU(fmaf(bflo(u.w), sc1.z, sh1.z));
  float v7 = LRELU(fmaf(bfhi(u.w), sc1.w, sh1.w));
  uint4 o;
  o.x = (uint)bfbits(v0) | ((uint)bfbits(v1) << 16);
  o.y = (uint)bfbits(v2) | ((uint)bfbits(v3) << 16);
  o.z = (uint)bfbits(v4) | ((uint)bfbits(v5) << 16);
  o.w = (uint)bfbits(v6) | ((uint)bfbits(v7) << 16);
  *(uint4*)&io[(size_t)i*8] = o;
}

// ---------------- MFMA parity-GEMM deconv
// in: NHWC bf16 [1280][HI][WI][CI] (already activated), wp: [4][CO][4*CI] bf16
// out: NHWC bf16 [1280][2HI][2WI][CO] raw; gsum/gsq: per-co batch stats (f32)
template<int CI, int CO, int HI>
__global__ __launch_bounds__(256) void k_dcv(
    const ushort* __restrict__ in, const ushort* __restrict__ wp,
    ushort* __restrict__ out, float* __restrict__ gsum, float* __restrict__ gsq)
{
  constexpr int WI = HI, HO = 2*HI, WO = 2*WI;
  constexpr int K = 4*CI, BK = 64, NK = K/BK;
  constexpr int BSP = 128;
  constexpr int RS = 72;               // LDS row stride (bf16 elems), 144B
  constexpr int NCF = CO/16;           // co-frags
  constexpr int AC = BSP/32;           // A 16B-chunks per thread (4)
  constexpr int WC = CO/32;            // W 16B-chunks per thread

  __shared__ __align__(16) ushort Al[2][BSP*RS];
  __shared__ __align__(16) ushort Wl[2][CO*RS];
  __shared__ float s_sum[CO], s_sq[CO];

  const int tid = threadIdx.x;
  const int sp0 = blockIdx.x * BSP;
  const int p  = blockIdx.y;
  const int py = p >> 1, px = p & 1;
  const int w  = tid >> 6, l = tid & 63;
  const int lm = l & 15, lk = l >> 4;

  if (tid < CO) { s_sum[tid] = 0.f; s_sq[tid] = 0.f; }

  f32x4 acc[NCF][2];
  #pragma unroll
  for (int m = 0; m < NCF; ++m)
    #pragma unroll
    for (int s = 0; s < 2; ++s)
      acc[m][s] = (f32x4){0.f,0.f,0.f,0.f};

  uint4 ar[AC], wr[WC];

  #define LOADT(kt) { \
    int t = ((kt)*BK)/CI, ci0 = ((kt)*BK)%CI; \
    int dy = t >> 1, dx = t & 1; \
    _Pragma("unroll") \
    for (int i = 0; i < AC; ++i) { \
      int chunk = tid + i*256; \
      int rl = chunk >> 3, kc = chunk & 7; \
      int r = sp0 + rl; \
      int n = r / (HI*WI), rem = r % (HI*WI); \
      int oy = rem / WI, ox = rem % WI; \
      int iy = oy + py - dy, ix = ox + px - dx; \
      if ((unsigned)iy < (unsigned)HI && (unsigned)ix < (unsigned)WI) \
        ar[i] = *(const uint4*)&in[((((size_t)n*HI + iy)*WI + ix)*CI) + ci0 + kc*8]; \
      else ar[i] = make_uint4(0,0,0,0); \
    } \
    _Pragma("unroll") \
    for (int i = 0; i < WC; ++i) { \
      int chunk = tid + i*256; \
      int co = chunk >> 3, kc = chunk & 7; \
      wr[i] = *(const uint4*)&wp[((size_t)p*CO + co)*K + (kt)*BK + kc*8]; \
    } }

  #define STORET(buf) { \
    _Pragma("unroll") \
    for (int i = 0; i < AC; ++i) { \
      int chunk = tid + i*256; \
      int rl = chunk >> 3, kc = chunk & 7; \
      *(uint4*)&Al[buf][rl*RS + kc*8] = ar[i]; \
    } \
    _Pragma("unroll") \
    for (int i = 0; i < WC; ++i) { \
      int chunk = tid + i*256; \
      int co = chunk >> 3, kc = chunk & 7; \
      *(uint4*)&Wl[buf][co*RS + kc*8] = wr[i]; \
    } }

  LOADT(0);
  STORET(0);
  int cur = 0;
  for (int kt = 0; kt < NK; ++kt) {
    if (kt + 1 < NK) LOADT(kt + 1);
    __syncthreads();
    #pragma unroll
    for (int kf = 0; kf < 2; ++kf) {
      bf16x8 bfr[2];
      #pragma unroll
      for (int s = 0; s < 2; ++s)
        bfr[s] = *(bf16x8*)&Al[cur][(w*32 + s*16 + lm)*RS + kf*32 + lk*8];
      #pragma unroll
      for (int m = 0; m < NCF; ++m) {
        bf16x8 afr = *(bf16x8*)&Wl[cur][(m*16 + lm)*RS + kf*32 + lk*8];
        acc[m][0] = __builtin_amdgcn_mfma_f32_16x16x32_bf16(afr, bfr[0], acc[m][0], 0, 0, 0);
        acc[m][1] = __builtin_amdgcn_mfma_f32_16x16x32_bf16(afr, bfr[1], acc[m][1], 0, 0, 0);
      }
    }
    if (kt + 1 < NK) STORET(cur ^ 1);
    cur ^= 1;
  }

  // epilogue: write out (NHWC bf16) + per-co stats
  #pragma unroll
  for (int m = 0; m < NCF; ++m) {
    float s1[4] = {0,0,0,0}, s2[4] = {0,0,0,0};
    #pragma unroll
    for (int s = 0; s < 2; ++s) {
      f32x4 v = acc[m][s];
      int sp = sp0 + w*32 + s*16 + lm;
      int n = sp / (HI*WI), rem = sp % (HI*WI);
      int y = 2*(rem / WI) + py, x = 2*(rem % WI) + px;
      size_t ob = (((size_t)n*HO + y)*WO + x)*CO + m*16 + lk*4;
      union { ushort u[4]; uint2 q; } pk;
      #pragma unroll
      for (int j = 0; j < 4; ++j) {
        pk.u[j] = bfbits(v[j]);
        s1[j] += v[j];
        s2[j] += v[j]*v[j];
      }
      *(uint2*)&out[ob] = pk.q;
    }
    #pragma unroll
    for (int j = 0; j < 4; ++j) {
      float a = s1[j], b = s2[j];
      #pragma unroll
      for (int o = 1; o < 16; o <<= 1) { a += __shfl_xor(a, o); b += __shfl_xor(b, o); }
      if (lm == 0) {
        atomicAdd(&s_sum[m*16 + lk*4 + j], a);
        atomicAdd(&s_sq [m*16 + lk*4 + j], b);
      }
    }
  }
  __syncthreads();
  for (int cc = tid; cc < CO; cc += 256) {
    atomicAdd(&gsum[cc], s_sum[cc]);
    atomicAdd(&gsq[cc],  s_sq[cc]);
  }
  #undef LOADT
  #undef STORET
}

// ---------------- BN finalize
__global__ void k_bnfin(const float* __restrict__ sum, const float* __restrict__ sq,
                        const float* __restrict__ g, const float* __restrict__ be,
                        float* __restrict__ scale, float* __restrict__ shift,
                        int CO, float invN){
  int c = threadIdx.x;
  if (c >= CO) return;
  float m = sum[c]*invN;
  float v = sq[c]*invN - m*m;
  float sc = g[c]*rsqrtf(v + 1e-5f);
  scale[c] = sc;
  shift[c] = be[c] - m*sc;
}

// ---------------- final deconv 32->1 + sigmoid (input NHWC bf16 raw, BN fused on load)
__global__ __launch_bounds__(256) void k_final(
    const ushort* __restrict__ in, const float* __restrict__ wfT,
    const float* __restrict__ scale, const float* __restrict__ shift,
    const float* __restrict__ bfb, float* __restrict__ outp)
{
  constexpr int CI=32, HI=32, WI=32, HO=64, WO=64, SPLIT=4, HOq=HO/SPLIT, SP=HOq*WO;
  constexpr int CIP = CI+4;
  constexpr int RMAX = HOq/2 + 2;   // 10
  __shared__ __align__(16) float in_s[RMAX * WI * CIP];

  const int tid = threadIdx.x;
  const int bid = blockIdx.x;
  const int n = bid / SPLIT, q = bid % SPLIT;
  const int y0 = q * HOq;
  const int rows_lo = max(0, y0/2 - 1);
  const int rows_hi = min(HI-1, (y0 + HOq)/2);
  const int nrows = rows_hi - rows_lo + 1;

  const ushort* inb = in + (size_t)n * CI * HI * WI;
  const int NC = nrows * WI * (CI/8);     // 16B chunks
  for (int c8 = tid; c8 < NC; c8 += 256) {
    int rl = c8 / (WI * (CI/8));
    int rem = c8 - rl * (WI * (CI/8));
    int ix = rem >> 2;
    int ci0 = (rem & 3) * 8;
    uint4 u = *(const uint4*)&inb[(((rows_lo + rl)*WI + ix)*CI) + ci0];
    float4 sc0 = *(const float4*)&scale[ci0];
    float4 sc1 = *(const float4*)&scale[ci0+4];
    float4 sh0 = *(const float4*)&shift[ci0];
    float4 sh1 = *(const float4*)&shift[ci0+4];
    float* dst = &in_s[(rl*WI + ix)*CIP + ci0];
    dst[0] = LRELU(fmaf(bflo(u.x), sc0.x, sh0.x));
    dst[1] = LRELU(fmaf(bfhi(u.x), sc0.y, sh0.y));
    dst[2] = LRELU(fmaf(bflo(u.y), sc0.z, sh0.z));
    dst[3] = LRELU(fmaf(bfhi(u.y), sc0.w, sh0.w));
    dst[4] = LRELU(fmaf(bflo(u.z), sc1.x, sh1.x));
    dst[5] = LRELU(fmaf(bfhi(u.z), sc1.y, sh1.y));
    dst[6] = LRELU(fmaf(bflo(u.w), sc1.z, sh1.z));
    dst[7] = LRELU(fmaf(bfhi(u.w), sc1.w, sh1.w));
  }
  __syncthreads();

  float b0 = bfb[0];
  for (int sp = tid; sp < SP; sp += 256) {
    int y = y0 + sp / WO, x = sp % WO;
    int kya = (y + 1) & 1, iya = (y + 1) >> 1;
    int kxa = (x + 1) & 1, ixa = (x + 1) >> 1;
    float acc = 0.f;
    #pragma unroll
    for (int dy = 0; dy < 2; ++dy) {
      int iy = iya - dy, ky = kya + 2*dy;
      if (iy < 0 || iy >= HI) continue;
      #pragma unroll
      for (int dx = 0; dx < 2; ++dx) {
        int ix = ixa - dx, kx = kxa + 2*dx;
        if (ix < 0 || ix >= WI) continue;
        const float* __restrict__ wpp = wfT + (ky*4 + kx)*CI;
        const float* __restrict__ ib = &in_s[((iy - rows_lo)*WI + ix)*CIP];
        #pragma unroll
        for (int ci = 0; ci < CI; ci += 4) {
          float4 iv = *(const float4*)&ib[ci];
          float4 wv = *(const float4*)&wpp[ci];
          acc = fmaf(iv.x, wv.x, acc);
          acc = fmaf(iv.y, wv.y, acc);
          acc = fmaf(iv.z, wv.z, acc);
          acc = fmaf(iv.w, wv.w, acc);
        }
      }
    }
    float v = acc + b0;
    outp[(size_t)n*HO*WO + y*WO + x] = 1.f/(1.f + __expf(-v));
  }
}

extern "C" void kernel_launch(void* const* d_in, const int* in_sizes, int n_in,
                              void* d_out, int out_size, void* d_ws, size_t ws_size,
                              hipStream_t stream) {
  const float* z_content = (const float*)d_in[0];
  const float* z_motion  = (const float*)d_in[1];
  const float* W_h  = (const float*)d_in[2];
  const float* b_h  = (const float*)d_in[3];
  const float* W_c  = (const float*)d_in[4];
  const float* b_c  = (const float*)d_in[5];
  const float* W_ih = (const float*)d_in[6];
  const float* W_hh = (const float*)d_in[7];
  const float* b_ih = (const float*)d_in[8];
  const float* b_hh = (const float*)d_in[9];
  const float* W_f  = (const float*)d_in[10];
  const float* b_f  = (const float*)d_in[11];
  const float* init_in = (const float*)d_in[12];
  const float* fc_W = (const float*)d_in[13];
  const float* fc_b = (const float*)d_in[14];
  const float* w0 = (const float*)d_in[15];
  const float* g0 = (const float*)d_in[16];
  const float* be0 = (const float*)d_in[17];
  const float* w1 = (const float*)d_in[18];
  const float* g1 = (const float*)d_in[19];
  const float* be1 = (const float*)d_in[20];
  const float* w2 = (const float*)d_in[21];
  const float* g2 = (const float*)d_in[22];
  const float* be2 = (const float*)d_in[23];
  const float* wf = (const float*)d_in[24];
  const float* bf_ = (const float*)d_in[25];

  // ---- workspace layout (same region scheme as the passing round)
  const size_t P_BYTES = 10631168;
  const size_t X_OFF   = P_BYTES;
  const size_t X_BYTES = 83886080;
  const size_t Y_OFF   = X_OFF + X_BYTES;
  const size_t NEED    = Y_OFF + 41943040;
  if (ws_size < NEED) return;

  float* ws = (float*)d_ws;
  char*  wsb = (char*)d_ws;
  float* sum0 = ws + 0;        float* sq0 = ws + 128;
  float* sum1 = ws + 256;      float* sq1 = ws + 320;
  float* sum2 = ws + 384;      float* sq2 = ws + 416;
  float* scale0 = ws + 512;    float* shift0 = ws + 640;
  float* scale1 = ws + 768;    float* shift1 = ws + 832;
  float* scale2 = ws + 896;    float* shift2 = ws + 928;
  float4* xg4   = (float4*)(ws + 1024);
  float4* bias4 = (float4*)(ws + 2048);
  float* h    = ws + 3072;
  float* c    = ws + 19456;
  float* outs = ws + 35840;
  float* WhT  = ws + 363520;
  float* WcT  = ws + 429056;
  float* WfT  = ws + 494592;
  float4* W4hh = (float4*)(ws + 625664);
  float4* W4s  = (float4*)(ws + 887808);
  ushort* wp0 = (ushort*)(ws + 1149952);   // 524288 bf16
  ushort* wp1 = (ushort*)(ws + 1412096);   // 131072 bf16
  ushort* wp2 = (ushort*)(ws + 1477632);   // 32768 bf16
  float* wfT  = ws + 1494016;              // 512 f32
  float* feat = ws + 1494528;              // 819200 f32 -> ends 2,313,728 < P_BYTES/4

  float*  fcWT = (float*) (wsb + X_OFF);   // f32, dead after fc
  ushort* out0 = (ushort*)(wsb + X_OFF);   // NHWC bf16 [1280][8][8][128]
  ushort* out2 = (ushort*)(wsb + X_OFF);   // NHWC bf16 [1280][32][32][32]
  ushort* h1   = (ushort*)(wsb + Y_OFF);   // NHWC bf16 [1280][4][4][256]
  ushort* out1 = (ushort*)(wsb + Y_OFF);   // NHWC bf16 [1280][16][16][64]

  k_zero<<<2, 256, 0, stream>>>(ws, 448);

  dim3 tb(32,8);
  k_transpose<<<dim3(8,8),   tb, 0, stream>>>(W_h,  WhT, 256, 256);
  k_transpose<<<dim3(8,8),   tb, 0, stream>>>(W_c,  WcT, 256, 256);
  k_transpose<<<dim3(8,16),  tb, 0, stream>>>(W_f,  WfT, 512, 256);
  k_transpose<<<dim3(20,128),tb, 0, stream>>>(fc_W, fcWT, 4096, 640);
  k_w4prep<<<256, 256, 0, stream>>>(W_ih, W_hh, W4hh, W4s);
  k_xgbias<<<256, 256, 0, stream>>>(W_ih, b_ih, b_hh, init_in, xg4, bias4);
  k_h0c0<<<64, 256, 0, stream>>>(z_content, z_motion, WhT, WcT, b_h, b_c, h, c);
  k_wprep<256,128><<<2048, 256, 0, stream>>>(w0, wp0);
  k_wprep<128,64><<<512, 256, 0, stream>>>(w1, wp1);
  k_wprep<64,32><<<128, 256, 0, stream>>>(w2, wp2);
  k_wfperm<<<2, 256, 0, stream>>>(wf, wfT);

  k_lstm<<<64, 256, 0, stream>>>(W4hh, xg4, h, c, outs, 0);
  for (int t = 1; t < 20; ++t)
    k_lstm<<<64, 256, 0, stream>>>(W4s, bias4, h, c, outs, t);

  k_ff<<<320, 256, 0, stream>>>(outs, WfT, b_f, feat);
  k_zc<<<640, 256, 0, stream>>>(z_content, feat);
  k_gemm_fc<<<dim3(64,20), 256, 0, stream>>>(feat, fcWT, fc_b, h1);

  // ---- MFMA deconvs (per-parity implicit GEMM) + BN
  k_dcv<256,128,4><<<dim3(160,4), 256, 0, stream>>>(h1, wp0, out0, sum0, sq0);
  k_bnfin<<<1, 128, 0, stream>>>(sum0, sq0, g0, be0, scale0, shift0, 128, 1.f/81920.f);
  k_bnact<<<5120, 256, 0, stream>>>(out0, scale0, shift0, 1310720, 127);
  k_dcv<128,64,8><<<dim3(640,4), 256, 0, stream>>>(out0, wp1, out1, sum1, sq1);
  k_bnfin<<<1, 64, 0, stream>>>(sum1, sq1, g1, be1, scale1, shift1, 64, 1.f/327680.f);
  k_bnact<<<10240, 256, 0, stream>>>(out1, scale1, shift1, 2621440, 63);
  k_dcv<64,32,16><<<dim3(2560,4), 256, 0, stream>>>(out1, wp2, out2, sum2, sq2);
  k_bnfin<<<1, 32, 0, stream>>>(sum2, sq2, g2, be2, scale2, shift2, 32, 1.f/1310720.f);
  k_final<<<5120, 256, 0, stream>>>(out2, wfT, scale2, shift2, bf_, (float*)d_out);
}

// Round 4
// 796.302 us; speedup vs baseline: 9.2856x; 1.2545x over previous
//
#include <hip/hip_runtime.h>
#include <hip/hip_bf16.h>
#include <math.h>

typedef __hip_bfloat16 bf16;
typedef __attribute__((ext_vector_type(8))) short bf16x8;
typedef __attribute__((ext_vector_type(4))) float f32x4;

#define LRELU(v) ((v) > 0.f ? (v) : 0.2f*(v))

__device__ __forceinline__ float sig_f(float x){ return 1.f/(1.f + __expf(-x)); }
__device__ __forceinline__ float tanh_f(float x){
  float ax = fabsf(x);
  float e = __expf(-2.f*ax);
  float t = (1.f - e)/(1.f + e);
  return x >= 0.f ? t : -t;
}
__device__ __forceinline__ ushort bfbits(float v){
  bf16 b = __float2bfloat16(v);
  return *(ushort*)&b;
}
__device__ __forceinline__ float bflo(uint u){ return __uint_as_float(u << 16); }
__device__ __forceinline__ float bfhi(uint u){ return __uint_as_float(u & 0xffff0000u); }

__global__ void k_zero(float* __restrict__ p, int n){
  int i = blockIdx.x*256 + threadIdx.x;
  if (i < n) p[i] = 0.f;
}

// ---------------- generic tiled transpose: src[R][C] -> dst[C][R]; R,C mult of 32; block(32,8)
__global__ void k_transpose(const float* __restrict__ src, float* __restrict__ dst, int R, int C){
  __shared__ float t[32][33];
  int c0 = blockIdx.x*32, r0 = blockIdx.y*32;
  int tx = threadIdx.x, ty = threadIdx.y;
  #pragma unroll
  for (int i = 0; i < 4; ++i)
    t[ty+8*i][tx] = src[(size_t)(r0+ty+8*i)*C + c0+tx];
  __syncthreads();
  #pragma unroll
  for (int i = 0; i < 4; ++i)
    dst[(size_t)(c0+ty+8*i)*R + r0+tx] = t[tx][ty+8*i];
}

// ---------------- LSTM weight pack
__global__ void k_w4prep(const float* __restrict__ Wih, const float* __restrict__ Whh,
                         float4* __restrict__ W4hh, float4* __restrict__ W4s){
  int k = blockIdx.x, j = threadIdx.x;
  float h0 = Whh[j*256+k],       h1 = Whh[(256+j)*256+k];
  float h2 = Whh[(512+j)*256+k], h3 = Whh[(768+j)*256+k];
  float i0 = Wih[j*256+k],       i1 = Wih[(256+j)*256+k];
  float i2 = Wih[(512+j)*256+k], i3 = Wih[(768+j)*256+k];
  W4hh[k*256+j] = make_float4(h0,h1,h2,h3);
  W4s [k*256+j] = make_float4(h0+i0, h1+i1, h2+i2, h3+i3);
}

__global__ void k_xgbias(const float* __restrict__ Wih, const float* __restrict__ b_ih,
                         const float* __restrict__ b_hh, const float* __restrict__ init_in,
                         float4* __restrict__ xg4, float4* __restrict__ bias4){
  int b = blockIdx.x, t = threadIdx.x;
  float v = init_in[t];
  float p0 = v * Wih[b*256 + t];
  float p1 = v * Wih[(256+b)*256 + t];
  float p2 = v * Wih[(512+b)*256 + t];
  float p3 = v * Wih[(768+b)*256 + t];
  #pragma unroll
  for (int o = 32; o; o >>= 1) {
    p0 += __shfl_xor(p0, o); p1 += __shfl_xor(p1, o);
    p2 += __shfl_xor(p2, o); p3 += __shfl_xor(p3, o);
  }
  __shared__ float4 red[4];
  int lane = t & 63, wid = t >> 6;
  if (lane == 0) red[wid] = make_float4(p0,p1,p2,p3);
  __syncthreads();
  if (t == 0) {
    float4 bi = make_float4(b_ih[b]+b_hh[b], b_ih[256+b]+b_hh[256+b],
                            b_ih[512+b]+b_hh[512+b], b_ih[768+b]+b_hh[768+b]);
    bias4[b] = bi;
    float4 a = bi;
    #pragma unroll
    for (int w = 0; w < 4; ++w) { a.x += red[w].x; a.y += red[w].y; a.z += red[w].z; a.w += red[w].w; }
    xg4[b] = a;
  }
}

__global__ __launch_bounds__(256) void k_h0c0(const float* __restrict__ zc, const float* __restrict__ zm,
                      const float* __restrict__ WhT, const float* __restrict__ WcT,
                      const float* __restrict__ b_h, const float* __restrict__ b_c,
                      float* __restrict__ h, float* __restrict__ c){
  __shared__ float zs[256];
  int b = blockIdx.x, j = threadIdx.x;
  zs[j] = (j < 128) ? zc[b*128 + j] : zm[b*128 + (j-128)];
  __syncthreads();
  float ah = b_h[j], ac = b_c[j];
  #pragma unroll 4
  for (int k = 0; k < 256; ++k) {
    float zv = zs[k];
    ah = fmaf(zv, WhT[k*256 + j], ah);
    ac = fmaf(zv, WcT[k*256 + j], ac);
  }
  h[b*256+j] = ah; c[b*256+j] = ac;
}

__global__ __launch_bounds__(256) void k_lstm(const float4* __restrict__ W4, const float4* __restrict__ base4,
                      float* __restrict__ h, float* __restrict__ c,
                      float* __restrict__ outs, int t){
  __shared__ float hs[256];
  int b = blockIdx.x, j = threadIdx.x;
  hs[j] = h[b*256 + j];
  __syncthreads();
  float4 a = base4[j];
  #pragma unroll 8
  for (int k = 0; k < 256; ++k) {
    float4 w = W4[k*256 + j];
    float hv = hs[k];
    a.x = fmaf(hv, w.x, a.x);
    a.y = fmaf(hv, w.y, a.y);
    a.z = fmaf(hv, w.z, a.z);
    a.w = fmaf(hv, w.w, a.w);
  }
  float cv = c[b*256 + j];
  float ig = sig_f(a.x), fg = sig_f(a.y), gg = tanh_f(a.z), og = sig_f(a.w);
  float cn = fmaf(fg, cv, ig*gg);
  float hn = og * tanh_f(cn);
  c[b*256+j] = cn;
  h[b*256+j] = hn;
  outs[(b*20 + t)*256 + j] = hn;
}

__global__ __launch_bounds__(256) void k_ff(const float* __restrict__ outs, const float* __restrict__ WfT,
                    const float* __restrict__ b_f, float* __restrict__ feat){
  __shared__ float rows[4][256];
  int r0 = blockIdx.x * 4, tid = threadIdx.x;
  #pragma unroll
  for (int i = 0; i < 4; ++i) rows[i][tid] = outs[(r0+i)*256 + tid];
  __syncthreads();
  #pragma unroll
  for (int half = 0; half < 2; ++half) {
    int j = tid + half*256;
    float bb = b_f[j];
    float a0 = bb, a1 = bb, a2 = bb, a3 = bb;
    #pragma unroll 4
    for (int k = 0; k < 256; ++k) {
      float w = WfT[k*512 + j];
      a0 = fmaf(rows[0][k], w, a0);
      a1 = fmaf(rows[1][k], w, a1);
      a2 = fmaf(rows[2][k], w, a2);
      a3 = fmaf(rows[3][k], w, a3);
    }
    feat[(r0+0)*640 + j] = LRELU(a0);
    feat[(r0+1)*640 + j] = LRELU(a1);
    feat[(r0+2)*640 + j] = LRELU(a2);
    feat[(r0+3)*640 + j] = LRELU(a3);
  }
}

__global__ void k_zc(const float* __restrict__ zc, float* __restrict__ feat){
  int e = blockIdx.x*256 + threadIdx.x;
  int r = e >> 7, c = e & 127;
  feat[r*640 + 512 + c] = zc[(r/20)*128 + c];
}

// ---------------- FC GEMM: lrelu(A[1280][640]@B[640][4096]+bias) -> h1 NHWC bf16 [r][y][x][co]
__global__ __launch_bounds__(256) void k_gemm_fc(const float* __restrict__ A, const float* __restrict__ B,
                         const float* __restrict__ bias, ushort* __restrict__ C){
  constexpr int N = 4096, K = 640;
  __shared__ float As[16][68];
  __shared__ float Bs[16][68];
  int tid = threadIdx.x, tx = tid & 15, ty = tid >> 4;
  int col0 = blockIdx.x * 64, row0 = blockIdx.y * 64;
  float4 acc[4];
  #pragma unroll
  for (int i = 0; i < 4; ++i) acc[i] = make_float4(0,0,0,0);
  for (int k0 = 0; k0 < K; k0 += 16) {
    #pragma unroll
    for (int i = 0; i < 4; ++i) {
      int e = i*256 + tid;
      int ak = e & 15, am = e >> 4;
      As[ak][am] = A[(row0+am)*K + k0+ak];
      int bn = e & 63, bk = e >> 6;
      Bs[bk][bn] = B[(size_t)(k0+bk)*N + col0+bn];
    }
    __syncthreads();
    #pragma unroll
    for (int k = 0; k < 16; ++k) {
      float4 a = *(const float4*)&As[k][ty*4];
      float4 b = *(const float4*)&Bs[k][tx*4];
      acc[0].x = fmaf(a.x,b.x,acc[0].x); acc[0].y = fmaf(a.x,b.y,acc[0].y); acc[0].z = fmaf(a.x,b.z,acc[0].z); acc[0].w = fmaf(a.x,b.w,acc[0].w);
      acc[1].x = fmaf(a.y,b.x,acc[1].x); acc[1].y = fmaf(a.y,b.y,acc[1].y); acc[1].z = fmaf(a.y,b.z,acc[1].z); acc[1].w = fmaf(a.y,b.w,acc[1].w);
      acc[2].x = fmaf(a.z,b.x,acc[2].x); acc[2].y = fmaf(a.z,b.y,acc[2].y); acc[2].z = fmaf(a.z,b.z,acc[2].z); acc[2].w = fmaf(a.z,b.w,acc[2].w);
      acc[3].x = fmaf(a.w,b.x,acc[3].x); acc[3].y = fmaf(a.w,b.y,acc[3].y); acc[3].z = fmaf(a.w,b.z,acc[3].z); acc[3].w = fmaf(a.w,b.w,acc[3].w);
    }
    __syncthreads();
  }
  float4 bv = *(const float4*)&bias[col0 + tx*4];
  #pragma unroll
  for (int i = 0; i < 4; ++i) {
    int row = row0 + ty*4 + i;
    float vv[4] = {acc[i].x + bv.x, acc[i].y + bv.y, acc[i].z + bv.z, acc[i].w + bv.w};
    #pragma unroll
    for (int jj = 0; jj < 4; ++jj) {
      int j = col0 + tx*4 + jj;      // j = co*16 + s  ->  NHWC idx = (row*16 + s)*256 + co
      C[((size_t)row << 12) + ((size_t)(j & 15) << 8) + (j >> 4)] = bfbits(LRELU(vv[jj]));
    }
  }
}

// ---------------- deconv weight prep: w[ci][co][ky][kx] f32 -> wp[p][co][t*CI+ci] bf16
template<int CI, int CO>
__global__ void k_wprep(const float* __restrict__ w, ushort* __restrict__ wp){
  int e = blockIdx.x*256 + threadIdx.x;     // total 16*CI*CO
  if (e >= 16*CI*CO) return;
  int ci = e % CI; int t1 = e / CI;
  int t = t1 & 3;  int t2 = t1 >> 2;
  int co = t2 % CO; int pp = t2 / CO;
  int py = pp >> 1, px = pp & 1, dy = t >> 1, dx = t & 1;
  int ky = (py ? 0 : 1) + 2*dy;
  int kx = (px ? 0 : 1) + 2*dx;
  wp[e] = bfbits(w[((ci*CO + co)*4 + ky)*4 + kx]);
}

__global__ void k_wfperm(const float* __restrict__ wf, float* __restrict__ wfT){
  int e = blockIdx.x*256 + threadIdx.x;
  if (e < 512) {
    int tap = e >> 5, ci = e & 31;
    wfT[tap*32 + ci] = wf[ci*16 + tap];
  }
}

// ---------------- MFMA parity-GEMM deconv (stage 0 only: deep K, spatial-tiled)
// in: NHWC bf16 (already activated), wp: [4][CO][4*CI] bf16
// out: NHWC bf16 raw; gsum/gsq: per-co batch stats (f32)
template<int CI, int CO, int HI>
__global__ __launch_bounds__(256) void k_dcv(
    const ushort* __restrict__ in, const ushort* __restrict__ wp,
    ushort* __restrict__ out, float* __restrict__ gsum, float* __restrict__ gsq)
{
  constexpr int WI = HI, HO = 2*HI, WO = 2*WI;
  constexpr int K = 4*CI, BK = 64, NK = K/BK;
  constexpr int BSP = 128;
  constexpr int RS = 72;
  constexpr int NCF = CO/16;
  constexpr int AC = BSP/32;
  constexpr int WC = CO/32;

  __shared__ __align__(16) ushort Al[2][BSP*RS];
  __shared__ __align__(16) ushort Wl[2][CO*RS];
  __shared__ float s_sum[CO], s_sq[CO];

  const int tid = threadIdx.x;
  const int sp0 = blockIdx.x * BSP;
  const int p  = blockIdx.y;
  const int py = p >> 1, px = p & 1;
  const int w  = tid >> 6, l = tid & 63;
  const int lm = l & 15, lk = l >> 4;

  if (tid < CO) { s_sum[tid] = 0.f; s_sq[tid] = 0.f; }

  f32x4 acc[NCF][2];
  #pragma unroll
  for (int m = 0; m < NCF; ++m)
    #pragma unroll
    for (int s = 0; s < 2; ++s)
      acc[m][s] = (f32x4){0.f,0.f,0.f,0.f};

  uint4 ar[AC], wr[WC];

  #define LOADT(kt) { \
    int t = ((kt)*BK)/CI, ci0 = ((kt)*BK)%CI; \
    int dy = t >> 1, dx = t & 1; \
    _Pragma("unroll") \
    for (int i = 0; i < AC; ++i) { \
      int chunk = tid + i*256; \
      int rl = chunk >> 3, kc = chunk & 7; \
      int r = sp0 + rl; \
      int n = r / (HI*WI), rem = r % (HI*WI); \
      int oy = rem / WI, ox = rem % WI; \
      int iy = oy + py - dy, ix = ox + px - dx; \
      if ((unsigned)iy < (unsigned)HI && (unsigned)ix < (unsigned)WI) \
        ar[i] = *(const uint4*)&in[((((size_t)n*HI + iy)*WI + ix)*CI) + ci0 + kc*8]; \
      else ar[i] = make_uint4(0,0,0,0); \
    } \
    _Pragma("unroll") \
    for (int i = 0; i < WC; ++i) { \
      int chunk = tid + i*256; \
      int co = chunk >> 3, kc = chunk & 7; \
      wr[i] = *(const uint4*)&wp[((size_t)p*CO + co)*K + (kt)*BK + kc*8]; \
    } }

  #define STORET(buf) { \
    _Pragma("unroll") \
    for (int i = 0; i < AC; ++i) { \
      int chunk = tid + i*256; \
      int rl = chunk >> 3, kc = chunk & 7; \
      *(uint4*)&Al[buf][rl*RS + kc*8] = ar[i]; \
    } \
    _Pragma("unroll") \
    for (int i = 0; i < WC; ++i) { \
      int chunk = tid + i*256; \
      int co = chunk >> 3, kc = chunk & 7; \
      *(uint4*)&Wl[buf][co*RS + kc*8] = wr[i]; \
    } }

  LOADT(0);
  STORET(0);
  int cur = 0;
  for (int kt = 0; kt < NK; ++kt) {
    if (kt + 1 < NK) LOADT(kt + 1);
    __syncthreads();
    #pragma unroll
    for (int kf = 0; kf < 2; ++kf) {
      bf16x8 bfr[2];
      #pragma unroll
      for (int s = 0; s < 2; ++s)
        bfr[s] = *(bf16x8*)&Al[cur][(w*32 + s*16 + lm)*RS + kf*32 + lk*8];
      #pragma unroll
      for (int m = 0; m < NCF; ++m) {
        bf16x8 afr = *(bf16x8*)&Wl[cur][(m*16 + lm)*RS + kf*32 + lk*8];
        acc[m][0] = __builtin_amdgcn_mfma_f32_16x16x32_bf16(afr, bfr[0], acc[m][0], 0, 0, 0);
        acc[m][1] = __builtin_amdgcn_mfma_f32_16x16x32_bf16(afr, bfr[1], acc[m][1], 0, 0, 0);
      }
    }
    if (kt + 1 < NK) STORET(cur ^ 1);
    cur ^= 1;
  }

  #pragma unroll
  for (int m = 0; m < NCF; ++m) {
    float s1[4] = {0,0,0,0}, s2[4] = {0,0,0,0};
    #pragma unroll
    for (int s = 0; s < 2; ++s) {
      f32x4 v = acc[m][s];
      int sp = sp0 + w*32 + s*16 + lm;
      int n = sp / (HI*WI), rem = sp % (HI*WI);
      int y = 2*(rem / WI) + py, x = 2*(rem % WI) + px;
      size_t ob = (((size_t)n*HO + y)*WO + x)*CO + m*16 + lk*4;
      union { ushort u[4]; uint2 q; } pk;
      #pragma unroll
      for (int j = 0; j < 4; ++j) {
        pk.u[j] = bfbits(v[j]);
        s1[j] += v[j];
        s2[j] += v[j]*v[j];
      }
      *(uint2*)&out[ob] = pk.q;
    }
    #pragma unroll
    for (int j = 0; j < 4; ++j) {
      float a = s1[j], b = s2[j];
      #pragma unroll
      for (int o = 1; o < 16; o <<= 1) { a += __shfl_xor(a, o); b += __shfl_xor(b, o); }
      if (lm == 0) {
        atomicAdd(&s_sum[m*16 + lk*4 + j], a);
        atomicAdd(&s_sq [m*16 + lk*4 + j], b);
      }
    }
  }
  __syncthreads();
  for (int cc = tid; cc < CO; cc += 256) {
    atomicAdd(&gsum[cc], s_sum[cc]);
    atomicAdd(&gsq[cc],  s_sq[cc]);
  }
  #undef LOADT
  #undef STORET
}

// ---------------- image-resident MFMA deconv (stages 1 & 2): one image per block,
// all 4 parities in-block; input staged once (BN+LReLU fused) into zero-halo
// swizzled LDS; weights read per-fragment from global (L2-hot); K-loop barrier-free.
// wave w: parity p = w>>1, co-half mh = w&1.
template<int CI, int CO, int HI>
__global__ __launch_bounds__(512) void k_dcvim(
    const ushort* __restrict__ in, const ushort* __restrict__ wp,
    const float* __restrict__ scale, const float* __restrict__ shift,
    ushort* __restrict__ out, float* __restrict__ gsum, float* __restrict__ gsq)
{
  constexpr int WI = HI, HO = 2*HI, WO = 2*WI;
  constexpr int K = 4*CI;
  constexpr int KF = K/32;
  constexpr int PAD = HI + 2;
  constexpr int CICH = CI/8;                 // 16B ci-chunks
  constexpr int AU4 = PAD*PAD*CICH;          // Ain size in uint4
  constexpr int SFT = HI*WI/16;              // spatial fragments (all per wave)
  constexpr int MMW = CO/32;                 // m-frags per wave (co-half)

  __shared__ __align__(16) ushort Ain[PAD*PAD*CI];
  __shared__ float s_sum[CO], s_sq[CO];

  const int tid = threadIdx.x;
  const int n = blockIdx.x;
  const int w = tid >> 6, l = tid & 63, lm = l & 15, lk = l >> 4;
  const int p = w >> 1, py = p >> 1, px = p & 1, mh = w & 1;

  if (tid < CO) { s_sum[tid] = 0.f; s_sq[tid] = 0.f; }

  // zero whole padded tile (halo)
  uint4 zz = make_uint4(0,0,0,0);
  for (int i = tid; i < AU4; i += 512) ((uint4*)Ain)[i] = zz;
  __syncthreads();

  // stage interior with BN+LReLU, swizzled: chunk' = ci8 ^ (c&7)
  const ushort* inb = in + (size_t)n * HI * WI * CI;
  constexpr int NCHK = HI*WI*CICH;
  for (int e = tid; e < NCHK; e += 512) {
    int ci8 = e % CICH; int sp = e / CICH;
    int ix = sp % WI, iy = sp / WI;
    uint4 u = *(const uint4*)&inb[(size_t)sp*CI + ci8*8];
    int ci0 = ci8*8;
    float4 sc0 = *(const float4*)&scale[ci0];
    float4 sc1 = *(const float4*)&scale[ci0+4];
    float4 sh0 = *(const float4*)&shift[ci0];
    float4 sh1 = *(const float4*)&shift[ci0+4];
    float v0 = LRELU(fmaf(bflo(u.x), sc0.x, sh0.x));
    float v1 = LRELU(fmaf(bfhi(u.x), sc0.y, sh0.y));
    float v2 = LRELU(fmaf(bflo(u.y), sc0.z, sh0.z));
    float v3 = LRELU(fmaf(bfhi(u.y), sc0.w, sh0.w));
    float v4 = LRELU(fmaf(bflo(u.z), sc1.x, sh1.x));
    float v5 = LRELU(fmaf(bfhi(u.z), sc1.y, sh1.y));
    float v6 = LRELU(fmaf(bflo(u.w), sc1.z, sh1.z));
    float v7 = LRELU(fmaf(bfhi(u.w), sc1.w, sh1.w));
    uint4 o;
    o.x = (uint)bfbits(v0) | ((uint)bfbits(v1) << 16);
    o.y = (uint)bfbits(v2) | ((uint)bfbits(v3) << 16);
    o.z = (uint)bfbits(v4) | ((uint)bfbits(v5) << 16);
    o.w = (uint)bfbits(v6) | ((uint)bfbits(v7) << 16);
    int r = iy + 1, c = ix + 1;
    int chS = ci8 ^ (c & 7);
    ((uint4*)Ain)[(r*PAD + c)*CICH + chS] = o;
  }
  __syncthreads();

  // accumulators
  f32x4 acc[MMW][SFT];
  #pragma unroll
  for (int m = 0; m < MMW; ++m)
    #pragma unroll
    for (int sf = 0; sf < SFT; ++sf)
      acc[m][sf] = (f32x4){0.f,0.f,0.f,0.f};

  // barrier-free K loop: W fragments straight from global (L2-hot)
  const ushort* wpb = wp + ((size_t)p*CO + mh*(CO/2))*K;
  #pragma unroll
  for (int kf = 0; kf < KF; ++kf) {
    const int t = (kf*32)/CI, cib = (kf*32)%CI;
    const int dy = t >> 1, dx = t & 1;
    bf16x8 afr[MMW];
    #pragma unroll
    for (int m = 0; m < MMW; ++m)
      afr[m] = *(const bf16x8*)&wpb[(size_t)(m*16 + lm)*K + kf*32 + lk*8];
    const int ch = (cib >> 3) + lk;          // global ci-chunk for this lane
    #pragma unroll
    for (int sf = 0; sf < SFT; ++sf) {
      int s = sf*16 + lm;
      int y = s / WI, x = s % WI;
      int r = y + py - dy + 1, c = x + px - dx + 1;
      bf16x8 bfr = *(const bf16x8*)&Ain[((r*PAD + c)*CICH + (ch ^ (c & 7)))*8];
      #pragma unroll
      for (int m = 0; m < MMW; ++m)
        acc[m][sf] = __builtin_amdgcn_mfma_f32_16x16x32_bf16(afr[m], bfr, acc[m][sf], 0, 0, 0);
    }
  }

  // epilogue: NHWC write + stats
  #pragma unroll
  for (int m = 0; m < MMW; ++m) {
    int co0 = mh*(CO/2) + m*16 + lk*4;
    float s1[4] = {0,0,0,0}, s2[4] = {0,0,0,0};
    #pragma unroll
    for (int sf = 0; sf < SFT; ++sf) {
      f32x4 v = acc[m][sf];
      int s = sf*16 + lm;
      int y = 2*(s / WI) + py, x = 2*(s % WI) + px;
      size_t ob = (((size_t)n*HO + y)*WO + x)*CO + co0;
      union { ushort u[4]; uint2 q; } pk;
      #pragma unroll
      for (int j = 0; j < 4; ++j) {
        pk.u[j] = bfbits(v[j]);
        s1[j] += v[j];
        s2[j] += v[j]*v[j];
      }
      *(uint2*)&out[ob] = pk.q;
    }
    #pragma unroll
    for (int j = 0; j < 4; ++j) {
      float a = s1[j], b = s2[j];
      #pragma unroll
      for (int o = 1; o < 16; o <<= 1) { a += __shfl_xor(a, o); b += __shfl_xor(b, o); }
      if (lm == 0) {
        atomicAdd(&s_sum[co0 + j], a);
        atomicAdd(&s_sq [co0 + j], b);
      }
    }
  }
  __syncthreads();
  for (int cc = tid; cc < CO; cc += 512) {
    atomicAdd(&gsum[cc], s_sum[cc]);
    atomicAdd(&gsq[cc],  s_sq[cc]);
  }
}

// ---------------- BN finalize
__global__ void k_bnfin(const float* __restrict__ sum, const float* __restrict__ sq,
                        const float* __restrict__ g, const float* __restrict__ be,
                        float* __restrict__ scale, float* __restrict__ shift,
                        int CO, float invN){
  int c = threadIdx.x;
  if (c >= CO) return;
  float m = sum[c]*invN;
  float v = sq[c]*invN - m*m;
  float sc = g[c]*rsqrtf(v + 1e-5f);
  scale[c] = sc;
  shift[c] = be[c] - m*sc;
}

// ---------------- final deconv 32->1 + sigmoid (input NHWC bf16 raw, BN fused on load)
__global__ __launch_bounds__(256) void k_final(
    const ushort* __restrict__ in, const float* __restrict__ wfT,
    const float* __restrict__ scale, const float* __restrict__ shift,
    const float* __restrict__ bfb, float* __restrict__ outp)
{
  constexpr int CI=32, HI=32, WI=32, HO=64, WO=64, SPLIT=4, HOq=HO/SPLIT, SP=HOq*WO;
  constexpr int CIP = CI+4;
  constexpr int RMAX = HOq/2 + 2;   // 10
  __shared__ __align__(16) float in_s[RMAX * WI * CIP];

  const int tid = threadIdx.x;
  const int bid = blockIdx.x;
  const int n = bid / SPLIT, q = bid % SPLIT;
  const int y0 = q * HOq;
  const int rows_lo = max(0, y0/2 - 1);
  const int rows_hi = min(HI-1, (y0 + HOq)/2);
  const int nrows = rows_hi - rows_lo + 1;

  const ushort* inb = in + (size_t)n * CI * HI * WI;
  const int NC = nrows * WI * (CI/8);
  for (int c8 = tid; c8 < NC; c8 += 256) {
    int rl = c8 / (WI * (CI/8));
    int rem = c8 - rl * (WI * (CI/8));
    int ix = rem >> 2;
    int ci0 = (rem & 3) * 8;
    uint4 u = *(const uint4*)&inb[(((rows_lo + rl)*WI + ix)*CI) + ci0];
    float4 sc0 = *(const float4*)&scale[ci0];
    float4 sc1 = *(const float4*)&scale[ci0+4];
    float4 sh0 = *(const float4*)&shift[ci0];
    float4 sh1 = *(const float4*)&shift[ci0+4];
    float* dst = &in_s[(rl*WI + ix)*CIP + ci0];
    dst[0] = LRELU(fmaf(bflo(u.x), sc0.x, sh0.x));
    dst[1] = LRELU(fmaf(bfhi(u.x), sc0.y, sh0.y));
    dst[2] = LRELU(fmaf(bflo(u.y), sc0.z, sh0.z));
    dst[3] = LRELU(fmaf(bfhi(u.y), sc0.w, sh0.w));
    dst[4] = LRELU(fmaf(bflo(u.z), sc1.x, sh1.x));
    dst[5] = LRELU(fmaf(bfhi(u.z), sc1.y, sh1.y));
    dst[6] = LRELU(fmaf(bflo(u.w), sc1.z, sh1.z));
    dst[7] = LRELU(fmaf(bfhi(u.w), sc1.w, sh1.w));
  }
  __syncthreads();

  float b0 = bfb[0];
  for (int sp = tid; sp < SP; sp += 256) {
    int y = y0 + sp / WO, x = sp % WO;
    int kya = (y + 1) & 1, iya = (y + 1) >> 1;
    int kxa = (x + 1) & 1, ixa = (x + 1) >> 1;
    float acc = 0.f;
    #pragma unroll
    for (int dy = 0; dy < 2; ++dy) {
      int iy = iya - dy, ky = kya + 2*dy;
      if (iy < 0 || iy >= HI) continue;
      #pragma unroll
      for (int dx = 0; dx < 2; ++dx) {
        int ix = ixa - dx, kx = kxa + 2*dx;
        if (ix < 0 || ix >= WI) continue;
        const float* __restrict__ wpp = wfT + (ky*4 + kx)*CI;
        const float* __restrict__ ib = &in_s[((iy - rows_lo)*WI + ix)*CIP];
        #pragma unroll
        for (int ci = 0; ci < CI; ci += 4) {
          float4 iv = *(const float4*)&ib[ci];
          float4 wv = *(const float4*)&wpp[ci];
          acc = fmaf(iv.x, wv.x, acc);
          acc = fmaf(iv.y, wv.y, acc);
          acc = fmaf(iv.z, wv.z, acc);
          acc = fmaf(iv.w, wv.w, acc);
        }
      }
    }
    float v = acc + b0;
    outp[(size_t)n*HO*WO + y*WO + x] = 1.f/(1.f + __expf(-v));
  }
}

extern "C" void kernel_launch(void* const* d_in, const int* in_sizes, int n_in,
                              void* d_out, int out_size, void* d_ws, size_t ws_size,
                              hipStream_t stream) {
  const float* z_content = (const float*)d_in[0];
  const float* z_motion  = (const float*)d_in[1];
  const float* W_h  = (const float*)d_in[2];
  const float* b_h  = (const float*)d_in[3];
  const float* W_c  = (const float*)d_in[4];
  const float* b_c  = (const float*)d_in[5];
  const float* W_ih = (const float*)d_in[6];
  const float* W_hh = (const float*)d_in[7];
  const float* b_ih = (const float*)d_in[8];
  const float* b_hh = (const float*)d_in[9];
  const float* W_f  = (const float*)d_in[10];
  const float* b_f  = (const float*)d_in[11];
  const float* init_in = (const float*)d_in[12];
  const float* fc_W = (const float*)d_in[13];
  const float* fc_b = (const float*)d_in[14];
  const float* w0 = (const float*)d_in[15];
  const float* g0 = (const float*)d_in[16];
  const float* be0 = (const float*)d_in[17];
  const float* w1 = (const float*)d_in[18];
  const float* g1 = (const float*)d_in[19];
  const float* be1 = (const float*)d_in[20];
  const float* w2 = (const float*)d_in[21];
  const float* g2 = (const float*)d_in[22];
  const float* be2 = (const float*)d_in[23];
  const float* wf = (const float*)d_in[24];
  const float* bf_ = (const float*)d_in[25];

  const size_t P_BYTES = 10631168;
  const size_t X_OFF   = P_BYTES;
  const size_t X_BYTES = 83886080;
  const size_t Y_OFF   = X_OFF + X_BYTES;
  const size_t NEED    = Y_OFF + 41943040;
  if (ws_size < NEED) return;

  float* ws = (float*)d_ws;
  char*  wsb = (char*)d_ws;
  float* sum0 = ws + 0;        float* sq0 = ws + 128;
  float* sum1 = ws + 256;      float* sq1 = ws + 320;
  float* sum2 = ws + 384;      float* sq2 = ws + 416;
  float* scale0 = ws + 512;    float* shift0 = ws + 640;
  float* scale1 = ws + 768;    float* shift1 = ws + 832;
  float* scale2 = ws + 896;    float* shift2 = ws + 928;
  float4* xg4   = (float4*)(ws + 1024);
  float4* bias4 = (float4*)(ws + 2048);
  float* h    = ws + 3072;
  float* c    = ws + 19456;
  float* outs = ws + 35840;
  float* WhT  = ws + 363520;
  float* WcT  = ws + 429056;
  float* WfT  = ws + 494592;
  float4* W4hh = (float4*)(ws + 625664);
  float4* W4s  = (float4*)(ws + 887808);
  ushort* wp0 = (ushort*)(ws + 1149952);   // 524288 bf16
  ushort* wp1 = (ushort*)(ws + 1412096);   // 131072 bf16
  ushort* wp2 = (ushort*)(ws + 1477632);   // 32768 bf16
  float* wfT  = ws + 1494016;              // 512 f32
  float* feat = ws + 1494528;              // 819200 f32

  float*  fcWT = (float*) (wsb + X_OFF);
  ushort* out0 = (ushort*)(wsb + X_OFF);   // NHWC bf16 [1280][8][8][128]
  ushort* out2 = (ushort*)(wsb + X_OFF);   // NHWC bf16 [1280][32][32][32]
  ushort* h1   = (ushort*)(wsb + Y_OFF);   // NHWC bf16 [1280][4][4][256]
  ushort* out1 = (ushort*)(wsb + Y_OFF);   // NHWC bf16 [1280][16][16][64]

  k_zero<<<2, 256, 0, stream>>>(ws, 448);

  dim3 tb(32,8);
  k_transpose<<<dim3(8,8),   tb, 0, stream>>>(W_h,  WhT, 256, 256);
  k_transpose<<<dim3(8,8),   tb, 0, stream>>>(W_c,  WcT, 256, 256);
  k_transpose<<<dim3(8,16),  tb, 0, stream>>>(W_f,  WfT, 512, 256);
  k_transpose<<<dim3(20,128),tb, 0, stream>>>(fc_W, fcWT, 4096, 640);
  k_w4prep<<<256, 256, 0, stream>>>(W_ih, W_hh, W4hh, W4s);
  k_xgbias<<<256, 256, 0, stream>>>(W_ih, b_ih, b_hh, init_in, xg4, bias4);
  k_h0c0<<<64, 256, 0, stream>>>(z_content, z_motion, WhT, WcT, b_h, b_c, h, c);
  k_wprep<256,128><<<2048, 256, 0, stream>>>(w0, wp0);
  k_wprep<128,64><<<512, 256, 0, stream>>>(w1, wp1);
  k_wprep<64,32><<<128, 256, 0, stream>>>(w2, wp2);
  k_wfperm<<<2, 256, 0, stream>>>(wf, wfT);

  k_lstm<<<64, 256, 0, stream>>>(W4hh, xg4, h, c, outs, 0);
  for (int t = 1; t < 20; ++t)
    k_lstm<<<64, 256, 0, stream>>>(W4s, bias4, h, c, outs, t);

  k_ff<<<320, 256, 0, stream>>>(outs, WfT, b_f, feat);
  k_zc<<<640, 256, 0, stream>>>(z_content, feat);
  k_gemm_fc<<<dim3(64,20), 256, 0, stream>>>(feat, fcWT, fc_b, h1);

  // ---- deconv pipeline: stage0 spatial-tiled, stages 1&2 image-resident (BN fused on stage)
  k_dcv<256,128,4><<<dim3(160,4), 256, 0, stream>>>(h1, wp0, out0, sum0, sq0);
  k_bnfin<<<1, 128, 0, stream>>>(sum0, sq0, g0, be0, scale0, shift0, 128, 1.f/81920.f);
  k_dcvim<128,64,8><<<1280, 512, 0, stream>>>(out0, wp1, scale0, shift0, out1, sum1, sq1);
  k_bnfin<<<1, 64, 0, stream>>>(sum1, sq1, g1, be1, scale1, shift1, 64, 1.f/327680.f);
  k_dcvim<64,32,16><<<1280, 512, 0, stream>>>(out1, wp2, scale1, shift1, out2, sum2, sq2);
  k_bnfin<<<1, 32, 0, stream>>>(sum2, sq2, g2, be2, scale2, shift2, 32, 1.f/1310720.f);
  k_final<<<5120, 256, 0, stream>>>(out2, wfT, scale2, shift2, bf_, (float*)d_out);
}

// Round 5
// 686.358 us; speedup vs baseline: 10.7730x; 1.1602x over previous
//
#include <hip/hip_runtime.h>
#include <hip/hip_bf16.h>
#include <math.h>

typedef __hip_bfloat16 bf16;
typedef __attribute__((ext_vector_type(8))) short bf16x8;
typedef __attribute__((ext_vector_type(4))) float f32x4;

#define LRELU(v) ((v) > 0.f ? (v) : 0.2f*(v))

__device__ __forceinline__ float sig_f(float x){ return 1.f/(1.f + __expf(-x)); }
__device__ __forceinline__ float tanh_f(float x){
  float ax = fabsf(x);
  float e = __expf(-2.f*ax);
  float t = (1.f - e)/(1.f + e);
  return x >= 0.f ? t : -t;
}
__device__ __forceinline__ ushort bfbits(float v){
  bf16 b = __float2bfloat16(v);
  return *(ushort*)&b;
}
__device__ __forceinline__ float bflo(uint u){ return __uint_as_float(u << 16); }
__device__ __forceinline__ float bfhi(uint u){ return __uint_as_float(u & 0xffff0000u); }

__global__ void k_zero(float* __restrict__ p, int n){
  int i = blockIdx.x*256 + threadIdx.x;
  if (i < n) p[i] = 0.f;
}

__global__ void k_tobf16(const float* __restrict__ src, ushort* __restrict__ dst, int n){
  int i = blockIdx.x*256 + threadIdx.x;
  if (i < n) dst[i] = bfbits(src[i]);
}

// ---------------- generic tiled transpose: src[R][C] -> dst[C][R]; R,C mult of 32; block(32,8)
__global__ void k_transpose(const float* __restrict__ src, float* __restrict__ dst, int R, int C){
  __shared__ float t[32][33];
  int c0 = blockIdx.x*32, r0 = blockIdx.y*32;
  int tx = threadIdx.x, ty = threadIdx.y;
  #pragma unroll
  for (int i = 0; i < 4; ++i)
    t[ty+8*i][tx] = src[(size_t)(r0+ty+8*i)*C + c0+tx];
  __syncthreads();
  #pragma unroll
  for (int i = 0; i < 4; ++i)
    dst[(size_t)(c0+ty+8*i)*R + r0+tx] = t[tx][ty+8*i];
}

// ---------------- LSTM weight pack
__global__ void k_w4prep(const float* __restrict__ Wih, const float* __restrict__ Whh,
                         float4* __restrict__ W4hh, float4* __restrict__ W4s){
  int k = blockIdx.x, j = threadIdx.x;
  float h0 = Whh[j*256+k],       float_h1 = Whh[(256+j)*256+k];
  float h2 = Whh[(512+j)*256+k], h3 = Whh[(768+j)*256+k];
  float i0 = Wih[j*256+k],       i1 = Wih[(256+j)*256+k];
  float i2 = Wih[(512+j)*256+k], i3 = Wih[(768+j)*256+k];
  W4hh[k*256+j] = make_float4(h0,float_h1,h2,h3);
  W4s [k*256+j] = make_float4(h0+i0, float_h1+i1, h2+i2, h3+i3);
}

__global__ void k_xgbias(const float* __restrict__ Wih, const float* __restrict__ b_ih,
                         const float* __restrict__ b_hh, const float* __restrict__ init_in,
                         float4* __restrict__ xg4, float4* __restrict__ bias4){
  int b = blockIdx.x, t = threadIdx.x;
  float v = init_in[t];
  float p0 = v * Wih[b*256 + t];
  float p1 = v * Wih[(256+b)*256 + t];
  float p2 = v * Wih[(512+b)*256 + t];
  float p3 = v * Wih[(768+b)*256 + t];
  #pragma unroll
  for (int o = 32; o; o >>= 1) {
    p0 += __shfl_xor(p0, o); p1 += __shfl_xor(p1, o);
    p2 += __shfl_xor(p2, o); p3 += __shfl_xor(p3, o);
  }
  __shared__ float4 red[4];
  int lane = t & 63, wid = t >> 6;
  if (lane == 0) red[wid] = make_float4(p0,p1,p2,p3);
  __syncthreads();
  if (t == 0) {
    float4 bi = make_float4(b_ih[b]+b_hh[b], b_ih[256+b]+b_hh[256+b],
                            b_ih[512+b]+b_hh[512+b], b_ih[768+b]+b_hh[768+b]);
    bias4[b] = bi;
    float4 a = bi;
    #pragma unroll
    for (int w = 0; w < 4; ++w) { a.x += red[w].x; a.y += red[w].y; a.z += red[w].z; a.w += red[w].w; }
    xg4[b] = a;
  }
}

__global__ __launch_bounds__(256) void k_h0c0(const float* __restrict__ zc, const float* __restrict__ zm,
                      const float* __restrict__ WhT, const float* __restrict__ WcT,
                      const float* __restrict__ b_h, const float* __restrict__ b_c,
                      float* __restrict__ h, float* __restrict__ c){
  __shared__ float zs[256];
  int b = blockIdx.x, j = threadIdx.x;
  zs[j] = (j < 128) ? zc[b*128 + j] : zm[b*128 + (j-128)];
  __syncthreads();
  float ah = b_h[j], ac = b_c[j];
  #pragma unroll 4
  for (int k = 0; k < 256; ++k) {
    float zv = zs[k];
    ah = fmaf(zv, WhT[k*256 + j], ah);
    ac = fmaf(zv, WcT[k*256 + j], ac);
  }
  h[b*256+j] = ah; c[b*256+j] = ac;
}

// ---------------- entire 20-step LSTM in one launch; block = batch row, h/c in regs
__global__ __launch_bounds__(256) void k_lstm_all(
    const float4* __restrict__ W4hh, const float4* __restrict__ W4s,
    const float4* __restrict__ xg4, const float4* __restrict__ bias4,
    const float* __restrict__ h0, const float* __restrict__ c0,
    float* __restrict__ outs){
  __shared__ float hs[256];
  int b = blockIdx.x, j = threadIdx.x;
  float hj = h0[b*256 + j];
  float cj = c0[b*256 + j];
  for (int t = 0; t < 20; ++t) {
    hs[j] = hj;
    __syncthreads();
    const float4* __restrict__ W = (t == 0) ? W4hh : W4s;
    float4 a = (t == 0) ? xg4[j] : bias4[j];
    #pragma unroll 16
    for (int k = 0; k < 256; ++k) {
      float4 w = W[k*256 + j];
      float hv = hs[k];
      a.x = fmaf(hv, w.x, a.x);
      a.y = fmaf(hv, w.y, a.y);
      a.z = fmaf(hv, w.z, a.z);
      a.w = fmaf(hv, w.w, a.w);
    }
    float ig = sig_f(a.x), fg = sig_f(a.y), gg = tanh_f(a.z), og = sig_f(a.w);
    cj = fmaf(fg, cj, ig*gg);
    hj = og * tanh_f(cj);
    outs[(b*20 + t)*256 + j] = hj;
    __syncthreads();
  }
}

// ---------------- ff = lrelu(outs@W_f^T + b_f) into featb[:,0:512] (bf16)
__global__ __launch_bounds__(256) void k_ff(const float* __restrict__ outs, const float* __restrict__ WfT,
                    const float* __restrict__ b_f, ushort* __restrict__ featb){
  __shared__ float rows[4][256];
  int r0 = blockIdx.x * 4, tid = threadIdx.x;
  #pragma unroll
  for (int i = 0; i < 4; ++i) rows[i][tid] = outs[(r0+i)*256 + tid];
  __syncthreads();
  #pragma unroll
  for (int half = 0; half < 2; ++half) {
    int j = tid + half*256;
    float bb = b_f[j];
    float a0 = bb, a1 = bb, a2 = bb, a3 = bb;
    #pragma unroll 4
    for (int k = 0; k < 256; ++k) {
      float w = WfT[k*512 + j];
      a0 = fmaf(rows[0][k], w, a0);
      a1 = fmaf(rows[1][k], w, a1);
      a2 = fmaf(rows[2][k], w, a2);
      a3 = fmaf(rows[3][k], w, a3);
    }
    featb[(r0+0)*640 + j] = bfbits(LRELU(a0));
    featb[(r0+1)*640 + j] = bfbits(LRELU(a1));
    featb[(r0+2)*640 + j] = bfbits(LRELU(a2));
    featb[(r0+3)*640 + j] = bfbits(LRELU(a3));
  }
}

__global__ void k_zc(const float* __restrict__ zc, ushort* __restrict__ featb){
  int e = blockIdx.x*256 + threadIdx.x;
  int r = e >> 7, c = e & 127;
  featb[r*640 + 512 + c] = bfbits(zc[(r/20)*128 + c]);
}

// ---------------- MFMA FC GEMM: C[1280][4096] = lrelu(A@W^T + bias), NHWC bf16 out
// A: featb [1280][640] bf16; W: wpfc [4096][640] bf16 (k-contig)
__global__ __launch_bounds__(256) void k_gemm_fc_m(
    const ushort* __restrict__ A, const ushort* __restrict__ W,
    const float* __restrict__ bias, ushort* __restrict__ C)
{
  constexpr int K = 640, BK = 64, NK = K/BK, BM = 128, BN = 64;
  constexpr int RS = 72;
  constexpr int NCF = BN/16;     // 4
  constexpr int AC = 4, WC = 2;  // 16B chunks per thread

  __shared__ __align__(16) ushort Al[2][BM*RS];
  __shared__ __align__(16) ushort Wl[2][BN*RS];

  const int tid = threadIdx.x;
  const int col0 = blockIdx.x * BN, row0 = blockIdx.y * BM;
  const int w = tid >> 6, l = tid & 63, lm = l & 15, lk = l >> 4;

  f32x4 acc[NCF][2];
  #pragma unroll
  for (int m = 0; m < NCF; ++m)
    #pragma unroll
    for (int s = 0; s < 2; ++s)
      acc[m][s] = (f32x4){0.f,0.f,0.f,0.f};

  uint4 ar[AC], wr[WC];

  #define LOADG(kt) { \
    _Pragma("unroll") \
    for (int i = 0; i < AC; ++i) { \
      int chunk = tid + i*256; \
      int rl = chunk >> 3, kc = chunk & 7; \
      ar[i] = *(const uint4*)&A[(size_t)(row0+rl)*K + (kt)*BK + kc*8]; \
    } \
    _Pragma("unroll") \
    for (int i = 0; i < WC; ++i) { \
      int chunk = tid + i*256; \
      int co = chunk >> 3, kc = chunk & 7; \
      wr[i] = *(const uint4*)&W[(size_t)(col0+co)*K + (kt)*BK + kc*8]; \
    } }

  #define STOREL(buf) { \
    _Pragma("unroll") \
    for (int i = 0; i < AC; ++i) { \
      int chunk = tid + i*256; \
      int rl = chunk >> 3, kc = chunk & 7; \
      *(uint4*)&Al[buf][rl*RS + kc*8] = ar[i]; \
    } \
    _Pragma("unroll") \
    for (int i = 0; i < WC; ++i) { \
      int chunk = tid + i*256; \
      int co = chunk >> 3, kc = chunk & 7; \
      *(uint4*)&Wl[buf][co*RS + kc*8] = wr[i]; \
    } }

  LOADG(0);
  STOREL(0);
  int cur = 0;
  for (int kt = 0; kt < NK; ++kt) {
    if (kt + 1 < NK) LOADG(kt + 1);
    __syncthreads();
    #pragma unroll
    for (int kf = 0; kf < 2; ++kf) {
      bf16x8 bfr[2];
      #pragma unroll
      for (int s = 0; s < 2; ++s)
        bfr[s] = *(bf16x8*)&Al[cur][(w*32 + s*16 + lm)*RS + kf*32 + lk*8];
      #pragma unroll
      for (int m = 0; m < NCF; ++m) {
        bf16x8 afr = *(bf16x8*)&Wl[cur][(m*16 + lm)*RS + kf*32 + lk*8];
        acc[m][0] = __builtin_amdgcn_mfma_f32_16x16x32_bf16(afr, bfr[0], acc[m][0], 0, 0, 0);
        acc[m][1] = __builtin_amdgcn_mfma_f32_16x16x32_bf16(afr, bfr[1], acc[m][1], 0, 0, 0);
      }
    }
    if (kt + 1 < NK) STOREL(cur ^ 1);
    cur ^= 1;
  }

  // epilogue: bias + lrelu + NHWC permute (u = co*16+s -> [(row*16+s)*256+co])
  #pragma unroll
  for (int m = 0; m < NCF; ++m) {
    #pragma unroll
    for (int s = 0; s < 2; ++s) {
      int row = row0 + w*32 + s*16 + lm;
      f32x4 v = acc[m][s];
      #pragma unroll
      for (int j = 0; j < 4; ++j) {
        int u = col0 + m*16 + lk*4 + j;
        float val = LRELU(v[j] + bias[u]);
        C[((size_t)row << 12) + ((size_t)(u & 15) << 8) + (u >> 4)] = bfbits(val);
      }
    }
  }
  #undef LOADG
  #undef STOREL
}

// ---------------- deconv weight prep: w[ci][co][ky][kx] f32 -> wp[p][co][t*CI+ci] bf16
template<int CI, int CO>
__global__ void k_wprep(const float* __restrict__ w, ushort* __restrict__ wp){
  int e = blockIdx.x*256 + threadIdx.x;     // total 16*CI*CO
  if (e >= 16*CI*CO) return;
  int ci = e % CI; int t1 = e / CI;
  int t = t1 & 3;  int t2 = t1 >> 2;
  int co = t2 % CO; int pp = t2 / CO;
  int py = pp >> 1, px = pp & 1, dy = t >> 1, dx = t & 1;
  int ky = (py ? 0 : 1) + 2*dy;
  int kx = (px ? 0 : 1) + 2*dx;
  wp[e] = bfbits(w[((ci*CO + co)*4 + ky)*4 + kx]);
}

__global__ void k_wfperm(const float* __restrict__ wf, float* __restrict__ wfT){
  int e = blockIdx.x*256 + threadIdx.x;
  if (e < 512) {
    int tap = e >> 5, ci = e & 31;
    wfT[tap*32 + ci] = wf[ci*16 + tap];
  }
}

// ---------------- MFMA parity-GEMM deconv (stage 0: deep K, spatial-tiled)
template<int CI, int CO, int HI>
__global__ __launch_bounds__(256) void k_dcv(
    const ushort* __restrict__ in, const ushort* __restrict__ wp,
    ushort* __restrict__ out, float* __restrict__ gsum, float* __restrict__ gsq)
{
  constexpr int WI = HI, HO = 2*HI, WO = 2*WI;
  constexpr int K = 4*CI, BK = 64, NK = K/BK;
  constexpr int BSP = 128;
  constexpr int RS = 72;
  constexpr int NCF = CO/16;
  constexpr int AC = BSP/32;
  constexpr int WC = CO/32;

  __shared__ __align__(16) ushort Al[2][BSP*RS];
  __shared__ __align__(16) ushort Wl[2][CO*RS];
  __shared__ float s_sum[CO], s_sq[CO];

  const int tid = threadIdx.x;
  const int sp0 = blockIdx.x * BSP;
  const int p  = blockIdx.y;
  const int py = p >> 1, px = p & 1;
  const int w  = tid >> 6, l = tid & 63;
  const int lm = l & 15, lk = l >> 4;

  if (tid < CO) { s_sum[tid] = 0.f; s_sq[tid] = 0.f; }

  f32x4 acc[NCF][2];
  #pragma unroll
  for (int m = 0; m < NCF; ++m)
    #pragma unroll
    for (int s = 0; s < 2; ++s)
      acc[m][s] = (f32x4){0.f,0.f,0.f,0.f};

  uint4 ar[AC], wr[WC];

  #define LOADT(kt) { \
    int t = ((kt)*BK)/CI, ci0 = ((kt)*BK)%CI; \
    int dy = t >> 1, dx = t & 1; \
    _Pragma("unroll") \
    for (int i = 0; i < AC; ++i) { \
      int chunk = tid + i*256; \
      int rl = chunk >> 3, kc = chunk & 7; \
      int r = sp0 + rl; \
      int n = r / (HI*WI), rem = r % (HI*WI); \
      int oy = rem / WI, ox = rem % WI; \
      int iy = oy + py - dy, ix = ox + px - dx; \
      if ((unsigned)iy < (unsigned)HI && (unsigned)ix < (unsigned)WI) \
        ar[i] = *(const uint4*)&in[((((size_t)n*HI + iy)*WI + ix)*CI) + ci0 + kc*8]; \
      else ar[i] = make_uint4(0,0,0,0); \
    } \
    _Pragma("unroll") \
    for (int i = 0; i < WC; ++i) { \
      int chunk = tid + i*256; \
      int co = chunk >> 3, kc = chunk & 7; \
      wr[i] = *(const uint4*)&wp[((size_t)p*CO + co)*K + (kt)*BK + kc*8]; \
    } }

  #define STORET(buf) { \
    _Pragma("unroll") \
    for (int i = 0; i < AC; ++i) { \
      int chunk = tid + i*256; \
      int rl = chunk >> 3, kc = chunk & 7; \
      *(uint4*)&Al[buf][rl*RS + kc*8] = ar[i]; \
    } \
    _Pragma("unroll") \
    for (int i = 0; i < WC; ++i) { \
      int chunk = tid + i*256; \
      int co = chunk >> 3, kc = chunk & 7; \
      *(uint4*)&Wl[buf][co*RS + kc*8] = wr[i]; \
    } }

  LOADT(0);
  STORET(0);
  int cur = 0;
  for (int kt = 0; kt < NK; ++kt) {
    if (kt + 1 < NK) LOADT(kt + 1);
    __syncthreads();
    #pragma unroll
    for (int kf = 0; kf < 2; ++kf) {
      bf16x8 bfr[2];
      #pragma unroll
      for (int s = 0; s < 2; ++s)
        bfr[s] = *(bf16x8*)&Al[cur][(w*32 + s*16 + lm)*RS + kf*32 + lk*8];
      #pragma unroll
      for (int m = 0; m < NCF; ++m) {
        bf16x8 afr = *(bf16x8*)&Wl[cur][(m*16 + lm)*RS + kf*32 + lk*8];
        acc[m][0] = __builtin_amdgcn_mfma_f32_16x16x32_bf16(afr, bfr[0], acc[m][0], 0, 0, 0);
        acc[m][1] = __builtin_amdgcn_mfma_f32_16x16x32_bf16(afr, bfr[1], acc[m][1], 0, 0, 0);
      }
    }
    if (kt + 1 < NK) STORET(cur ^ 1);
    cur ^= 1;
  }

  #pragma unroll
  for (int m = 0; m < NCF; ++m) {
    float s1[4] = {0,0,0,0}, s2[4] = {0,0,0,0};
    #pragma unroll
    for (int s = 0; s < 2; ++s) {
      f32x4 v = acc[m][s];
      int sp = sp0 + w*32 + s*16 + lm;
      int n = sp / (HI*WI), rem = sp % (HI*WI);
      int y = 2*(rem / WI) + py, x = 2*(rem % WI) + px;
      size_t ob = (((size_t)n*HO + y)*WO + x)*CO + m*16 + lk*4;
      union { ushort u[4]; uint2 q; } pk;
      #pragma unroll
      for (int j = 0; j < 4; ++j) {
        pk.u[j] = bfbits(v[j]);
        s1[j] += v[j];
        s2[j] += v[j]*v[j];
      }
      *(uint2*)&out[ob] = pk.q;
    }
    #pragma unroll
    for (int j = 0; j < 4; ++j) {
      float a = s1[j], b = s2[j];
      #pragma unroll
      for (int o = 1; o < 16; o <<= 1) { a += __shfl_xor(a, o); b += __shfl_xor(b, o); }
      if (lm == 0) {
        atomicAdd(&s_sum[m*16 + lk*4 + j], a);
        atomicAdd(&s_sq [m*16 + lk*4 + j], b);
      }
    }
  }
  __syncthreads();
  for (int cc = tid; cc < CO; cc += 256) {
    atomicAdd(&gsum[cc], s_sum[cc]);
    atomicAdd(&gsq[cc],  s_sq[cc]);
  }
  #undef LOADT
  #undef STORET
}

// ---------------- image-resident MFMA deconv (stages 1 & 2)
template<int CI, int CO, int HI>
__global__ __launch_bounds__(512) void k_dcvim(
    const ushort* __restrict__ in, const ushort* __restrict__ wp,
    const float* __restrict__ scale, const float* __restrict__ shift,
    ushort* __restrict__ out, float* __restrict__ gsum, float* __restrict__ gsq)
{
  constexpr int WI = HI, HO = 2*HI, WO = 2*WI;
  constexpr int K = 4*CI;
  constexpr int KF = K/32;
  constexpr int PAD = HI + 2;
  constexpr int CICH = CI/8;
  constexpr int AU4 = PAD*PAD*CICH;
  constexpr int SFT = HI*WI/16;
  constexpr int MMW = CO/32;

  __shared__ __align__(16) ushort Ain[PAD*PAD*CI];
  __shared__ float s_sum[CO], s_sq[CO];

  const int tid = threadIdx.x;
  const int n = blockIdx.x;
  const int w = tid >> 6, l = tid & 63, lm = l & 15, lk = l >> 4;
  const int p = w >> 1, py = p >> 1, px = p & 1, mh = w & 1;

  if (tid < CO) { s_sum[tid] = 0.f; s_sq[tid] = 0.f; }

  uint4 zz = make_uint4(0,0,0,0);
  for (int i = tid; i < AU4; i += 512) ((uint4*)Ain)[i] = zz;
  __syncthreads();

  const ushort* inb = in + (size_t)n * HI * WI * CI;
  constexpr int NCHK = HI*WI*CICH;
  for (int e = tid; e < NCHK; e += 512) {
    int ci8 = e % CICH; int sp = e / CICH;
    int ix = sp % WI, iy = sp / WI;
    uint4 u = *(const uint4*)&inb[(size_t)sp*CI + ci8*8];
    int ci0 = ci8*8;
    float4 sc0 = *(const float4*)&scale[ci0];
    float4 sc1 = *(const float4*)&scale[ci0+4];
    float4 sh0 = *(const float4*)&shift[ci0];
    float4 sh1 = *(const float4*)&shift[ci0+4];
    float v0 = LRELU(fmaf(bflo(u.x), sc0.x, sh0.x));
    float v1 = LRELU(fmaf(bfhi(u.x), sc0.y, sh0.y));
    float v2 = LRELU(fmaf(bflo(u.y), sc0.z, sh0.z));
    float v3 = LRELU(fmaf(bfhi(u.y), sc0.w, sh0.w));
    float v4 = LRELU(fmaf(bflo(u.z), sc1.x, sh1.x));
    float v5 = LRELU(fmaf(bfhi(u.z), sc1.y, sh1.y));
    float v6 = LRELU(fmaf(bflo(u.w), sc1.z, sh1.z));
    float v7 = LRELU(fmaf(bfhi(u.w), sc1.w, sh1.w));
    uint4 o;
    o.x = (uint)bfbits(v0) | ((uint)bfbits(v1) << 16);
    o.y = (uint)bfbits(v2) | ((uint)bfbits(v3) << 16);
    o.z = (uint)bfbits(v4) | ((uint)bfbits(v5) << 16);
    o.w = (uint)bfbits(v6) | ((uint)bfbits(v7) << 16);
    int r = iy + 1, c = ix + 1;
    int chS = ci8 ^ (c & 7);
    ((uint4*)Ain)[(r*PAD + c)*CICH + chS] = o;
  }
  __syncthreads();

  f32x4 acc[MMW][SFT];
  #pragma unroll
  for (int m = 0; m < MMW; ++m)
    #pragma unroll
    for (int sf = 0; sf < SFT; ++sf)
      acc[m][sf] = (f32x4){0.f,0.f,0.f,0.f};

  const ushort* wpb = wp + ((size_t)p*CO + mh*(CO/2))*K;
  #pragma unroll
  for (int kf = 0; kf < KF; ++kf) {
    const int t = (kf*32)/CI, cib = (kf*32)%CI;
    const int dy = t >> 1, dx = t & 1;
    bf16x8 afr[MMW];
    #pragma unroll
    for (int m = 0; m < MMW; ++m)
      afr[m] = *(const bf16x8*)&wpb[(size_t)(m*16 + lm)*K + kf*32 + lk*8];
    const int ch = (cib >> 3) + lk;
    #pragma unroll
    for (int sf = 0; sf < SFT; ++sf) {
      int s = sf*16 + lm;
      int y = s / WI, x = s % WI;
      int r = y + py - dy + 1, c = x + px - dx + 1;
      bf16x8 bfr = *(const bf16x8*)&Ain[((r*PAD + c)*CICH + (ch ^ (c & 7)))*8];
      #pragma unroll
      for (int m = 0; m < MMW; ++m)
        acc[m][sf] = __builtin_amdgcn_mfma_f32_16x16x32_bf16(afr[m], bfr, acc[m][sf], 0, 0, 0);
    }
  }

  #pragma unroll
  for (int m = 0; m < MMW; ++m) {
    int co0 = mh*(CO/2) + m*16 + lk*4;
    float s1[4] = {0,0,0,0}, s2[4] = {0,0,0,0};
    #pragma unroll
    for (int sf = 0; sf < SFT; ++sf) {
      f32x4 v = acc[m][sf];
      int s = sf*16 + lm;
      int y = 2*(s / WI) + py, x = 2*(s % WI) + px;
      size_t ob = (((size_t)n*HO + y)*WO + x)*CO + co0;
      union { ushort u[4]; uint2 q; } pk;
      #pragma unroll
      for (int j = 0; j < 4; ++j) {
        pk.u[j] = bfbits(v[j]);
        s1[j] += v[j];
        s2[j] += v[j]*v[j];
      }
      *(uint2*)&out[ob] = pk.q;
    }
    #pragma unroll
    for (int j = 0; j < 4; ++j) {
      float a = s1[j], b = s2[j];
      #pragma unroll
      for (int o = 1; o < 16; o <<= 1) { a += __shfl_xor(a, o); b += __shfl_xor(b, o); }
      if (lm == 0) {
        atomicAdd(&s_sum[co0 + j], a);
        atomicAdd(&s_sq [co0 + j], b);
      }
    }
  }
  __syncthreads();
  for (int cc = tid; cc < CO; cc += 512) {
    atomicAdd(&gsum[cc], s_sum[cc]);
    atomicAdd(&gsq[cc],  s_sq[cc]);
  }
}

// ---------------- BN finalize
__global__ void k_bnfin(const float* __restrict__ sum, const float* __restrict__ sq,
                        const float* __restrict__ g, const float* __restrict__ be,
                        float* __restrict__ scale, float* __restrict__ shift,
                        int CO, float invN){
  int c = threadIdx.x;
  if (c >= CO) return;
  float m = sum[c]*invN;
  float v = sq[c]*invN - m*m;
  float sc = g[c]*rsqrtf(v + 1e-5f);
  scale[c] = sc;
  shift[c] = be[c] - m*sc;
}

// ---------------- final deconv 32->1 + sigmoid. bf16 LDS stage (BN fused), wave=parity,
// weights wave-uniform (scalar loads). SPLIT=8 -> 13.9KB LDS -> 8 blocks/CU.
__global__ __launch_bounds__(256) void k_final(
    const ushort* __restrict__ in, const float* __restrict__ wfo,
    const float* __restrict__ scale, const float* __restrict__ shift,
    const float* __restrict__ bfb, float* __restrict__ outp)
{
  constexpr int CI=32, HI=32, WI=32, HO=64, WO=64, SPLIT=8, HOq=HO/SPLIT; // 8 out rows
  constexpr int ROWW = 32*36 + 8;      // ushort stride per input row (bank skew)
  __shared__ __align__(8) ushort As[6 * ROWW];

  const int tid = threadIdx.x, bid = blockIdx.x;
  const int n = bid / SPLIT, q = bid % SPLIT;
  const int y0 = q * HOq;
  const int rows_lo = max(0, y0/2 - 1);
  const int rows_hi = min(HI-1, (y0 + HOq)/2);
  const int nrows = rows_hi - rows_lo + 1;

  const ushort* inb = in + (size_t)n * HI * WI * CI;
  const int NC = nrows * WI * (CI/4);      // uint2 chunks
  for (int e = tid; e < NC; e += 256) {
    int c2 = e & 7;
    int sp = e >> 3;
    int rl = sp >> 5, ix = sp & 31;
    uint2 u = *(const uint2*)&inb[(((rows_lo + rl)*WI + ix)*CI) + c2*4];
    float4 sc = *(const float4*)&scale[c2*4];
    float4 sh = *(const float4*)&shift[c2*4];
    float v0 = LRELU(fmaf(bflo(u.x), sc.x, sh.x));
    float v1 = LRELU(fmaf(bfhi(u.x), sc.y, sh.y));
    float v2 = LRELU(fmaf(bflo(u.y), sc.z, sh.z));
    float v3 = LRELU(fmaf(bfhi(u.y), sc.w, sh.w));
    uint2 o;
    o.x = (uint)bfbits(v0) | ((uint)bfbits(v1) << 16);
    o.y = (uint)bfbits(v2) | ((uint)bfbits(v3) << 16);
    *(uint2*)&As[rl*ROWW + ix*36 + c2*4] = o;
  }
  __syncthreads();

  const int w = tid >> 6, l = tid & 63;
  const int py = w >> 1, px = w & 1;
  const int ky0 = 1 - py, kx0 = 1 - px;    // valid taps: ky0, ky0+2 (parity of y+1)
  const float b0 = bfb[0];
  const int xi = l & 31;
  const int x = 2*xi + px;

  for (int rowi = (l >> 5); rowi < 4; rowi += 2) {
    int y = y0 + 2*rowi + py;
    float acc = b0;
    #pragma unroll
    for (int t = 0; t < 4; ++t) {
      int ky = ky0 + 2*(t >> 1), kx = kx0 + 2*(t & 1);
      int iy = (y + 1 - ky) >> 1, ix = (x + 1 - kx) >> 1;
      if (iy < 0 || iy >= HI || ix < 0 || ix >= WI) continue;
      const float* __restrict__ wv = &wfo[(ky*4 + kx)*CI];
      const ushort* __restrict__ arow = &As[(iy - rows_lo)*ROWW + ix*36];
      #pragma unroll
      for (int c2 = 0; c2 < 8; ++c2) {
        uint2 v = *(const uint2*)&arow[c2*4];
        acc = fmaf(bflo(v.x), wv[c2*4+0], acc);
        acc = fmaf(bfhi(v.x), wv[c2*4+1], acc);
        acc = fmaf(bflo(v.y), wv[c2*4+2], acc);
        acc = fmaf(bfhi(v.y), wv[c2*4+3], acc);
      }
    }
    outp[(size_t)n*HO*WO + y*WO + x] = 1.f/(1.f + __expf(-acc));
  }
}

extern "C" void kernel_launch(void* const* d_in, const int* in_sizes, int n_in,
                              void* d_out, int out_size, void* d_ws, size_t ws_size,
                              hipStream_t stream) {
  const float* z_content = (const float*)d_in[0];
  const float* z_motion  = (const float*)d_in[1];
  const float* W_h  = (const float*)d_in[2];
  const float* b_h  = (const float*)d_in[3];
  const float* W_c  = (const float*)d_in[4];
  const float* b_c  = (const float*)d_in[5];
  const float* W_ih = (const float*)d_in[6];
  const float* W_hh = (const float*)d_in[7];
  const float* b_ih = (const float*)d_in[8];
  const float* b_hh = (const float*)d_in[9];
  const float* W_f  = (const float*)d_in[10];
  const float* b_f  = (const float*)d_in[11];
  const float* init_in = (const float*)d_in[12];
  const float* fc_W = (const float*)d_in[13];
  const float* fc_b = (const float*)d_in[14];
  const float* w0 = (const float*)d_in[15];
  const float* g0 = (const float*)d_in[16];
  const float* be0 = (const float*)d_in[17];
  const float* w1 = (const float*)d_in[18];
  const float* g1 = (const float*)d_in[19];
  const float* be1 = (const float*)d_in[20];
  const float* w2 = (const float*)d_in[21];
  const float* g2 = (const float*)d_in[22];
  const float* be2 = (const float*)d_in[23];
  const float* wf = (const float*)d_in[24];
  const float* bf_ = (const float*)d_in[25];

  const size_t P_BYTES = 10631168;
  const size_t X_OFF   = P_BYTES;
  const size_t X_BYTES = 83886080;
  const size_t Y_OFF   = X_OFF + X_BYTES;
  const size_t NEED    = Y_OFF + 41943040;
  if (ws_size < NEED) return;

  float* ws = (float*)d_ws;
  char*  wsb = (char*)d_ws;
  float* sum0 = ws + 0;        float* sq0 = ws + 128;
  float* sum1 = ws + 256;      float* sq1 = ws + 320;
  float* sum2 = ws + 384;      float* sq2 = ws + 416;
  float* scale0 = ws + 512;    float* shift0 = ws + 640;
  float* scale1 = ws + 768;    float* shift1 = ws + 832;
  float* scale2 = ws + 896;    float* shift2 = ws + 928;
  float4* xg4   = (float4*)(ws + 1024);
  float4* bias4 = (float4*)(ws + 2048);
  float* h    = ws + 3072;
  float* c    = ws + 19456;
  float* outs = ws + 35840;
  float* WhT  = ws + 363520;
  float* WcT  = ws + 429056;
  float* WfT  = ws + 494592;
  float4* W4hh = (float4*)(ws + 625664);
  float4* W4s  = (float4*)(ws + 887808);
  ushort* wp0 = (ushort*)(ws + 1149952);   // 524288 bf16
  ushort* wp1 = (ushort*)(ws + 1412096);   // 131072 bf16
  ushort* wp2 = (ushort*)(ws + 1477632);   // 32768 bf16
  float* wfT  = ws + 1494016;              // 512 f32
  ushort* featb = (ushort*)(ws + 1494528); // 819200 bf16 (1.6MB)

  ushort* wpfc = (ushort*)(wsb + X_OFF);   // 2,621,440 bf16 (5.2MB, dead after gemm)
  ushort* out0 = (ushort*)(wsb + X_OFF);   // NHWC bf16 [1280][8][8][128]
  ushort* out2 = (ushort*)(wsb + X_OFF);   // NHWC bf16 [1280][32][32][32]
  ushort* h1   = (ushort*)(wsb + Y_OFF);   // NHWC bf16 [1280][4][4][256]
  ushort* out1 = (ushort*)(wsb + Y_OFF);   // NHWC bf16 [1280][16][16][64]

  k_zero<<<2, 256, 0, stream>>>(ws, 448);

  dim3 tb(32,8);
  k_transpose<<<dim3(8,8),   tb, 0, stream>>>(W_h,  WhT, 256, 256);
  k_transpose<<<dim3(8,8),   tb, 0, stream>>>(W_c,  WcT, 256, 256);
  k_transpose<<<dim3(8,16),  tb, 0, stream>>>(W_f,  WfT, 512, 256);
  k_tobf16<<<10240, 256, 0, stream>>>(fc_W, wpfc, 2621440);
  k_w4prep<<<256, 256, 0, stream>>>(W_ih, W_hh, W4hh, W4s);
  k_xgbias<<<256, 256, 0, stream>>>(W_ih, b_ih, b_hh, init_in, xg4, bias4);
  k_h0c0<<<64, 256, 0, stream>>>(z_content, z_motion, WhT, WcT, b_h, b_c, h, c);
  k_wprep<256,128><<<2048, 256, 0, stream>>>(w0, wp0);
  k_wprep<128,64><<<512, 256, 0, stream>>>(w1, wp1);
  k_wprep<64,32><<<128, 256, 0, stream>>>(w2, wp2);
  k_wfperm<<<2, 256, 0, stream>>>(wf, wfT);

  // ---- whole LSTM in one launch
  k_lstm_all<<<64, 256, 0, stream>>>(W4hh, W4s, xg4, bias4, h, c, outs);

  k_ff<<<320, 256, 0, stream>>>(outs, WfT, b_f, featb);
  k_zc<<<640, 256, 0, stream>>>(z_content, featb);
  k_gemm_fc_m<<<dim3(64, 10), 256, 0, stream>>>(featb, wpfc, fc_b, h1);

  // ---- deconv pipeline
  k_dcv<256,128,4><<<dim3(160,4), 256, 0, stream>>>(h1, wp0, out0, sum0, sq0);
  k_bnfin<<<1, 128, 0, stream>>>(sum0, sq0, g0, be0, scale0, shift0, 128, 1.f/81920.f);
  k_dcvim<128,64,8><<<1280, 512, 0, stream>>>(out0, wp1, scale0, shift0, out1, sum1, sq1);
  k_bnfin<<<1, 64, 0, stream>>>(sum1, sq1, g1, be1, scale1, shift1, 64, 1.f/327680.f);
  k_dcvim<64,32,16><<<1280, 512, 0, stream>>>(out1, wp2, scale1, shift1, out2, sum2, sq2);
  k_bnfin<<<1, 32, 0, stream>>>(sum2, sq2, g2, be2, scale2, shift2, 32, 1.f/1310720.f);
  k_final<<<10240, 256, 0, stream>>>(out2, wfT, scale2, shift2, bf_, (float*)d_out);
}

// Round 6
// 649.908 us; speedup vs baseline: 11.3772x; 1.0561x over previous
//
#include <hip/hip_runtime.h>
#include <hip/hip_bf16.h>
#include <math.h>

typedef __hip_bfloat16 bf16;
typedef __attribute__((ext_vector_type(8))) short bf16x8;
typedef __attribute__((ext_vector_type(4))) float f32x4;

#define LRELU(v) ((v) > 0.f ? (v) : 0.2f*(v))

__device__ __forceinline__ float sig_f(float x){ return 1.f/(1.f + __expf(-x)); }
__device__ __forceinline__ float tanh_f(float x){
  float ax = fabsf(x);
  float e = __expf(-2.f*ax);
  float t = (1.f - e)/(1.f + e);
  return x >= 0.f ? t : -t;
}
__device__ __forceinline__ ushort bfbits(float v){
  bf16 b = __float2bfloat16(v);
  return *(ushort*)&b;
}
__device__ __forceinline__ float bflo(uint u){ return __uint_as_float(u << 16); }
__device__ __forceinline__ float bfhi(uint u){ return __uint_as_float(u & 0xffff0000u); }

__global__ void k_zero(float* __restrict__ p, int n){
  int i = blockIdx.x*256 + threadIdx.x;
  if (i < n) p[i] = 0.f;
}

__global__ void k_tobf16(const float* __restrict__ src, ushort* __restrict__ dst, int n){
  int i = blockIdx.x*256 + threadIdx.x;
  if (i < n) dst[i] = bfbits(src[i]);
}

// ---------------- generic tiled transpose: src[R][C] -> dst[C][R]; R,C mult of 32; block(32,8)
__global__ void k_transpose(const float* __restrict__ src, float* __restrict__ dst, int R, int C){
  __shared__ float t[32][33];
  int c0 = blockIdx.x*32, r0 = blockIdx.y*32;
  int tx = threadIdx.x, ty = threadIdx.y;
  #pragma unroll
  for (int i = 0; i < 4; ++i)
    t[ty+8*i][tx] = src[(size_t)(r0+ty+8*i)*C + c0+tx];
  __syncthreads();
  #pragma unroll
  for (int i = 0; i < 4; ++i)
    dst[(size_t)(c0+ty+8*i)*R + r0+tx] = t[tx][ty+8*i];
}

// ---------------- LSTM weight pack
__global__ void k_w4prep(const float* __restrict__ Wih, const float* __restrict__ Whh,
                         float4* __restrict__ W4hh, float4* __restrict__ W4s){
  int k = blockIdx.x, j = threadIdx.x;
  float h0 = Whh[j*256+k],       float_h1 = Whh[(256+j)*256+k];
  float h2 = Whh[(512+j)*256+k], h3 = Whh[(768+j)*256+k];
  float i0 = Wih[j*256+k],       i1 = Wih[(256+j)*256+k];
  float i2 = Wih[(512+j)*256+k], i3 = Wih[(768+j)*256+k];
  W4hh[k*256+j] = make_float4(h0,float_h1,h2,h3);
  W4s [k*256+j] = make_float4(h0+i0, float_h1+i1, h2+i2, h3+i3);
}

__global__ void k_xgbias(const float* __restrict__ Wih, const float* __restrict__ b_ih,
                         const float* __restrict__ b_hh, const float* __restrict__ init_in,
                         float4* __restrict__ xg4, float4* __restrict__ bias4){
  int b = blockIdx.x, t = threadIdx.x;
  float v = init_in[t];
  float p0 = v * Wih[b*256 + t];
  float p1 = v * Wih[(256+b)*256 + t];
  float p2 = v * Wih[(512+b)*256 + t];
  float p3 = v * Wih[(768+b)*256 + t];
  #pragma unroll
  for (int o = 32; o; o >>= 1) {
    p0 += __shfl_xor(p0, o); p1 += __shfl_xor(p1, o);
    p2 += __shfl_xor(p2, o); p3 += __shfl_xor(p3, o);
  }
  __shared__ float4 red[4];
  int lane = t & 63, wid = t >> 6;
  if (lane == 0) red[wid] = make_float4(p0,p1,p2,p3);
  __syncthreads();
  if (t == 0) {
    float4 bi = make_float4(b_ih[b]+b_hh[b], b_ih[256+b]+b_hh[256+b],
                            b_ih[512+b]+b_hh[512+b], b_ih[768+b]+b_hh[768+b]);
    bias4[b] = bi;
    float4 a = bi;
    #pragma unroll
    for (int w = 0; w < 4; ++w) { a.x += red[w].x; a.y += red[w].y; a.z += red[w].z; a.w += red[w].w; }
    xg4[b] = a;
  }
}

__global__ __launch_bounds__(256) void k_h0c0(const float* __restrict__ zc, const float* __restrict__ zm,
                      const float* __restrict__ WhT, const float* __restrict__ WcT,
                      const float* __restrict__ b_h, const float* __restrict__ b_c,
                      float* __restrict__ h, float* __restrict__ c){
  __shared__ float zs[256];
  int b = blockIdx.x, j = threadIdx.x;
  zs[j] = (j < 128) ? zc[b*128 + j] : zm[b*128 + (j-128)];
  __syncthreads();
  float ah = b_h[j], ac = b_c[j];
  #pragma unroll 4
  for (int k = 0; k < 256; ++k) {
    float zv = zs[k];
    ah = fmaf(zv, WhT[k*256 + j], ah);
    ac = fmaf(zv, WcT[k*256 + j], ac);
  }
  h[b*256+j] = ah; c[b*256+j] = ac;
}

// ---------------- entire 20-step LSTM in one launch; block = batch row,
// 1024 threads: thread (j = tid&255, kq = tid>>8) 4-way K-split for latency hiding.
// outs written directly as bf16.
__global__ __launch_bounds__(1024) void k_lstm_all(
    const float4* __restrict__ W4hh, const float4* __restrict__ W4s,
    const float4* __restrict__ xg4, const float4* __restrict__ bias4,
    const float* __restrict__ h0, const float* __restrict__ c0,
    ushort* __restrict__ outsb){
  __shared__ float hs[256];
  __shared__ float4 part[3][256];
  const int b = blockIdx.x, tid = threadIdx.x;
  const int j = tid & 255, kq = tid >> 8;
  float cj = 0.f;
  if (kq == 0) { hs[j] = h0[b*256 + j]; cj = c0[b*256 + j]; }
  __syncthreads();
  for (int t = 0; t < 20; ++t) {
    const float4* __restrict__ W = (t == 0) ? W4hh : W4s;
    const float4* __restrict__ Wp = W + (size_t)(kq*64)*256 + j;
    float4 a = make_float4(0.f, 0.f, 0.f, 0.f);
    #pragma unroll 16
    for (int kk = 0; kk < 64; ++kk) {
      float4 w = Wp[(size_t)kk*256];
      float hv = hs[kq*64 + kk];
      a.x = fmaf(hv, w.x, a.x);
      a.y = fmaf(hv, w.y, a.y);
      a.z = fmaf(hv, w.z, a.z);
      a.w = fmaf(hv, w.w, a.w);
    }
    if (kq) part[kq-1][j] = a;
    __syncthreads();
    if (kq == 0) {
      float4 p1 = part[0][j], p2 = part[1][j], p3 = part[2][j];
      float4 bb = (t == 0) ? xg4[j] : bias4[j];
      a.x += p1.x + p2.x + p3.x + bb.x;
      a.y += p1.y + p2.y + p3.y + bb.y;
      a.z += p1.z + p2.z + p3.z + bb.z;
      a.w += p1.w + p2.w + p3.w + bb.w;
      float ig = sig_f(a.x), fg = sig_f(a.y), gg = tanh_f(a.z), og = sig_f(a.w);
      cj = fmaf(fg, cj, ig*gg);
      float hj = og * tanh_f(cj);
      outsb[(b*20 + t)*256 + j] = bfbits(hj);
      hs[j] = hj;
    }
    __syncthreads();
  }
}

__global__ void k_zc(const float* __restrict__ zc, ushort* __restrict__ featb){
  int e = blockIdx.x*256 + threadIdx.x;
  int r = e >> 7, c = e & 127;
  featb[r*640 + 512 + c] = bfbits(zc[(r/20)*128 + c]);
}

// ---------------- MFMA ff GEMM: featb[1280][0:512] = lrelu(outsb[1280][256] @ wpff^T + b_f)
__global__ __launch_bounds__(256) void k_ff_m(
    const ushort* __restrict__ A, const ushort* __restrict__ W,
    const float* __restrict__ bias, ushort* __restrict__ C)
{
  constexpr int K = 256, BK = 64, NK = K/BK, BM = 128, BN = 64;
  constexpr int RS = 72;
  constexpr int NCF = BN/16;
  constexpr int AC = 4, WC = 2;

  __shared__ __align__(16) ushort Al[2][BM*RS];
  __shared__ __align__(16) ushort Wl[2][BN*RS];

  const int tid = threadIdx.x;
  const int col0 = blockIdx.x * BN, row0 = blockIdx.y * BM;
  const int w = tid >> 6, l = tid & 63, lm = l & 15, lk = l >> 4;

  f32x4 acc[NCF][2];
  #pragma unroll
  for (int m = 0; m < NCF; ++m)
    #pragma unroll
    for (int s = 0; s < 2; ++s)
      acc[m][s] = (f32x4){0.f,0.f,0.f,0.f};

  uint4 ar[AC], wr[WC];

  #define LOADG(kt) { \
    _Pragma("unroll") \
    for (int i = 0; i < AC; ++i) { \
      int chunk = tid + i*256; \
      int rl = chunk >> 3, kc = chunk & 7; \
      ar[i] = *(const uint4*)&A[(size_t)(row0+rl)*K + (kt)*BK + kc*8]; \
    } \
    _Pragma("unroll") \
    for (int i = 0; i < WC; ++i) { \
      int chunk = tid + i*256; \
      int co = chunk >> 3, kc = chunk & 7; \
      wr[i] = *(const uint4*)&W[(size_t)(col0+co)*K + (kt)*BK + kc*8]; \
    } }

  #define STOREL(buf) { \
    _Pragma("unroll") \
    for (int i = 0; i < AC; ++i) { \
      int chunk = tid + i*256; \
      int rl = chunk >> 3, kc = chunk & 7; \
      *(uint4*)&Al[buf][rl*RS + kc*8] = ar[i]; \
    } \
    _Pragma("unroll") \
    for (int i = 0; i < WC; ++i) { \
      int chunk = tid + i*256; \
      int co = chunk >> 3, kc = chunk & 7; \
      *(uint4*)&Wl[buf][co*RS + kc*8] = wr[i]; \
    } }

  LOADG(0);
  STOREL(0);
  int cur = 0;
  for (int kt = 0; kt < NK; ++kt) {
    if (kt + 1 < NK) LOADG(kt + 1);
    __syncthreads();
    #pragma unroll
    for (int kf = 0; kf < 2; ++kf) {
      bf16x8 bfr[2];
      #pragma unroll
      for (int s = 0; s < 2; ++s)
        bfr[s] = *(bf16x8*)&Al[cur][(w*32 + s*16 + lm)*RS + kf*32 + lk*8];
      #pragma unroll
      for (int m = 0; m < NCF; ++m) {
        bf16x8 afr = *(bf16x8*)&Wl[cur][(m*16 + lm)*RS + kf*32 + lk*8];
        acc[m][0] = __builtin_amdgcn_mfma_f32_16x16x32_bf16(afr, bfr[0], acc[m][0], 0, 0, 0);
        acc[m][1] = __builtin_amdgcn_mfma_f32_16x16x32_bf16(afr, bfr[1], acc[m][1], 0, 0, 0);
      }
    }
    if (kt + 1 < NK) STOREL(cur ^ 1);
    cur ^= 1;
  }

  #pragma unroll
  for (int m = 0; m < NCF; ++m) {
    #pragma unroll
    for (int s = 0; s < 2; ++s) {
      int row = row0 + w*32 + s*16 + lm;
      f32x4 v = acc[m][s];
      int u0 = col0 + m*16 + lk*4;
      union { ushort u[4]; uint2 q; } pk;
      #pragma unroll
      for (int j = 0; j < 4; ++j)
        pk.u[j] = bfbits(LRELU(v[j] + bias[u0+j]));
      *(uint2*)&C[(size_t)row*640 + u0] = pk.q;
    }
  }
  #undef LOADG
  #undef STOREL
}

// ---------------- MFMA FC GEMM: C[1280][4096] = lrelu(A@W^T + bias), NHWC bf16 out
__global__ __launch_bounds__(256) void k_gemm_fc_m(
    const ushort* __restrict__ A, const ushort* __restrict__ W,
    const float* __restrict__ bias, ushort* __restrict__ C)
{
  constexpr int K = 640, BK = 64, NK = K/BK, BM = 128, BN = 64;
  constexpr int RS = 72;
  constexpr int NCF = BN/16;
  constexpr int AC = 4, WC = 2;

  __shared__ __align__(16) ushort Al[2][BM*RS];
  __shared__ __align__(16) ushort Wl[2][BN*RS];

  const int tid = threadIdx.x;
  const int col0 = blockIdx.x * BN, row0 = blockIdx.y * BM;
  const int w = tid >> 6, l = tid & 63, lm = l & 15, lk = l >> 4;

  f32x4 acc[NCF][2];
  #pragma unroll
  for (int m = 0; m < NCF; ++m)
    #pragma unroll
    for (int s = 0; s < 2; ++s)
      acc[m][s] = (f32x4){0.f,0.f,0.f,0.f};

  uint4 ar[AC], wr[WC];

  #define LOADG(kt) { \
    _Pragma("unroll") \
    for (int i = 0; i < AC; ++i) { \
      int chunk = tid + i*256; \
      int rl = chunk >> 3, kc = chunk & 7; \
      ar[i] = *(const uint4*)&A[(size_t)(row0+rl)*K + (kt)*BK + kc*8]; \
    } \
    _Pragma("unroll") \
    for (int i = 0; i < WC; ++i) { \
      int chunk = tid + i*256; \
      int co = chunk >> 3, kc = chunk & 7; \
      wr[i] = *(const uint4*)&W[(size_t)(col0+co)*K + (kt)*BK + kc*8]; \
    } }

  #define STOREL(buf) { \
    _Pragma("unroll") \
    for (int i = 0; i < AC; ++i) { \
      int chunk = tid + i*256; \
      int rl = chunk >> 3, kc = chunk & 7; \
      *(uint4*)&Al[buf][rl*RS + kc*8] = ar[i]; \
    } \
    _Pragma("unroll") \
    for (int i = 0; i < WC; ++i) { \
      int chunk = tid + i*256; \
      int co = chunk >> 3, kc = chunk & 7; \
      *(uint4*)&Wl[buf][co*RS + kc*8] = wr[i]; \
    } }

  LOADG(0);
  STOREL(0);
  int cur = 0;
  for (int kt = 0; kt < NK; ++kt) {
    if (kt + 1 < NK) LOADG(kt + 1);
    __syncthreads();
    #pragma unroll
    for (int kf = 0; kf < 2; ++kf) {
      bf16x8 bfr[2];
      #pragma unroll
      for (int s = 0; s < 2; ++s)
        bfr[s] = *(bf16x8*)&Al[cur][(w*32 + s*16 + lm)*RS + kf*32 + lk*8];
      #pragma unroll
      for (int m = 0; m < NCF; ++m) {
        bf16x8 afr = *(bf16x8*)&Wl[cur][(m*16 + lm)*RS + kf*32 + lk*8];
        acc[m][0] = __builtin_amdgcn_mfma_f32_16x16x32_bf16(afr, bfr[0], acc[m][0], 0, 0, 0);
        acc[m][1] = __builtin_amdgcn_mfma_f32_16x16x32_bf16(afr, bfr[1], acc[m][1], 0, 0, 0);
      }
    }
    if (kt + 1 < NK) STOREL(cur ^ 1);
    cur ^= 1;
  }

  #pragma unroll
  for (int m = 0; m < NCF; ++m) {
    #pragma unroll
    for (int s = 0; s < 2; ++s) {
      int row = row0 + w*32 + s*16 + lm;
      f32x4 v = acc[m][s];
      #pragma unroll
      for (int j = 0; j < 4; ++j) {
        int u = col0 + m*16 + lk*4 + j;
        float val = LRELU(v[j] + bias[u]);
        C[((size_t)row << 12) + ((size_t)(u & 15) << 8) + (u >> 4)] = bfbits(val);
      }
    }
  }
  #undef LOADG
  #undef STOREL
}

// ---------------- deconv weight prep: w[ci][co][ky][kx] f32 -> wp[p][co][t*CI+ci] bf16
template<int CI, int CO>
__global__ void k_wprep(const float* __restrict__ w, ushort* __restrict__ wp){
  int e = blockIdx.x*256 + threadIdx.x;
  if (e >= 16*CI*CO) return;
  int ci = e % CI; int t1 = e / CI;
  int t = t1 & 3;  int t2 = t1 >> 2;
  int co = t2 % CO; int pp = t2 / CO;
  int py = pp >> 1, px = pp & 1, dy = t >> 1, dx = t & 1;
  int ky = (py ? 0 : 1) + 2*dy;
  int kx = (px ? 0 : 1) + 2*dx;
  wp[e] = bfbits(w[((ci*CO + co)*4 + ky)*4 + kx]);
}

__global__ void k_wfperm(const float* __restrict__ wf, float* __restrict__ wfT){
  int e = blockIdx.x*256 + threadIdx.x;
  if (e < 512) {
    int tap = e >> 5, ci = e & 31;
    wfT[tap*32 + ci] = wf[ci*16 + tap];
  }
}

// ---------------- MFMA parity-GEMM deconv (stage 0: deep K, spatial-tiled)
template<int CI, int CO, int HI>
__global__ __launch_bounds__(256) void k_dcv(
    const ushort* __restrict__ in, const ushort* __restrict__ wp,
    ushort* __restrict__ out, float* __restrict__ gsum, float* __restrict__ gsq)
{
  constexpr int WI = HI, HO = 2*HI, WO = 2*WI;
  constexpr int K = 4*CI, BK = 64, NK = K/BK;
  constexpr int BSP = 128;
  constexpr int RS = 72;
  constexpr int NCF = CO/16;
  constexpr int AC = BSP/32;
  constexpr int WC = CO/32;

  __shared__ __align__(16) ushort Al[2][BSP*RS];
  __shared__ __align__(16) ushort Wl[2][CO*RS];
  __shared__ float s_sum[CO], s_sq[CO];

  const int tid = threadIdx.x;
  const int sp0 = blockIdx.x * BSP;
  const int p  = blockIdx.y;
  const int py = p >> 1, px = p & 1;
  const int w  = tid >> 6, l = tid & 63;
  const int lm = l & 15, lk = l >> 4;

  if (tid < CO) { s_sum[tid] = 0.f; s_sq[tid] = 0.f; }

  f32x4 acc[NCF][2];
  #pragma unroll
  for (int m = 0; m < NCF; ++m)
    #pragma unroll
    for (int s = 0; s < 2; ++s)
      acc[m][s] = (f32x4){0.f,0.f,0.f,0.f};

  uint4 ar[AC], wr[WC];

  #define LOADT(kt) { \
    int t = ((kt)*BK)/CI, ci0 = ((kt)*BK)%CI; \
    int dy = t >> 1, dx = t & 1; \
    _Pragma("unroll") \
    for (int i = 0; i < AC; ++i) { \
      int chunk = tid + i*256; \
      int rl = chunk >> 3, kc = chunk & 7; \
      int r = sp0 + rl; \
      int n = r / (HI*WI), rem = r % (HI*WI); \
      int oy = rem / WI, ox = rem % WI; \
      int iy = oy + py - dy, ix = ox + px - dx; \
      if ((unsigned)iy < (unsigned)HI && (unsigned)ix < (unsigned)WI) \
        ar[i] = *(const uint4*)&in[((((size_t)n*HI + iy)*WI + ix)*CI) + ci0 + kc*8]; \
      else ar[i] = make_uint4(0,0,0,0); \
    } \
    _Pragma("unroll") \
    for (int i = 0; i < WC; ++i) { \
      int chunk = tid + i*256; \
      int co = chunk >> 3, kc = chunk & 7; \
      wr[i] = *(const uint4*)&wp[((size_t)p*CO + co)*K + (kt)*BK + kc*8]; \
    } }

  #define STORET(buf) { \
    _Pragma("unroll") \
    for (int i = 0; i < AC; ++i) { \
      int chunk = tid + i*256; \
      int rl = chunk >> 3, kc = chunk & 7; \
      *(uint4*)&Al[buf][rl*RS + kc*8] = ar[i]; \
    } \
    _Pragma("unroll") \
    for (int i = 0; i < WC; ++i) { \
      int chunk = tid + i*256; \
      int co = chunk >> 3, kc = chunk & 7; \
      *(uint4*)&Wl[buf][co*RS + kc*8] = wr[i]; \
    } }

  LOADT(0);
  STORET(0);
  int cur = 0;
  for (int kt = 0; kt < NK; ++kt) {
    if (kt + 1 < NK) LOADT(kt + 1);
    __syncthreads();
    #pragma unroll
    for (int kf = 0; kf < 2; ++kf) {
      bf16x8 bfr[2];
      #pragma unroll
      for (int s = 0; s < 2; ++s)
        bfr[s] = *(bf16x8*)&Al[cur][(w*32 + s*16 + lm)*RS + kf*32 + lk*8];
      #pragma unroll
      for (int m = 0; m < NCF; ++m) {
        bf16x8 afr = *(bf16x8*)&Wl[cur][(m*16 + lm)*RS + kf*32 + lk*8];
        acc[m][0] = __builtin_amdgcn_mfma_f32_16x16x32_bf16(afr, bfr[0], acc[m][0], 0, 0, 0);
        acc[m][1] = __builtin_amdgcn_mfma_f32_16x16x32_bf16(afr, bfr[1], acc[m][1], 0, 0, 0);
      }
    }
    if (kt + 1 < NK) STORET(cur ^ 1);
    cur ^= 1;
  }

  #pragma unroll
  for (int m = 0; m < NCF; ++m) {
    float s1[4] = {0,0,0,0}, s2[4] = {0,0,0,0};
    #pragma unroll
    for (int s = 0; s < 2; ++s) {
      f32x4 v = acc[m][s];
      int sp = sp0 + w*32 + s*16 + lm;
      int n = sp / (HI*WI), rem = sp % (HI*WI);
      int y = 2*(rem / WI) + py, x = 2*(rem % WI) + px;
      size_t ob = (((size_t)n*HO + y)*WO + x)*CO + m*16 + lk*4;
      union { ushort u[4]; uint2 q; } pk;
      #pragma unroll
      for (int j = 0; j < 4; ++j) {
        pk.u[j] = bfbits(v[j]);
        s1[j] += v[j];
        s2[j] += v[j]*v[j];
      }
      *(uint2*)&out[ob] = pk.q;
    }
    #pragma unroll
    for (int j = 0; j < 4; ++j) {
      float a = s1[j], b = s2[j];
      #pragma unroll
      for (int o = 1; o < 16; o <<= 1) { a += __shfl_xor(a, o); b += __shfl_xor(b, o); }
      if (lm == 0) {
        atomicAdd(&s_sum[m*16 + lk*4 + j], a);
        atomicAdd(&s_sq [m*16 + lk*4 + j], b);
      }
    }
  }
  __syncthreads();
  for (int cc = tid; cc < CO; cc += 256) {
    atomicAdd(&gsum[cc], s_sum[cc]);
    atomicAdd(&gsq[cc],  s_sq[cc]);
  }
  #undef LOADT
  #undef STORET
}

// ---------------- image-resident MFMA deconv (stages 1 & 2)
template<int CI, int CO, int HI>
__global__ __launch_bounds__(512) void k_dcvim(
    const ushort* __restrict__ in, const ushort* __restrict__ wp,
    const float* __restrict__ scale, const float* __restrict__ shift,
    ushort* __restrict__ out, float* __restrict__ gsum, float* __restrict__ gsq)
{
  constexpr int WI = HI, HO = 2*HI, WO = 2*WI;
  constexpr int K = 4*CI;
  constexpr int KF = K/32;
  constexpr int PAD = HI + 2;
  constexpr int CICH = CI/8;
  constexpr int AU4 = PAD*PAD*CICH;
  constexpr int SFT = HI*WI/16;
  constexpr int MMW = CO/32;

  __shared__ __align__(16) ushort Ain[PAD*PAD*CI];
  __shared__ float s_sum[CO], s_sq[CO];

  const int tid = threadIdx.x;
  const int n = blockIdx.x;
  const int w = tid >> 6, l = tid & 63, lm = l & 15, lk = l >> 4;
  const int p = w >> 1, py = p >> 1, px = p & 1, mh = w & 1;

  if (tid < CO) { s_sum[tid] = 0.f; s_sq[tid] = 0.f; }

  uint4 zz = make_uint4(0,0,0,0);
  for (int i = tid; i < AU4; i += 512) ((uint4*)Ain)[i] = zz;
  __syncthreads();

  const ushort* inb = in + (size_t)n * HI * WI * CI;
  constexpr int NCHK = HI*WI*CICH;
  for (int e = tid; e < NCHK; e += 512) {
    int ci8 = e % CICH; int sp = e / CICH;
    int ix = sp % WI, iy = sp / WI;
    uint4 u = *(const uint4*)&inb[(size_t)sp*CI + ci8*8];
    int ci0 = ci8*8;
    float4 sc0 = *(const float4*)&scale[ci0];
    float4 sc1 = *(const float4*)&scale[ci0+4];
    float4 sh0 = *(const float4*)&shift[ci0];
    float4 sh1 = *(const float4*)&shift[ci0+4];
    float v0 = LRELU(fmaf(bflo(u.x), sc0.x, sh0.x));
    float v1 = LRELU(fmaf(bfhi(u.x), sc0.y, sh0.y));
    float v2 = LRELU(fmaf(bflo(u.y), sc0.z, sh0.z));
    float v3 = LRELU(fmaf(bfhi(u.y), sc0.w, sh0.w));
    float v4 = LRELU(fmaf(bflo(u.z), sc1.x, sh1.x));
    float v5 = LRELU(fmaf(bfhi(u.z), sc1.y, sh1.y));
    float v6 = LRELU(fmaf(bflo(u.w), sc1.z, sh1.z));
    float v7 = LRELU(fmaf(bfhi(u.w), sc1.w, sh1.w));
    uint4 o;
    o.x = (uint)bfbits(v0) | ((uint)bfbits(v1) << 16);
    o.y = (uint)bfbits(v2) | ((uint)bfbits(v3) << 16);
    o.z = (uint)bfbits(v4) | ((uint)bfbits(v5) << 16);
    o.w = (uint)bfbits(v6) | ((uint)bfbits(v7) << 16);
    int r = iy + 1, c = ix + 1;
    int chS = ci8 ^ (c & 7);
    ((uint4*)Ain)[(r*PAD + c)*CICH + chS] = o;
  }
  __syncthreads();

  f32x4 acc[MMW][SFT];
  #pragma unroll
  for (int m = 0; m < MMW; ++m)
    #pragma unroll
    for (int sf = 0; sf < SFT; ++sf)
      acc[m][sf] = (f32x4){0.f,0.f,0.f,0.f};

  const ushort* wpb = wp + ((size_t)p*CO + mh*(CO/2))*K;
  #pragma unroll
  for (int kf = 0; kf < KF; ++kf) {
    const int t = (kf*32)/CI, cib = (kf*32)%CI;
    const int dy = t >> 1, dx = t & 1;
    bf16x8 afr[MMW];
    #pragma unroll
    for (int m = 0; m < MMW; ++m)
      afr[m] = *(const bf16x8*)&wpb[(size_t)(m*16 + lm)*K + kf*32 + lk*8];
    const int ch = (cib >> 3) + lk;
    #pragma unroll
    for (int sf = 0; sf < SFT; ++sf) {
      int s = sf*16 + lm;
      int y = s / WI, x = s % WI;
      int r = y + py - dy + 1, c = x + px - dx + 1;
      bf16x8 bfr = *(const bf16x8*)&Ain[((r*PAD + c)*CICH + (ch ^ (c & 7)))*8];
      #pragma unroll
      for (int m = 0; m < MMW; ++m)
        acc[m][sf] = __builtin_amdgcn_mfma_f32_16x16x32_bf16(afr[m], bfr, acc[m][sf], 0, 0, 0);
    }
  }

  #pragma unroll
  for (int m = 0; m < MMW; ++m) {
    int co0 = mh*(CO/2) + m*16 + lk*4;
    float s1[4] = {0,0,0,0}, s2[4] = {0,0,0,0};
    #pragma unroll
    for (int sf = 0; sf < SFT; ++sf) {
      f32x4 v = acc[m][sf];
      int s = sf*16 + lm;
      int y = 2*(s / WI) + py, x = 2*(s % WI) + px;
      size_t ob = (((size_t)n*HO + y)*WO + x)*CO + co0;
      union { ushort u[4]; uint2 q; } pk;
      #pragma unroll
      for (int j = 0; j < 4; ++j) {
        pk.u[j] = bfbits(v[j]);
        s1[j] += v[j];
        s2[j] += v[j]*v[j];
      }
      *(uint2*)&out[ob] = pk.q;
    }
    #pragma unroll
    for (int j = 0; j < 4; ++j) {
      float a = s1[j], b = s2[j];
      #pragma unroll
      for (int o = 1; o < 16; o <<= 1) { a += __shfl_xor(a, o); b += __shfl_xor(b, o); }
      if (lm == 0) {
        atomicAdd(&s_sum[co0 + j], a);
        atomicAdd(&s_sq [co0 + j], b);
      }
    }
  }
  __syncthreads();
  for (int cc = tid; cc < CO; cc += 512) {
    atomicAdd(&gsum[cc], s_sum[cc]);
    atomicAdd(&gsq[cc],  s_sq[cc]);
  }
}

// ---------------- BN finalize
__global__ void k_bnfin(const float* __restrict__ sum, const float* __restrict__ sq,
                        const float* __restrict__ g, const float* __restrict__ be,
                        float* __restrict__ scale, float* __restrict__ shift,
                        int CO, float invN){
  int c = threadIdx.x;
  if (c >= CO) return;
  float m = sum[c]*invN;
  float v = sq[c]*invN - m*m;
  float sc = g[c]*rsqrtf(v + 1e-5f);
  scale[c] = sc;
  shift[c] = be[c] - m*sc;
}

// ---------------- final deconv 32->1 + sigmoid
__global__ __launch_bounds__(256) void k_final(
    const ushort* __restrict__ in, const float* __restrict__ wfo,
    const float* __restrict__ scale, const float* __restrict__ shift,
    const float* __restrict__ bfb, float* __restrict__ outp)
{
  constexpr int CI=32, HI=32, WI=32, HO=64, WO=64, SPLIT=8, HOq=HO/SPLIT;
  constexpr int ROWW = 32*36 + 8;
  __shared__ __align__(8) ushort As[6 * ROWW];

  const int tid = threadIdx.x, bid = blockIdx.x;
  const int n = bid / SPLIT, q = bid % SPLIT;
  const int y0 = q * HOq;
  const int rows_lo = max(0, y0/2 - 1);
  const int rows_hi = min(HI-1, (y0 + HOq)/2);
  const int nrows = rows_hi - rows_lo + 1;

  const ushort* inb = in + (size_t)n * HI * WI * CI;
  const int NC = nrows * WI * (CI/4);
  for (int e = tid; e < NC; e += 256) {
    int c2 = e & 7;
    int sp = e >> 3;
    int rl = sp >> 5, ix = sp & 31;
    uint2 u = *(const uint2*)&inb[(((rows_lo + rl)*WI + ix)*CI) + c2*4];
    float4 sc = *(const float4*)&scale[c2*4];
    float4 sh = *(const float4*)&shift[c2*4];
    float v0 = LRELU(fmaf(bflo(u.x), sc.x, sh.x));
    float v1 = LRELU(fmaf(bfhi(u.x), sc.y, sh.y));
    float v2 = LRELU(fmaf(bflo(u.y), sc.z, sh.z));
    float v3 = LRELU(fmaf(bfhi(u.y), sc.w, sh.w));
    uint2 o;
    o.x = (uint)bfbits(v0) | ((uint)bfbits(v1) << 16);
    o.y = (uint)bfbits(v2) | ((uint)bfbits(v3) << 16);
    *(uint2*)&As[rl*ROWW + ix*36 + c2*4] = o;
  }
  __syncthreads();

  const int w = tid >> 6, l = tid & 63;
  const int py = w >> 1, px = w & 1;
  const int ky0 = 1 - py, kx0 = 1 - px;
  const float b0 = bfb[0];
  const int xi = l & 31;
  const int x = 2*xi + px;

  for (int rowi = (l >> 5); rowi < 4; rowi += 2) {
    int y = y0 + 2*rowi + py;
    float acc = b0;
    #pragma unroll
    for (int t = 0; t < 4; ++t) {
      int ky = ky0 + 2*(t >> 1), kx = kx0 + 2*(t & 1);
      int iy = (y + 1 - ky) >> 1, ix = (x + 1 - kx) >> 1;
      if (iy < 0 || iy >= HI || ix < 0 || ix >= WI) continue;
      const float* __restrict__ wv = &wfo[(ky*4 + kx)*CI];
      const ushort* __restrict__ arow = &As[(iy - rows_lo)*ROWW + ix*36];
      #pragma unroll
      for (int c2 = 0; c2 < 8; ++c2) {
        uint2 v = *(const uint2*)&arow[c2*4];
        acc = fmaf(bflo(v.x), wv[c2*4+0], acc);
        acc = fmaf(bfhi(v.x), wv[c2*4+1], acc);
        acc = fmaf(bflo(v.y), wv[c2*4+2], acc);
        acc = fmaf(bfhi(v.y), wv[c2*4+3], acc);
      }
    }
    outp[(size_t)n*HO*WO + y*WO + x] = 1.f/(1.f + __expf(-acc));
  }
}

extern "C" void kernel_launch(void* const* d_in, const int* in_sizes, int n_in,
                              void* d_out, int out_size, void* d_ws, size_t ws_size,
                              hipStream_t stream) {
  const float* z_content = (const float*)d_in[0];
  const float* z_motion  = (const float*)d_in[1];
  const float* W_h  = (const float*)d_in[2];
  const float* b_h  = (const float*)d_in[3];
  const float* W_c  = (const float*)d_in[4];
  const float* b_c  = (const float*)d_in[5];
  const float* W_ih = (const float*)d_in[6];
  const float* W_hh = (const float*)d_in[7];
  const float* b_ih = (const float*)d_in[8];
  const float* b_hh = (const float*)d_in[9];
  const float* W_f  = (const float*)d_in[10];
  const float* b_f  = (const float*)d_in[11];
  const float* init_in = (const float*)d_in[12];
  const float* fc_W = (const float*)d_in[13];
  const float* fc_b = (const float*)d_in[14];
  const float* w0 = (const float*)d_in[15];
  const float* g0 = (const float*)d_in[16];
  const float* be0 = (const float*)d_in[17];
  const float* w1 = (const float*)d_in[18];
  const float* g1 = (const float*)d_in[19];
  const float* be1 = (const float*)d_in[20];
  const float* w2 = (const float*)d_in[21];
  const float* g2 = (const float*)d_in[22];
  const float* be2 = (const float*)d_in[23];
  const float* wf = (const float*)d_in[24];
  const float* bf_ = (const float*)d_in[25];

  const size_t P_BYTES = 10631168;
  const size_t X_OFF   = P_BYTES;
  const size_t X_BYTES = 83886080;
  const size_t Y_OFF   = X_OFF + X_BYTES;
  const size_t NEED    = Y_OFF + 41943040;
  if (ws_size < NEED) return;

  float* ws = (float*)d_ws;
  char*  wsb = (char*)d_ws;
  float* sum0 = ws + 0;        float* sq0 = ws + 128;
  float* sum1 = ws + 256;      float* sq1 = ws + 320;
  float* sum2 = ws + 384;      float* sq2 = ws + 416;
  float* scale0 = ws + 512;    float* shift0 = ws + 640;
  float* scale1 = ws + 768;    float* shift1 = ws + 832;
  float* scale2 = ws + 896;    float* shift2 = ws + 928;
  float4* xg4   = (float4*)(ws + 1024);
  float4* bias4 = (float4*)(ws + 2048);
  float* h    = ws + 3072;                  // 16384
  float* c    = ws + 19456;                 // 16384
  ushort* outsb = (ushort*)(ws + 35840);    // 327680 bf16 = 163840 f32 slots
  float* WhT  = ws + 199680;                // 65536
  float* WcT  = ws + 265216;                // 65536
  float4* W4hh = (float4*)(ws + 330752);    // 262144 f32
  float4* W4s  = (float4*)(ws + 592896);    // 262144 f32
  ushort* wp0 = (ushort*)(ws + 855040);     // 524288 bf16
  ushort* wp1 = (ushort*)(ws + 1117184);    // 131072 bf16
  ushort* wp2 = (ushort*)(ws + 1182720);    // 32768 bf16
  float* wfT  = ws + 1199104;               // 512 f32
  ushort* wpff = (ushort*)(ws + 1199616);   // 131072 bf16
  ushort* featb = (ushort*)(ws + 1265152);  // 819200 bf16 -> ends 1,674,752 f32 < P_BYTES/4

  ushort* wpfc = (ushort*)(wsb + X_OFF);   // 2,621,440 bf16 (dead after gemm)
  ushort* out0 = (ushort*)(wsb + X_OFF);   // NHWC bf16 [1280][8][8][128]
  ushort* out2 = (ushort*)(wsb + X_OFF);   // NHWC bf16 [1280][32][32][32]
  ushort* h1   = (ushort*)(wsb + Y_OFF);   // NHWC bf16 [1280][4][4][256]
  ushort* out1 = (ushort*)(wsb + Y_OFF);   // NHWC bf16 [1280][16][16][64]

  k_zero<<<2, 256, 0, stream>>>(ws, 448);

  dim3 tb(32,8);
  k_transpose<<<dim3(8,8),   tb, 0, stream>>>(W_h,  WhT, 256, 256);
  k_transpose<<<dim3(8,8),   tb, 0, stream>>>(W_c,  WcT, 256, 256);
  k_tobf16<<<10240, 256, 0, stream>>>(fc_W, wpfc, 2621440);
  k_tobf16<<<512, 256, 0, stream>>>(W_f, wpff, 131072);
  k_w4prep<<<256, 256, 0, stream>>>(W_ih, W_hh, W4hh, W4s);
  k_xgbias<<<256, 256, 0, stream>>>(W_ih, b_ih, b_hh, init_in, xg4, bias4);
  k_h0c0<<<64, 256, 0, stream>>>(z_content, z_motion, WhT, WcT, b_h, b_c, h, c);
  k_wprep<256,128><<<2048, 256, 0, stream>>>(w0, wp0);
  k_wprep<128,64><<<512, 256, 0, stream>>>(w1, wp1);
  k_wprep<64,32><<<128, 256, 0, stream>>>(w2, wp2);
  k_wfperm<<<2, 256, 0, stream>>>(wf, wfT);

  // ---- whole LSTM in one launch (1024 threads, 4-way K split)
  k_lstm_all<<<64, 1024, 0, stream>>>(W4hh, W4s, xg4, bias4, h, c, outsb);

  // ---- ff (MFMA) + concat + fc (MFMA)
  k_ff_m<<<dim3(8, 10), 256, 0, stream>>>(outsb, wpff, b_f, featb);
  k_zc<<<640, 256, 0, stream>>>(z_content, featb);
  k_gemm_fc_m<<<dim3(64, 10), 256, 0, stream>>>(featb, wpfc, fc_b, h1);

  // ---- deconv pipeline
  k_dcv<256,128,4><<<dim3(160,4), 256, 0, stream>>>(h1, wp0, out0, sum0, sq0);
  k_bnfin<<<1, 128, 0, stream>>>(sum0, sq0, g0, be0, scale0, shift0, 128, 1.f/81920.f);
  k_dcvim<128,64,8><<<1280, 512, 0, stream>>>(out0, wp1, scale0, shift0, out1, sum1, sq1);
  k_bnfin<<<1, 64, 0, stream>>>(sum1, sq1, g1, be1, scale1, shift1, 64, 1.f/327680.f);
  k_dcvim<64,32,16><<<1280, 512, 0, stream>>>(out1, wp2, scale1, shift1, out2, sum2, sq2);
  k_bnfin<<<1, 32, 0, stream>>>(sum2, sq2, g2, be2, scale2, shift2, 32, 1.f/1310720.f);
  k_final<<<10240, 256, 0, stream>>>(out2, wfT, scale2, shift2, bf_, (float*)d_out);
}

// Round 7
// 635.713 us; speedup vs baseline: 11.6312x; 1.0223x over previous
//
#include <hip/hip_runtime.h>
#include <hip/hip_bf16.h>
#include <math.h>

typedef __hip_bfloat16 bf16;
typedef __attribute__((ext_vector_type(8))) short bf16x8;
typedef __attribute__((ext_vector_type(4))) float f32x4;

#define LRELU(v) ((v) > 0.f ? (v) : 0.2f*(v))

__device__ __forceinline__ float sig_f(float x){ return 1.f/(1.f + __expf(-x)); }
__device__ __forceinline__ float tanh_f(float x){
  float ax = fabsf(x);
  float e = __expf(-2.f*ax);
  float t = (1.f - e)/(1.f + e);
  return x >= 0.f ? t : -t;
}
__device__ __forceinline__ ushort bfbits(float v){
  bf16 b = __float2bfloat16(v);
  return *(ushort*)&b;
}
__device__ __forceinline__ uint bfpack(float a, float b){
  return (uint)bfbits(a) | ((uint)bfbits(b) << 16);
}
__device__ __forceinline__ float bflo(uint u){ return __uint_as_float(u << 16); }
__device__ __forceinline__ float bfhi(uint u){ return __uint_as_float(u & 0xffff0000u); }

__global__ void k_tobf16(const float* __restrict__ src, ushort* __restrict__ dst, int n){
  int i = blockIdx.x*256 + threadIdx.x;
  if (i < n) dst[i] = bfbits(src[i]);
}

// ---------------- generic tiled transpose: src[R][C] -> dst[C][R]; R,C mult of 32; block(32,8)
__global__ void k_transpose(const float* __restrict__ src, float* __restrict__ dst, int R, int C){
  __shared__ float t[32][33];
  int c0 = blockIdx.x*32, r0 = blockIdx.y*32;
  int tx = threadIdx.x, ty = threadIdx.y;
  #pragma unroll
  for (int i = 0; i < 4; ++i)
    t[ty+8*i][tx] = src[(size_t)(r0+ty+8*i)*C + c0+tx];
  __syncthreads();
  #pragma unroll
  for (int i = 0; i < 4; ++i)
    dst[(size_t)(c0+ty+8*i)*R + r0+tx] = t[tx][ty+8*i];
}

// ---------------- LSTM weight pack (bf16 gate-packed) + BN-stat zeroing fold
__global__ void k_w4prep(const float* __restrict__ Wih, const float* __restrict__ Whh,
                         uint2* __restrict__ W4hhb, uint2* __restrict__ W4sb,
                         float* __restrict__ stats){
  int k = blockIdx.x, j = threadIdx.x;
  if (k < 2) { int i = k*256 + j; if (i < 448) stats[i] = 0.f; }
  float h0 = Whh[j*256+k],       h1 = Whh[(256+j)*256+k];
  float h2 = Whh[(512+j)*256+k], h3 = Whh[(768+j)*256+k];
  float i0 = Wih[j*256+k],       i1 = Wih[(256+j)*256+k];
  float i2 = Wih[(512+j)*256+k], i3 = Wih[(768+j)*256+k];
  W4hhb[k*256+j] = make_uint2(bfpack(h0,h1), bfpack(h2,h3));
  W4sb [k*256+j] = make_uint2(bfpack(h0+i0,h1+i1), bfpack(h2+i2,h3+i3));
}

__global__ void k_xgbias(const float* __restrict__ Wih, const float* __restrict__ b_ih,
                         const float* __restrict__ b_hh, const float* __restrict__ init_in,
                         float4* __restrict__ xg4, float4* __restrict__ bias4){
  int b = blockIdx.x, t = threadIdx.x;
  float v = init_in[t];
  float p0 = v * Wih[b*256 + t];
  float p1 = v * Wih[(256+b)*256 + t];
  float p2 = v * Wih[(512+b)*256 + t];
  float p3 = v * Wih[(768+b)*256 + t];
  #pragma unroll
  for (int o = 32; o; o >>= 1) {
    p0 += __shfl_xor(p0, o); p1 += __shfl_xor(p1, o);
    p2 += __shfl_xor(p2, o); p3 += __shfl_xor(p3, o);
  }
  __shared__ float4 red[4];
  int lane = t & 63, wid = t >> 6;
  if (lane == 0) red[wid] = make_float4(p0,p1,p2,p3);
  __syncthreads();
  if (t == 0) {
    float4 bi = make_float4(b_ih[b]+b_hh[b], b_ih[256+b]+b_hh[256+b],
                            b_ih[512+b]+b_hh[512+b], b_ih[768+b]+b_hh[768+b]);
    bias4[b] = bi;
    float4 a = bi;
    #pragma unroll
    for (int w = 0; w < 4; ++w) { a.x += red[w].x; a.y += red[w].y; a.z += red[w].z; a.w += red[w].w; }
    xg4[b] = a;
  }
}

__global__ __launch_bounds__(256) void k_h0c0(const float* __restrict__ zc, const float* __restrict__ zm,
                      const float* __restrict__ WhT, const float* __restrict__ WcT,
                      const float* __restrict__ b_h, const float* __restrict__ b_c,
                      float* __restrict__ h, float* __restrict__ c){
  __shared__ float zs[256];
  int b = blockIdx.x, j = threadIdx.x;
  zs[j] = (j < 128) ? zc[b*128 + j] : zm[b*128 + (j-128)];
  __syncthreads();
  float ah = b_h[j], ac = b_c[j];
  #pragma unroll 4
  for (int k = 0; k < 256; ++k) {
    float zv = zs[k];
    ah = fmaf(zv, WhT[k*256 + j], ah);
    ac = fmaf(zv, WcT[k*256 + j], ac);
  }
  h[b*256+j] = ah; c[b*256+j] = ac;
}

// ---------------- entire 20-step LSTM; block = batch row, 1024 thr, 4-way K split,
// bf16 gate-packed weights (uint2 per k) to halve the per-CU load-port bytes.
__global__ __launch_bounds__(1024) void k_lstm_all(
    const uint2* __restrict__ W4hhb, const uint2* __restrict__ W4sb,
    const float4* __restrict__ xg4, const float4* __restrict__ bias4,
    const float* __restrict__ h0, const float* __restrict__ c0,
    ushort* __restrict__ outsb){
  __shared__ float hs[256];
  __shared__ float4 part[3][256];
  const int b = blockIdx.x, tid = threadIdx.x;
  const int j = tid & 255, kq = tid >> 8;
  float cj = 0.f;
  if (kq == 0) { hs[j] = h0[b*256 + j]; cj = c0[b*256 + j]; }
  __syncthreads();
  for (int t = 0; t < 20; ++t) {
    const uint2* __restrict__ Wp = ((t == 0) ? W4hhb : W4sb) + (size_t)(kq*64)*256 + j;
    float4 a = make_float4(0.f, 0.f, 0.f, 0.f);
    #pragma unroll 32
    for (int kk = 0; kk < 64; ++kk) {
      uint2 wv = Wp[(size_t)kk*256];
      float hv = hs[kq*64 + kk];
      a.x = fmaf(hv, bflo(wv.x), a.x);
      a.y = fmaf(hv, bfhi(wv.x), a.y);
      a.z = fmaf(hv, bflo(wv.y), a.z);
      a.w = fmaf(hv, bfhi(wv.y), a.w);
    }
    if (kq) part[kq-1][j] = a;
    __syncthreads();
    if (kq == 0) {
      float4 p1 = part[0][j], p2 = part[1][j], p3 = part[2][j];
      float4 bb = (t == 0) ? xg4[j] : bias4[j];
      a.x += p1.x + p2.x + p3.x + bb.x;
      a.y += p1.y + p2.y + p3.y + bb.y;
      a.z += p1.z + p2.z + p3.z + bb.z;
      a.w += p1.w + p2.w + p3.w + bb.w;
      float ig = sig_f(a.x), fg = sig_f(a.y), gg = tanh_f(a.z), og = sig_f(a.w);
      cj = fmaf(fg, cj, ig*gg);
      float hj = og * tanh_f(cj);
      outsb[(b*20 + t)*256 + j] = bfbits(hj);
      hs[j] = hj;
    }
    __syncthreads();
  }
}

__global__ void k_zc(const float* __restrict__ zc, ushort* __restrict__ featb){
  int e = blockIdx.x*256 + threadIdx.x;
  int r = e >> 7, c = e & 127;
  featb[r*640 + 512 + c] = bfbits(zc[(r/20)*128 + c]);
}

// ---------------- MFMA ff GEMM: featb[1280][0:512] = lrelu(outsb[1280][256] @ wpff^T + b_f)
__global__ __launch_bounds__(256) void k_ff_m(
    const ushort* __restrict__ A, const ushort* __restrict__ W,
    const float* __restrict__ bias, ushort* __restrict__ C)
{
  constexpr int K = 256, BK = 64, NK = K/BK, BM = 128, BN = 64;
  constexpr int RS = 72;
  constexpr int NCF = BN/16;
  constexpr int AC = 4, WC = 2;

  __shared__ __align__(16) ushort Al[2][BM*RS];
  __shared__ __align__(16) ushort Wl[2][BN*RS];

  const int tid = threadIdx.x;
  const int col0 = blockIdx.x * BN, row0 = blockIdx.y * BM;
  const int w = tid >> 6, l = tid & 63, lm = l & 15, lk = l >> 4;

  f32x4 acc[NCF][2];
  #pragma unroll
  for (int m = 0; m < NCF; ++m)
    #pragma unroll
    for (int s = 0; s < 2; ++s)
      acc[m][s] = (f32x4){0.f,0.f,0.f,0.f};

  uint4 ar[AC], wr[WC];

  #define LOADG(kt) { \
    _Pragma("unroll") \
    for (int i = 0; i < AC; ++i) { \
      int chunk = tid + i*256; \
      int rl = chunk >> 3, kc = chunk & 7; \
      ar[i] = *(const uint4*)&A[(size_t)(row0+rl)*K + (kt)*BK + kc*8]; \
    } \
    _Pragma("unroll") \
    for (int i = 0; i < WC; ++i) { \
      int chunk = tid + i*256; \
      int co = chunk >> 3, kc = chunk & 7; \
      wr[i] = *(const uint4*)&W[(size_t)(col0+co)*K + (kt)*BK + kc*8]; \
    } }

  #define STOREL(buf) { \
    _Pragma("unroll") \
    for (int i = 0; i < AC; ++i) { \
      int chunk = tid + i*256; \
      int rl = chunk >> 3, kc = chunk & 7; \
      *(uint4*)&Al[buf][rl*RS + kc*8] = ar[i]; \
    } \
    _Pragma("unroll") \
    for (int i = 0; i < WC; ++i) { \
      int chunk = tid + i*256; \
      int co = chunk >> 3, kc = chunk & 7; \
      *(uint4*)&Wl[buf][co*RS + kc*8] = wr[i]; \
    } }

  LOADG(0);
  STOREL(0);
  int cur = 0;
  for (int kt = 0; kt < NK; ++kt) {
    if (kt + 1 < NK) LOADG(kt + 1);
    __syncthreads();
    #pragma unroll
    for (int kf = 0; kf < 2; ++kf) {
      bf16x8 bfr[2];
      #pragma unroll
      for (int s = 0; s < 2; ++s)
        bfr[s] = *(bf16x8*)&Al[cur][(w*32 + s*16 + lm)*RS + kf*32 + lk*8];
      #pragma unroll
      for (int m = 0; m < NCF; ++m) {
        bf16x8 afr = *(bf16x8*)&Wl[cur][(m*16 + lm)*RS + kf*32 + lk*8];
        acc[m][0] = __builtin_amdgcn_mfma_f32_16x16x32_bf16(afr, bfr[0], acc[m][0], 0, 0, 0);
        acc[m][1] = __builtin_amdgcn_mfma_f32_16x16x32_bf16(afr, bfr[1], acc[m][1], 0, 0, 0);
      }
    }
    if (kt + 1 < NK) STOREL(cur ^ 1);
    cur ^= 1;
  }

  #pragma unroll
  for (int m = 0; m < NCF; ++m) {
    #pragma unroll
    for (int s = 0; s < 2; ++s) {
      int row = row0 + w*32 + s*16 + lm;
      f32x4 v = acc[m][s];
      int u0 = col0 + m*16 + lk*4;
      union { ushort u[4]; uint2 q; } pk;
      #pragma unroll
      for (int j = 0; j < 4; ++j)
        pk.u[j] = bfbits(LRELU(v[j] + bias[u0+j]));
      *(uint2*)&C[(size_t)row*640 + u0] = pk.q;
    }
  }
  #undef LOADG
  #undef STOREL
}

// ---------------- MFMA FC GEMM: C[1280][4096] = lrelu(A@W^T + bias), NHWC bf16 out
__global__ __launch_bounds__(256) void k_gemm_fc_m(
    const ushort* __restrict__ A, const ushort* __restrict__ W,
    const float* __restrict__ bias, ushort* __restrict__ C)
{
  constexpr int K = 640, BK = 64, NK = K/BK, BM = 128, BN = 64;
  constexpr int RS = 72;
  constexpr int NCF = BN/16;
  constexpr int AC = 4, WC = 2;

  __shared__ __align__(16) ushort Al[2][BM*RS];
  __shared__ __align__(16) ushort Wl[2][BN*RS];

  const int tid = threadIdx.x;
  const int col0 = blockIdx.x * BN, row0 = blockIdx.y * BM;
  const int w = tid >> 6, l = tid & 63, lm = l & 15, lk = l >> 4;

  f32x4 acc[NCF][2];
  #pragma unroll
  for (int m = 0; m < NCF; ++m)
    #pragma unroll
    for (int s = 0; s < 2; ++s)
      acc[m][s] = (f32x4){0.f,0.f,0.f,0.f};

  uint4 ar[AC], wr[WC];

  #define LOADG(kt) { \
    _Pragma("unroll") \
    for (int i = 0; i < AC; ++i) { \
      int chunk = tid + i*256; \
      int rl = chunk >> 3, kc = chunk & 7; \
      ar[i] = *(const uint4*)&A[(size_t)(row0+rl)*K + (kt)*BK + kc*8]; \
    } \
    _Pragma("unroll") \
    for (int i = 0; i < WC; ++i) { \
      int chunk = tid + i*256; \
      int co = chunk >> 3, kc = chunk & 7; \
      wr[i] = *(const uint4*)&W[(size_t)(col0+co)*K + (kt)*BK + kc*8]; \
    } }

  #define STOREL(buf) { \
    _Pragma("unroll") \
    for (int i = 0; i < AC; ++i) { \
      int chunk = tid + i*256; \
      int rl = chunk >> 3, kc = chunk & 7; \
      *(uint4*)&Al[buf][rl*RS + kc*8] = ar[i]; \
    } \
    _Pragma("unroll") \
    for (int i = 0; i < WC; ++i) { \
      int chunk = tid + i*256; \
      int co = chunk >> 3, kc = chunk & 7; \
      *(uint4*)&Wl[buf][co*RS + kc*8] = wr[i]; \
    } }

  LOADG(0);
  STOREL(0);
  int cur = 0;
  for (int kt = 0; kt < NK; ++kt) {
    if (kt + 1 < NK) LOADG(kt + 1);
    __syncthreads();
    #pragma unroll
    for (int kf = 0; kf < 2; ++kf) {
      bf16x8 bfr[2];
      #pragma unroll
      for (int s = 0; s < 2; ++s)
        bfr[s] = *(bf16x8*)&Al[cur][(w*32 + s*16 + lm)*RS + kf*32 + lk*8];
      #pragma unroll
      for (int m = 0; m < NCF; ++m) {
        bf16x8 afr = *(bf16x8*)&Wl[cur][(m*16 + lm)*RS + kf*32 + lk*8];
        acc[m][0] = __builtin_amdgcn_mfma_f32_16x16x32_bf16(afr, bfr[0], acc[m][0], 0, 0, 0);
        acc[m][1] = __builtin_amdgcn_mfma_f32_16x16x32_bf16(afr, bfr[1], acc[m][1], 0, 0, 0);
      }
    }
    if (kt + 1 < NK) STOREL(cur ^ 1);
    cur ^= 1;
  }

  #pragma unroll
  for (int m = 0; m < NCF; ++m) {
    #pragma unroll
    for (int s = 0; s < 2; ++s) {
      int row = row0 + w*32 + s*16 + lm;
      f32x4 v = acc[m][s];
      #pragma unroll
      for (int j = 0; j < 4; ++j) {
        int u = col0 + m*16 + lk*4 + j;
        float val = LRELU(v[j] + bias[u]);
        C[((size_t)row << 12) + ((size_t)(u & 15) << 8) + (u >> 4)] = bfbits(val);
      }
    }
  }
  #undef LOADG
  #undef STOREL
}

// ---------------- deconv weight prep: w[ci][co][ky][kx] f32 -> wp[p][co][t*CI+ci] bf16
template<int CI, int CO>
__global__ void k_wprep(const float* __restrict__ w, ushort* __restrict__ wp){
  int e = blockIdx.x*256 + threadIdx.x;
  if (e >= 16*CI*CO) return;
  int ci = e % CI; int t1 = e / CI;
  int t = t1 & 3;  int t2 = t1 >> 2;
  int co = t2 % CO; int pp = t2 / CO;
  int py = pp >> 1, px = pp & 1, dy = t >> 1, dx = t & 1;
  int ky = (py ? 0 : 1) + 2*dy;
  int kx = (px ? 0 : 1) + 2*dx;
  wp[e] = bfbits(w[((ci*CO + co)*4 + ky)*4 + kx]);
}

__global__ void k_wfperm(const float* __restrict__ wf, float* __restrict__ wfT){
  int e = blockIdx.x*256 + threadIdx.x;
  if (e < 512) {
    int tap = e >> 5, ci = e & 31;
    wfT[tap*32 + ci] = wf[ci*16 + tap];
  }
}

// ---------------- MFMA parity-GEMM deconv (stage 0: deep K, spatial-tiled)
template<int CI, int CO, int HI>
__global__ __launch_bounds__(256) void k_dcv(
    const ushort* __restrict__ in, const ushort* __restrict__ wp,
    ushort* __restrict__ out, float* __restrict__ gsum, float* __restrict__ gsq)
{
  constexpr int WI = HI, HO = 2*HI, WO = 2*WI;
  constexpr int K = 4*CI, BK = 64, NK = K/BK;
  constexpr int BSP = 128;
  constexpr int RS = 72;
  constexpr int NCF = CO/16;
  constexpr int AC = BSP/32;
  constexpr int WC = CO/32;

  __shared__ __align__(16) ushort Al[2][BSP*RS];
  __shared__ __align__(16) ushort Wl[2][CO*RS];
  __shared__ float s_sum[CO], s_sq[CO];

  const int tid = threadIdx.x;
  const int sp0 = blockIdx.x * BSP;
  const int p  = blockIdx.y;
  const int py = p >> 1, px = p & 1;
  const int w  = tid >> 6, l = tid & 63;
  const int lm = l & 15, lk = l >> 4;

  if (tid < CO) { s_sum[tid] = 0.f; s_sq[tid] = 0.f; }

  f32x4 acc[NCF][2];
  #pragma unroll
  for (int m = 0; m < NCF; ++m)
    #pragma unroll
    for (int s = 0; s < 2; ++s)
      acc[m][s] = (f32x4){0.f,0.f,0.f,0.f};

  uint4 ar[AC], wr[WC];

  #define LOADT(kt) { \
    int t = ((kt)*BK)/CI, ci0 = ((kt)*BK)%CI; \
    int dy = t >> 1, dx = t & 1; \
    _Pragma("unroll") \
    for (int i = 0; i < AC; ++i) { \
      int chunk = tid + i*256; \
      int rl = chunk >> 3, kc = chunk & 7; \
      int r = sp0 + rl; \
      int n = r / (HI*WI), rem = r % (HI*WI); \
      int oy = rem / WI, ox = rem % WI; \
      int iy = oy + py - dy, ix = ox + px - dx; \
      if ((unsigned)iy < (unsigned)HI && (unsigned)ix < (unsigned)WI) \
        ar[i] = *(const uint4*)&in[((((size_t)n*HI + iy)*WI + ix)*CI) + ci0 + kc*8]; \
      else ar[i] = make_uint4(0,0,0,0); \
    } \
    _Pragma("unroll") \
    for (int i = 0; i < WC; ++i) { \
      int chunk = tid + i*256; \
      int co = chunk >> 3, kc = chunk & 7; \
      wr[i] = *(const uint4*)&wp[((size_t)p*CO + co)*K + (kt)*BK + kc*8]; \
    } }

  #define STORET(buf) { \
    _Pragma("unroll") \
    for (int i = 0; i < AC; ++i) { \
      int chunk = tid + i*256; \
      int rl = chunk >> 3, kc = chunk & 7; \
      *(uint4*)&Al[buf][rl*RS + kc*8] = ar[i]; \
    } \
    _Pragma("unroll") \
    for (int i = 0; i < WC; ++i) { \
      int chunk = tid + i*256; \
      int co = chunk >> 3, kc = chunk & 7; \
      *(uint4*)&Wl[buf][co*RS + kc*8] = wr[i]; \
    } }

  LOADT(0);
  STORET(0);
  int cur = 0;
  for (int kt = 0; kt < NK; ++kt) {
    if (kt + 1 < NK) LOADT(kt + 1);
    __syncthreads();
    #pragma unroll
    for (int kf = 0; kf < 2; ++kf) {
      bf16x8 bfr[2];
      #pragma unroll
      for (int s = 0; s < 2; ++s)
        bfr[s] = *(bf16x8*)&Al[cur][(w*32 + s*16 + lm)*RS + kf*32 + lk*8];
      #pragma unroll
      for (int m = 0; m < NCF; ++m) {
        bf16x8 afr = *(bf16x8*)&Wl[cur][(m*16 + lm)*RS + kf*32 + lk*8];
        acc[m][0] = __builtin_amdgcn_mfma_f32_16x16x32_bf16(afr, bfr[0], acc[m][0], 0, 0, 0);
        acc[m][1] = __builtin_amdgcn_mfma_f32_16x16x32_bf16(afr, bfr[1], acc[m][1], 0, 0, 0);
      }
    }
    if (kt + 1 < NK) STORET(cur ^ 1);
    cur ^= 1;
  }

  #pragma unroll
  for (int m = 0; m < NCF; ++m) {
    float s1[4] = {0,0,0,0}, s2[4] = {0,0,0,0};
    #pragma unroll
    for (int s = 0; s < 2; ++s) {
      f32x4 v = acc[m][s];
      int sp = sp0 + w*32 + s*16 + lm;
      int n = sp / (HI*WI), rem = sp % (HI*WI);
      int y = 2*(rem / WI) + py, x = 2*(rem % WI) + px;
      size_t ob = (((size_t)n*HO + y)*WO + x)*CO + m*16 + lk*4;
      union { ushort u[4]; uint2 q; } pk;
      #pragma unroll
      for (int j = 0; j < 4; ++j) {
        pk.u[j] = bfbits(v[j]);
        s1[j] += v[j];
        s2[j] += v[j]*v[j];
      }
      *(uint2*)&out[ob] = pk.q;
    }
    #pragma unroll
    for (int j = 0; j < 4; ++j) {
      float a = s1[j], b = s2[j];
      #pragma unroll
      for (int o = 1; o < 16; o <<= 1) { a += __shfl_xor(a, o); b += __shfl_xor(b, o); }
      if (lm == 0) {
        atomicAdd(&s_sum[m*16 + lk*4 + j], a);
        atomicAdd(&s_sq [m*16 + lk*4 + j], b);
      }
    }
  }
  __syncthreads();
  for (int cc = tid; cc < CO; cc += 256) {
    atomicAdd(&gsum[cc], s_sum[cc]);
    atomicAdd(&gsq[cc],  s_sq[cc]);
  }
  #undef LOADT
  #undef STORET
}

// ---------------- image-resident MFMA deconv (stages 1 & 2); BN finalize of the
// PREVIOUS stage computed in-prologue from gsum/gsq (removes k_bnfin launches).
template<int CI, int CO, int HI>
__global__ __launch_bounds__(512) void k_dcvim(
    const ushort* __restrict__ in, const ushort* __restrict__ wp,
    const float* __restrict__ gsumP, const float* __restrict__ gsqP,
    const float* __restrict__ gP, const float* __restrict__ beP, float invNP,
    ushort* __restrict__ out, float* __restrict__ gsum, float* __restrict__ gsq)
{
  constexpr int WI = HI, HO = 2*HI, WO = 2*WI;
  constexpr int K = 4*CI;
  constexpr int KF = K/32;
  constexpr int PAD = HI + 2;
  constexpr int CICH = CI/8;
  constexpr int AU4 = PAD*PAD*CICH;
  constexpr int SFT = HI*WI/16;
  constexpr int MMW = CO/32;

  __shared__ __align__(16) ushort Ain[PAD*PAD*CI];
  __shared__ float s_sum[CO], s_sq[CO];
  __shared__ float s_scale[CI], s_shift[CI];

  const int tid = threadIdx.x;
  const int n = blockIdx.x;
  const int w = tid >> 6, l = tid & 63, lm = l & 15, lk = l >> 4;
  const int p = w >> 1, py = p >> 1, px = p & 1, mh = w & 1;

  if (tid < CO) { s_sum[tid] = 0.f; s_sq[tid] = 0.f; }
  if (tid >= 512-CI) {                      // disjoint threads from s_sum init
    int c = tid - (512-CI);
    float m = gsumP[c]*invNP;
    float v = gsqP[c]*invNP - m*m;
    float sc = gP[c]*rsqrtf(v + 1e-5f);
    s_scale[c] = sc;
    s_shift[c] = beP[c] - m*sc;
  }

  uint4 zz = make_uint4(0,0,0,0);
  for (int i = tid; i < AU4; i += 512) ((uint4*)Ain)[i] = zz;
  __syncthreads();

  const ushort* inb = in + (size_t)n * HI * WI * CI;
  constexpr int NCHK = HI*WI*CICH;
  for (int e = tid; e < NCHK; e += 512) {
    int ci8 = e % CICH; int sp = e / CICH;
    int ix = sp % WI, iy = sp / WI;
    uint4 u = *(const uint4*)&inb[(size_t)sp*CI + ci8*8];
    int ci0 = ci8*8;
    float4 sc0 = *(const float4*)&s_scale[ci0];
    float4 sc1 = *(const float4*)&s_scale[ci0+4];
    float4 sh0 = *(const float4*)&s_shift[ci0];
    float4 sh1 = *(const float4*)&s_shift[ci0+4];
    float v0 = LRELU(fmaf(bflo(u.x), sc0.x, sh0.x));
    float v1 = LRELU(fmaf(bfhi(u.x), sc0.y, sh0.y));
    float v2 = LRELU(fmaf(bflo(u.y), sc0.z, sh0.z));
    float v3 = LRELU(fmaf(bfhi(u.y), sc0.w, sh0.w));
    float v4 = LRELU(fmaf(bflo(u.z), sc1.x, sh1.x));
    float v5 = LRELU(fmaf(bfhi(u.z), sc1.y, sh1.y));
    float v6 = LRELU(fmaf(bflo(u.w), sc1.z, sh1.z));
    float v7 = LRELU(fmaf(bfhi(u.w), sc1.w, sh1.w));
    uint4 o;
    o.x = (uint)bfbits(v0) | ((uint)bfbits(v1) << 16);
    o.y = (uint)bfbits(v2) | ((uint)bfbits(v3) << 16);
    o.z = (uint)bfbits(v4) | ((uint)bfbits(v5) << 16);
    o.w = (uint)bfbits(v6) | ((uint)bfbits(v7) << 16);
    int r = iy + 1, c = ix + 1;
    int chS = ci8 ^ (c & 7);
    ((uint4*)Ain)[(r*PAD + c)*CICH + chS] = o;
  }
  __syncthreads();

  f32x4 acc[MMW][SFT];
  #pragma unroll
  for (int m = 0; m < MMW; ++m)
    #pragma unroll
    for (int sf = 0; sf < SFT; ++sf)
      acc[m][sf] = (f32x4){0.f,0.f,0.f,0.f};

  const ushort* wpb = wp + ((size_t)p*CO + mh*(CO/2))*K;
  #pragma unroll
  for (int kf = 0; kf < KF; ++kf) {
    const int t = (kf*32)/CI, cib = (kf*32)%CI;
    const int dy = t >> 1, dx = t & 1;
    bf16x8 afr[MMW];
    #pragma unroll
    for (int m = 0; m < MMW; ++m)
      afr[m] = *(const bf16x8*)&wpb[(size_t)(m*16 + lm)*K + kf*32 + lk*8];
    const int ch = (cib >> 3) + lk;
    #pragma unroll
    for (int sf = 0; sf < SFT; ++sf) {
      int s = sf*16 + lm;
      int y = s / WI, x = s % WI;
      int r = y + py - dy + 1, c = x + px - dx + 1;
      bf16x8 bfr = *(const bf16x8*)&Ain[((r*PAD + c)*CICH + (ch ^ (c & 7)))*8];
      #pragma unroll
      for (int m = 0; m < MMW; ++m)
        acc[m][sf] = __builtin_amdgcn_mfma_f32_16x16x32_bf16(afr[m], bfr, acc[m][sf], 0, 0, 0);
    }
  }

  #pragma unroll
  for (int m = 0; m < MMW; ++m) {
    int co0 = mh*(CO/2) + m*16 + lk*4;
    float s1[4] = {0,0,0,0}, s2[4] = {0,0,0,0};
    #pragma unroll
    for (int sf = 0; sf < SFT; ++sf) {
      f32x4 v = acc[m][sf];
      int s = sf*16 + lm;
      int y = 2*(s / WI) + py, x = 2*(s % WI) + px;
      size_t ob = (((size_t)n*HO + y)*WO + x)*CO + co0;
      union { ushort u[4]; uint2 q; } pk;
      #pragma unroll
      for (int j = 0; j < 4; ++j) {
        pk.u[j] = bfbits(v[j]);
        s1[j] += v[j];
        s2[j] += v[j]*v[j];
      }
      *(uint2*)&out[ob] = pk.q;
    }
    #pragma unroll
    for (int j = 0; j < 4; ++j) {
      float a = s1[j], b = s2[j];
      #pragma unroll
      for (int o = 1; o < 16; o <<= 1) { a += __shfl_xor(a, o); b += __shfl_xor(b, o); }
      if (lm == 0) {
        atomicAdd(&s_sum[co0 + j], a);
        atomicAdd(&s_sq [co0 + j], b);
      }
    }
  }
  __syncthreads();
  for (int cc = tid; cc < CO; cc += 512) {
    atomicAdd(&gsum[cc], s_sum[cc]);
    atomicAdd(&gsq[cc],  s_sq[cc]);
  }
}

// ---------------- final deconv 32->1 + sigmoid; BN finalize inline
__global__ __launch_bounds__(256) void k_final(
    const ushort* __restrict__ in, const float* __restrict__ wfo,
    const float* __restrict__ gsumP, const float* __restrict__ gsqP,
    const float* __restrict__ gP, const float* __restrict__ beP, float invNP,
    const float* __restrict__ bfb, float* __restrict__ outp)
{
  constexpr int CI=32, HI=32, WI=32, HO=64, WO=64, SPLIT=8, HOq=HO/SPLIT;
  constexpr int ROWW = 32*36 + 8;
  __shared__ __align__(8) ushort As[6 * ROWW];
  __shared__ float s_scale[CI], s_shift[CI];

  const int tid = threadIdx.x, bid = blockIdx.x;
  const int n = bid / SPLIT, q = bid % SPLIT;
  const int y0 = q * HOq;
  const int rows_lo = max(0, y0/2 - 1);
  const int rows_hi = min(HI-1, (y0 + HOq)/2);
  const int nrows = rows_hi - rows_lo + 1;

  if (tid < CI) {
    float m = gsumP[tid]*invNP;
    float v = gsqP[tid]*invNP - m*m;
    float sc = gP[tid]*rsqrtf(v + 1e-5f);
    s_scale[tid] = sc;
    s_shift[tid] = beP[tid] - m*sc;
  }
  __syncthreads();

  const ushort* inb = in + (size_t)n * HI * WI * CI;
  const int NC = nrows * WI * (CI/4);
  for (int e = tid; e < NC; e += 256) {
    int c2 = e & 7;
    int sp = e >> 3;
    int rl = sp >> 5, ix = sp & 31;
    uint2 u = *(const uint2*)&inb[(((rows_lo + rl)*WI + ix)*CI) + c2*4];
    float4 sc = *(const float4*)&s_scale[c2*4];
    float4 sh = *(const float4*)&s_shift[c2*4];
    float v0 = LRELU(fmaf(bflo(u.x), sc.x, sh.x));
    float v1 = LRELU(fmaf(bfhi(u.x), sc.y, sh.y));
    float v2 = LRELU(fmaf(bflo(u.y), sc.z, sh.z));
    float v3 = LRELU(fmaf(bfhi(u.y), sc.w, sh.w));
    uint2 o;
    o.x = (uint)bfbits(v0) | ((uint)bfbits(v1) << 16);
    o.y = (uint)bfbits(v2) | ((uint)bfbits(v3) << 16);
    *(uint2*)&As[rl*ROWW + ix*36 + c2*4] = o;
  }
  __syncthreads();

  const int w = tid >> 6, l = tid & 63;
  const int py = w >> 1, px = w & 1;
  const int ky0 = 1 - py, kx0 = 1 - px;
  const float b0 = bfb[0];
  const int xi = l & 31;
  const int x = 2*xi + px;

  for (int rowi = (l >> 5); rowi < 4; rowi += 2) {
    int y = y0 + 2*rowi + py;
    float acc = b0;
    #pragma unroll
    for (int t = 0; t < 4; ++t) {
      int ky = ky0 + 2*(t >> 1), kx = kx0 + 2*(t & 1);
      int iy = (y + 1 - ky) >> 1, ix = (x + 1 - kx) >> 1;
      if (iy < 0 || iy >= HI || ix < 0 || ix >= WI) continue;
      const float* __restrict__ wv = &wfo[(ky*4 + kx)*CI];
      const ushort* __restrict__ arow = &As[(iy - rows_lo)*ROWW + ix*36];
      #pragma unroll
      for (int c2 = 0; c2 < 8; ++c2) {
        uint2 v = *(const uint2*)&arow[c2*4];
        acc = fmaf(bflo(v.x), wv[c2*4+0], acc);
        acc = fmaf(bfhi(v.x), wv[c2*4+1], acc);
        acc = fmaf(bflo(v.y), wv[c2*4+2], acc);
        acc = fmaf(bfhi(v.y), wv[c2*4+3], acc);
      }
    }
    outp[(size_t)n*HO*WO + y*WO + x] = 1.f/(1.f + __expf(-acc));
  }
}

extern "C" void kernel_launch(void* const* d_in, const int* in_sizes, int n_in,
                              void* d_out, int out_size, void* d_ws, size_t ws_size,
                              hipStream_t stream) {
  const float* z_content = (const float*)d_in[0];
  const float* z_motion  = (const float*)d_in[1];
  const float* W_h  = (const float*)d_in[2];
  const float* b_h  = (const float*)d_in[3];
  const float* W_c  = (const float*)d_in[4];
  const float* b_c  = (const float*)d_in[5];
  const float* W_ih = (const float*)d_in[6];
  const float* W_hh = (const float*)d_in[7];
  const float* b_ih = (const float*)d_in[8];
  const float* b_hh = (const float*)d_in[9];
  const float* W_f  = (const float*)d_in[10];
  const float* b_f  = (const float*)d_in[11];
  const float* init_in = (const float*)d_in[12];
  const float* fc_W = (const float*)d_in[13];
  const float* fc_b = (const float*)d_in[14];
  const float* w0 = (const float*)d_in[15];
  const float* g0 = (const float*)d_in[16];
  const float* be0 = (const float*)d_in[17];
  const float* w1 = (const float*)d_in[18];
  const float* g1 = (const float*)d_in[19];
  const float* be1 = (const float*)d_in[20];
  const float* w2 = (const float*)d_in[21];
  const float* g2 = (const float*)d_in[22];
  const float* be2 = (const float*)d_in[23];
  const float* wf = (const float*)d_in[24];
  const float* bf_ = (const float*)d_in[25];

  const size_t P_BYTES = 10631168;
  const size_t X_OFF   = P_BYTES;
  const size_t X_BYTES = 83886080;
  const size_t Y_OFF   = X_OFF + X_BYTES;
  const size_t NEED    = Y_OFF + 41943040;
  if (ws_size < NEED) return;

  float* ws = (float*)d_ws;
  char*  wsb = (char*)d_ws;
  float* sum0 = ws + 0;        float* sq0 = ws + 128;
  float* sum1 = ws + 256;      float* sq1 = ws + 320;
  float* sum2 = ws + 384;      float* sq2 = ws + 416;
  float4* xg4   = (float4*)(ws + 1024);
  float4* bias4 = (float4*)(ws + 2048);
  float* h    = ws + 3072;                  // 16384
  float* c    = ws + 19456;                 // 16384
  ushort* outsb = (ushort*)(ws + 35840);    // 327680 bf16
  float* WhT  = ws + 199680;                // 65536
  float* WcT  = ws + 265216;                // 65536
  uint2* W4hhb = (uint2*)(ws + 330752);     // 65536 uint2 = 131072 f32 slots
  uint2* W4sb  = (uint2*)(ws + 592896);     // 65536 uint2
  ushort* wp0 = (ushort*)(ws + 855040);     // 524288 bf16
  ushort* wp1 = (ushort*)(ws + 1117184);    // 131072 bf16
  ushort* wp2 = (ushort*)(ws + 1182720);    // 32768 bf16
  float* wfT  = ws + 1199104;               // 512 f32
  ushort* wpff = (ushort*)(ws + 1199616);   // 131072 bf16
  ushort* featb = (ushort*)(ws + 1265152);  // 819200 bf16

  ushort* wpfc = (ushort*)(wsb + X_OFF);   // 2,621,440 bf16 (dead after gemm)
  ushort* out0 = (ushort*)(wsb + X_OFF);   // NHWC bf16 [1280][8][8][128]
  ushort* out2 = (ushort*)(wsb + X_OFF);   // NHWC bf16 [1280][32][32][32]
  ushort* h1   = (ushort*)(wsb + Y_OFF);   // NHWC bf16 [1280][4][4][256]
  ushort* out1 = (ushort*)(wsb + Y_OFF);   // NHWC bf16 [1280][16][16][64]

  dim3 tb(32,8);
  k_transpose<<<dim3(8,8),   tb, 0, stream>>>(W_h,  WhT, 256, 256);
  k_transpose<<<dim3(8,8),   tb, 0, stream>>>(W_c,  WcT, 256, 256);
  k_tobf16<<<10240, 256, 0, stream>>>(fc_W, wpfc, 2621440);
  k_tobf16<<<512, 256, 0, stream>>>(W_f, wpff, 131072);
  k_w4prep<<<256, 256, 0, stream>>>(W_ih, W_hh, W4hhb, W4sb, ws);
  k_xgbias<<<256, 256, 0, stream>>>(W_ih, b_ih, b_hh, init_in, xg4, bias4);
  k_h0c0<<<64, 256, 0, stream>>>(z_content, z_motion, WhT, WcT, b_h, b_c, h, c);
  k_wprep<256,128><<<2048, 256, 0, stream>>>(w0, wp0);
  k_wprep<128,64><<<512, 256, 0, stream>>>(w1, wp1);
  k_wprep<64,32><<<128, 256, 0, stream>>>(w2, wp2);
  k_wfperm<<<2, 256, 0, stream>>>(wf, wfT);

  // ---- whole LSTM in one launch (1024 threads, 4-way K split, bf16 weights)
  k_lstm_all<<<64, 1024, 0, stream>>>(W4hhb, W4sb, xg4, bias4, h, c, outsb);

  // ---- ff (MFMA) + concat + fc (MFMA)
  k_ff_m<<<dim3(8, 10), 256, 0, stream>>>(outsb, wpff, b_f, featb);
  k_zc<<<640, 256, 0, stream>>>(z_content, featb);
  k_gemm_fc_m<<<dim3(64, 10), 256, 0, stream>>>(featb, wpfc, fc_b, h1);

  // ---- deconv pipeline (BN finalize folded into consumers)
  k_dcv<256,128,4><<<dim3(160,4), 256, 0, stream>>>(h1, wp0, out0, sum0, sq0);
  k_dcvim<128,64,8><<<1280, 512, 0, stream>>>(out0, wp1, sum0, sq0, g0, be0, 1.f/81920.f, out1, sum1, sq1);
  k_dcvim<64,32,16><<<1280, 512, 0, stream>>>(out1, wp2, sum1, sq1, g1, be1, 1.f/327680.f, out2, sum2, sq2);
  k_final<<<10240, 256, 0, stream>>>(out2, wfT, sum2, sq2, g2, be2, 1.f/1310720.f, bf_, (float*)d_out);
}

// Round 8
// 588.875 us; speedup vs baseline: 12.5564x; 1.0795x over previous
//
#include <hip/hip_runtime.h>
#include <hip/hip_bf16.h>
#include <math.h>

typedef __hip_bfloat16 bf16;
typedef __attribute__((ext_vector_type(8))) short bf16x8;
typedef __attribute__((ext_vector_type(4))) float f32x4;

#define LRELU(v) ((v) > 0.f ? (v) : 0.2f*(v))

__device__ __forceinline__ float sig_f(float x){ return 1.f/(1.f + __expf(-x)); }
__device__ __forceinline__ float tanh_f(float x){
  float ax = fabsf(x);
  float e = __expf(-2.f*ax);
  float t = (1.f - e)/(1.f + e);
  return x >= 0.f ? t : -t;
}
__device__ __forceinline__ ushort bfbits(float v){
  bf16 b = __float2bfloat16(v);
  return *(ushort*)&b;
}
__device__ __forceinline__ uint bfpack(float a, float b){
  return (uint)bfbits(a) | ((uint)bfbits(b) << 16);
}
__device__ __forceinline__ float bflo(uint u){ return __uint_as_float(u << 16); }
__device__ __forceinline__ float bfhi(uint u){ return __uint_as_float(u & 0xffff0000u); }

__global__ void k_tobf16(const float* __restrict__ src, ushort* __restrict__ dst, int n){
  int i = blockIdx.x*256 + threadIdx.x;
  if (i < n) dst[i] = bfbits(src[i]);
}

// ---------------- generic tiled transpose: src[R][C] -> dst[C][R]; R,C mult of 32; block(32,8)
__global__ void k_transpose(const float* __restrict__ src, float* __restrict__ dst, int R, int C){
  __shared__ float t[32][33];
  int c0 = blockIdx.x*32, r0 = blockIdx.y*32;
  int tx = threadIdx.x, ty = threadIdx.y;
  #pragma unroll
  for (int i = 0; i < 4; ++i)
    t[ty+8*i][tx] = src[(size_t)(r0+ty+8*i)*C + c0+tx];
  __syncthreads();
  #pragma unroll
  for (int i = 0; i < 4; ++i)
    dst[(size_t)(c0+ty+8*i)*R + r0+tx] = t[tx][ty+8*i];
}

// ---------------- LSTM weight pack: uint4 per (k-pair, unit): {(i,f)k0,(g,o)k0,(i,f)k1,(g,o)k1}
// grid 128 blocks (k2), 256 threads (j). Also zeroes BN stat accumulators.
__global__ void k_w4prep(const float* __restrict__ Wih, const float* __restrict__ Whh,
                         uint4* __restrict__ Whq, uint4* __restrict__ Wsq,
                         float* __restrict__ stats){
  int k2 = blockIdx.x, j = threadIdx.x;
  if (k2 < 2) { int i = k2*256 + j; if (i < 448) stats[i] = 0.f; }
  int k0 = 2*k2, k1 = 2*k2 + 1;
  float hi0 = Whh[j*256+k0],       hf0 = Whh[(256+j)*256+k0];
  float hg0 = Whh[(512+j)*256+k0], ho0 = Whh[(768+j)*256+k0];
  float hi1 = Whh[j*256+k1],       hf1 = Whh[(256+j)*256+k1];
  float hg1 = Whh[(512+j)*256+k1], ho1 = Whh[(768+j)*256+k1];
  float ii0 = Wih[j*256+k0],       if0 = Wih[(256+j)*256+k0];
  float ig0 = Wih[(512+j)*256+k0], io0 = Wih[(768+j)*256+k0];
  float ii1 = Wih[j*256+k1],       if1 = Wih[(256+j)*256+k1];
  float ig1 = Wih[(512+j)*256+k1], io1 = Wih[(768+j)*256+k1];
  Whq[k2*256+j] = make_uint4(bfpack(hi0,hf0), bfpack(hg0,ho0), bfpack(hi1,hf1), bfpack(hg1,ho1));
  Wsq[k2*256+j] = make_uint4(bfpack(hi0+ii0,hf0+if0), bfpack(hg0+ig0,ho0+io0),
                             bfpack(hi1+ii1,hf1+if1), bfpack(hg1+ig1,ho1+io1));
}

__global__ void k_xgbias(const float* __restrict__ Wih, const float* __restrict__ b_ih,
                         const float* __restrict__ b_hh, const float* __restrict__ init_in,
                         float4* __restrict__ xg4, float4* __restrict__ bias4){
  int b = blockIdx.x, t = threadIdx.x;
  float v = init_in[t];
  float p0 = v * Wih[b*256 + t];
  float p1 = v * Wih[(256+b)*256 + t];
  float p2 = v * Wih[(512+b)*256 + t];
  float p3 = v * Wih[(768+b)*256 + t];
  #pragma unroll
  for (int o = 32; o; o >>= 1) {
    p0 += __shfl_xor(p0, o); p1 += __shfl_xor(p1, o);
    p2 += __shfl_xor(p2, o); p3 += __shfl_xor(p3, o);
  }
  __shared__ float4 red[4];
  int lane = t & 63, wid = t >> 6;
  if (lane == 0) red[wid] = make_float4(p0,p1,p2,p3);
  __syncthreads();
  if (t == 0) {
    float4 bi = make_float4(b_ih[b]+b_hh[b], b_ih[256+b]+b_hh[256+b],
                            b_ih[512+b]+b_hh[512+b], b_ih[768+b]+b_hh[768+b]);
    bias4[b] = bi;
    float4 a = bi;
    #pragma unroll
    for (int w = 0; w < 4; ++w) { a.x += red[w].x; a.y += red[w].y; a.z += red[w].z; a.w += red[w].w; }
    xg4[b] = a;
  }
}

__global__ __launch_bounds__(256) void k_h0c0(const float* __restrict__ zc, const float* __restrict__ zm,
                      const float* __restrict__ WhT, const float* __restrict__ WcT,
                      const float* __restrict__ b_h, const float* __restrict__ b_c,
                      float* __restrict__ h, float* __restrict__ c){
  __shared__ float zs[256];
  int b = blockIdx.x, j = threadIdx.x;
  zs[j] = (j < 128) ? zc[b*128 + j] : zm[b*128 + (j-128)];
  __syncthreads();
  float ah = b_h[j], ac = b_c[j];
  #pragma unroll 4
  for (int k = 0; k < 256; ++k) {
    float zv = zs[k];
    ah = fmaf(zv, WhT[k*256 + j], ah);
    ac = fmaf(zv, WcT[k*256 + j], ac);
  }
  h[b*256+j] = ah; c[b*256+j] = ac;
}

// ---------------- entire 20-step LSTM; block = batch row, 1024 thr, 4-way K split,
// uint4 weight loads (2 k-steps per load) to halve VMEM instruction count.
__global__ __launch_bounds__(1024) void k_lstm_all(
    const uint4* __restrict__ Whq, const uint4* __restrict__ Wsq,
    const float4* __restrict__ xg4, const float4* __restrict__ bias4,
    const float* __restrict__ h0, const float* __restrict__ c0,
    ushort* __restrict__ outsb){
  __shared__ float hs[256];
  __shared__ float4 part[3][256];
  const int b = blockIdx.x, tid = threadIdx.x;
  const int j = tid & 255, kq = tid >> 8;
  float cj = 0.f;
  if (kq == 0) { hs[j] = h0[b*256 + j]; cj = c0[b*256 + j]; }
  __syncthreads();
  for (int t = 0; t < 20; ++t) {
    const uint4* __restrict__ Wp = ((t == 0) ? Whq : Wsq) + (size_t)(kq*32)*256 + j;
    float4 a = make_float4(0.f, 0.f, 0.f, 0.f);
    #pragma unroll 16
    for (int kk = 0; kk < 32; ++kk) {
      uint4 wv = Wp[(size_t)kk*256];
      float h0v = hs[kq*64 + 2*kk];
      float h1v = hs[kq*64 + 2*kk + 1];
      a.x = fmaf(h0v, bflo(wv.x), a.x);
      a.y = fmaf(h0v, bfhi(wv.x), a.y);
      a.z = fmaf(h0v, bflo(wv.y), a.z);
      a.w = fmaf(h0v, bfhi(wv.y), a.w);
      a.x = fmaf(h1v, bflo(wv.z), a.x);
      a.y = fmaf(h1v, bfhi(wv.z), a.y);
      a.z = fmaf(h1v, bflo(wv.w), a.z);
      a.w = fmaf(h1v, bfhi(wv.w), a.w);
    }
    if (kq) part[kq-1][j] = a;
    __syncthreads();
    if (kq == 0) {
      float4 p1 = part[0][j], p2 = part[1][j], p3 = part[2][j];
      float4 bb = (t == 0) ? xg4[j] : bias4[j];
      a.x += p1.x + p2.x + p3.x + bb.x;
      a.y += p1.y + p2.y + p3.y + bb.y;
      a.z += p1.z + p2.z + p3.z + bb.z;
      a.w += p1.w + p2.w + p3.w + bb.w;
      float ig = sig_f(a.x), fg = sig_f(a.y), gg = tanh_f(a.z), og = sig_f(a.w);
      cj = fmaf(fg, cj, ig*gg);
      float hj = og * tanh_f(cj);
      outsb[(b*20 + t)*256 + j] = bfbits(hj);
      hs[j] = hj;
    }
    __syncthreads();
  }
}

__global__ void k_zc(const float* __restrict__ zc, ushort* __restrict__ featb){
  int e = blockIdx.x*256 + threadIdx.x;
  int r = e >> 7, c = e & 127;
  featb[r*640 + 512 + c] = bfbits(zc[(r/20)*128 + c]);
}

// ---------------- MFMA ff GEMM: featb[1280][0:512] = lrelu(outsb[1280][256] @ wpff^T + b_f)
__global__ __launch_bounds__(256) void k_ff_m(
    const ushort* __restrict__ A, const ushort* __restrict__ W,
    const float* __restrict__ bias, ushort* __restrict__ C)
{
  constexpr int K = 256, BK = 64, NK = K/BK, BM = 128, BN = 64;
  constexpr int RS = 72;
  constexpr int NCF = BN/16;
  constexpr int AC = 4, WC = 2;

  __shared__ __align__(16) ushort Al[2][BM*RS];
  __shared__ __align__(16) ushort Wl[2][BN*RS];

  const int tid = threadIdx.x;
  const int col0 = blockIdx.x * BN, row0 = blockIdx.y * BM;
  const int w = tid >> 6, l = tid & 63, lm = l & 15, lk = l >> 4;

  f32x4 acc[NCF][2];
  #pragma unroll
  for (int m = 0; m < NCF; ++m)
    #pragma unroll
    for (int s = 0; s < 2; ++s)
      acc[m][s] = (f32x4){0.f,0.f,0.f,0.f};

  uint4 ar[AC], wr[WC];

  #define LOADG(kt) { \
    _Pragma("unroll") \
    for (int i = 0; i < AC; ++i) { \
      int chunk = tid + i*256; \
      int rl = chunk >> 3, kc = chunk & 7; \
      ar[i] = *(const uint4*)&A[(size_t)(row0+rl)*K + (kt)*BK + kc*8]; \
    } \
    _Pragma("unroll") \
    for (int i = 0; i < WC; ++i) { \
      int chunk = tid + i*256; \
      int co = chunk >> 3, kc = chunk & 7; \
      wr[i] = *(const uint4*)&W[(size_t)(col0+co)*K + (kt)*BK + kc*8]; \
    } }

  #define STOREL(buf) { \
    _Pragma("unroll") \
    for (int i = 0; i < AC; ++i) { \
      int chunk = tid + i*256; \
      int rl = chunk >> 3, kc = chunk & 7; \
      *(uint4*)&Al[buf][rl*RS + kc*8] = ar[i]; \
    } \
    _Pragma("unroll") \
    for (int i = 0; i < WC; ++i) { \
      int chunk = tid + i*256; \
      int co = chunk >> 3, kc = chunk & 7; \
      *(uint4*)&Wl[buf][co*RS + kc*8] = wr[i]; \
    } }

  LOADG(0);
  STOREL(0);
  int cur = 0;
  for (int kt = 0; kt < NK; ++kt) {
    if (kt + 1 < NK) LOADG(kt + 1);
    __syncthreads();
    #pragma unroll
    for (int kf = 0; kf < 2; ++kf) {
      bf16x8 bfr[2];
      #pragma unroll
      for (int s = 0; s < 2; ++s)
        bfr[s] = *(bf16x8*)&Al[cur][(w*32 + s*16 + lm)*RS + kf*32 + lk*8];
      #pragma unroll
      for (int m = 0; m < NCF; ++m) {
        bf16x8 afr = *(bf16x8*)&Wl[cur][(m*16 + lm)*RS + kf*32 + lk*8];
        acc[m][0] = __builtin_amdgcn_mfma_f32_16x16x32_bf16(afr, bfr[0], acc[m][0], 0, 0, 0);
        acc[m][1] = __builtin_amdgcn_mfma_f32_16x16x32_bf16(afr, bfr[1], acc[m][1], 0, 0, 0);
      }
    }
    if (kt + 1 < NK) STOREL(cur ^ 1);
    cur ^= 1;
  }

  #pragma unroll
  for (int m = 0; m < NCF; ++m) {
    #pragma unroll
    for (int s = 0; s < 2; ++s) {
      int row = row0 + w*32 + s*16 + lm;
      f32x4 v = acc[m][s];
      int u0 = col0 + m*16 + lk*4;
      union { ushort u[4]; uint2 q; } pk;
      #pragma unroll
      for (int j = 0; j < 4; ++j)
        pk.u[j] = bfbits(LRELU(v[j] + bias[u0+j]));
      *(uint2*)&C[(size_t)row*640 + u0] = pk.q;
    }
  }
  #undef LOADG
  #undef STOREL
}

// ---------------- MFMA FC GEMM: C[1280][4096] = lrelu(A@W^T + bias), NHWC bf16 out
__global__ __launch_bounds__(256) void k_gemm_fc_m(
    const ushort* __restrict__ A, const ushort* __restrict__ W,
    const float* __restrict__ bias, ushort* __restrict__ C)
{
  constexpr int K = 640, BK = 64, NK = K/BK, BM = 128, BN = 64;
  constexpr int RS = 72;
  constexpr int NCF = BN/16;
  constexpr int AC = 4, WC = 2;

  __shared__ __align__(16) ushort Al[2][BM*RS];
  __shared__ __align__(16) ushort Wl[2][BN*RS];

  const int tid = threadIdx.x;
  const int col0 = blockIdx.x * BN, row0 = blockIdx.y * BM;
  const int w = tid >> 6, l = tid & 63, lm = l & 15, lk = l >> 4;

  f32x4 acc[NCF][2];
  #pragma unroll
  for (int m = 0; m < NCF; ++m)
    #pragma unroll
    for (int s = 0; s < 2; ++s)
      acc[m][s] = (f32x4){0.f,0.f,0.f,0.f};

  uint4 ar[AC], wr[WC];

  #define LOADG(kt) { \
    _Pragma("unroll") \
    for (int i = 0; i < AC; ++i) { \
      int chunk = tid + i*256; \
      int rl = chunk >> 3, kc = chunk & 7; \
      ar[i] = *(const uint4*)&A[(size_t)(row0+rl)*K + (kt)*BK + kc*8]; \
    } \
    _Pragma("unroll") \
    for (int i = 0; i < WC; ++i) { \
      int chunk = tid + i*256; \
      int co = chunk >> 3, kc = chunk & 7; \
      wr[i] = *(const uint4*)&W[(size_t)(col0+co)*K + (kt)*BK + kc*8]; \
    } }

  #define STOREL(buf) { \
    _Pragma("unroll") \
    for (int i = 0; i < AC; ++i) { \
      int chunk = tid + i*256; \
      int rl = chunk >> 3, kc = chunk & 7; \
      *(uint4*)&Al[buf][rl*RS + kc*8] = ar[i]; \
    } \
    _Pragma("unroll") \
    for (int i = 0; i < WC; ++i) { \
      int chunk = tid + i*256; \
      int co = chunk >> 3, kc = chunk & 7; \
      *(uint4*)&Wl[buf][co*RS + kc*8] = wr[i]; \
    } }

  LOADG(0);
  STOREL(0);
  int cur = 0;
  for (int kt = 0; kt < NK; ++kt) {
    if (kt + 1 < NK) LOADG(kt + 1);
    __syncthreads();
    #pragma unroll
    for (int kf = 0; kf < 2; ++kf) {
      bf16x8 bfr[2];
      #pragma unroll
      for (int s = 0; s < 2; ++s)
        bfr[s] = *(bf16x8*)&Al[cur][(w*32 + s*16 + lm)*RS + kf*32 + lk*8];
      #pragma unroll
      for (int m = 0; m < NCF; ++m) {
        bf16x8 afr = *(bf16x8*)&Wl[cur][(m*16 + lm)*RS + kf*32 + lk*8];
        acc[m][0] = __builtin_amdgcn_mfma_f32_16x16x32_bf16(afr, bfr[0], acc[m][0], 0, 0, 0);
        acc[m][1] = __builtin_amdgcn_mfma_f32_16x16x32_bf16(afr, bfr[1], acc[m][1], 0, 0, 0);
      }
    }
    if (kt + 1 < NK) STOREL(cur ^ 1);
    cur ^= 1;
  }

  #pragma unroll
  for (int m = 0; m < NCF; ++m) {
    #pragma unroll
    for (int s = 0; s < 2; ++s) {
      int row = row0 + w*32 + s*16 + lm;
      f32x4 v = acc[m][s];
      #pragma unroll
      for (int j = 0; j < 4; ++j) {
        int u = col0 + m*16 + lk*4 + j;
        float val = LRELU(v[j] + bias[u]);
        C[((size_t)row << 12) + ((size_t)(u & 15) << 8) + (u >> 4)] = bfbits(val);
      }
    }
  }
  #undef LOADG
  #undef STOREL
}

// ---------------- deconv weight prep: w[ci][co][ky][kx] f32 -> wp[p][co][t*CI+ci] bf16
template<int CI, int CO>
__global__ void k_wprep(const float* __restrict__ w, ushort* __restrict__ wp){
  int e = blockIdx.x*256 + threadIdx.x;
  if (e >= 16*CI*CO) return;
  int ci = e % CI; int t1 = e / CI;
  int t = t1 & 3;  int t2 = t1 >> 2;
  int co = t2 % CO; int pp = t2 / CO;
  int py = pp >> 1, px = pp & 1, dy = t >> 1, dx = t & 1;
  int ky = (py ? 0 : 1) + 2*dy;
  int kx = (px ? 0 : 1) + 2*dx;
  wp[e] = bfbits(w[((ci*CO + co)*4 + ky)*4 + kx]);
}

__global__ void k_wfperm(const float* __restrict__ wf, float* __restrict__ wfT){
  int e = blockIdx.x*256 + threadIdx.x;
  if (e < 512) {
    int tap = e >> 5, ci = e & 31;
    wfT[tap*32 + ci] = wf[ci*16 + tap];
  }
}

// ---------------- MFMA parity-GEMM deconv (stage 0: deep K, spatial-tiled)
template<int CI, int CO, int HI>
__global__ __launch_bounds__(256) void k_dcv(
    const ushort* __restrict__ in, const ushort* __restrict__ wp,
    ushort* __restrict__ out, float* __restrict__ gsum, float* __restrict__ gsq)
{
  constexpr int WI = HI, HO = 2*HI, WO = 2*WI;
  constexpr int K = 4*CI, BK = 64, NK = K/BK;
  constexpr int BSP = 128;
  constexpr int RS = 72;
  constexpr int NCF = CO/16;
  constexpr int AC = BSP/32;
  constexpr int WC = CO/32;

  __shared__ __align__(16) ushort Al[2][BSP*RS];
  __shared__ __align__(16) ushort Wl[2][CO*RS];
  __shared__ float s_sum[CO], s_sq[CO];

  const int tid = threadIdx.x;
  const int sp0 = blockIdx.x * BSP;
  const int p  = blockIdx.y;
  const int py = p >> 1, px = p & 1;
  const int w  = tid >> 6, l = tid & 63;
  const int lm = l & 15, lk = l >> 4;

  if (tid < CO) { s_sum[tid] = 0.f; s_sq[tid] = 0.f; }

  f32x4 acc[NCF][2];
  #pragma unroll
  for (int m = 0; m < NCF; ++m)
    #pragma unroll
    for (int s = 0; s < 2; ++s)
      acc[m][s] = (f32x4){0.f,0.f,0.f,0.f};

  uint4 ar[AC], wr[WC];

  #define LOADT(kt) { \
    int t = ((kt)*BK)/CI, ci0 = ((kt)*BK)%CI; \
    int dy = t >> 1, dx = t & 1; \
    _Pragma("unroll") \
    for (int i = 0; i < AC; ++i) { \
      int chunk = tid + i*256; \
      int rl = chunk >> 3, kc = chunk & 7; \
      int r = sp0 + rl; \
      int n = r / (HI*WI), rem = r % (HI*WI); \
      int oy = rem / WI, ox = rem % WI; \
      int iy = oy + py - dy, ix = ox + px - dx; \
      if ((unsigned)iy < (unsigned)HI && (unsigned)ix < (unsigned)WI) \
        ar[i] = *(const uint4*)&in[((((size_t)n*HI + iy)*WI + ix)*CI) + ci0 + kc*8]; \
      else ar[i] = make_uint4(0,0,0,0); \
    } \
    _Pragma("unroll") \
    for (int i = 0; i < WC; ++i) { \
      int chunk = tid + i*256; \
      int co = chunk >> 3, kc = chunk & 7; \
      wr[i] = *(const uint4*)&wp[((size_t)p*CO + co)*K + (kt)*BK + kc*8]; \
    } }

  #define STORET(buf) { \
    _Pragma("unroll") \
    for (int i = 0; i < AC; ++i) { \
      int chunk = tid + i*256; \
      int rl = chunk >> 3, kc = chunk & 7; \
      *(uint4*)&Al[buf][rl*RS + kc*8] = ar[i]; \
    } \
    _Pragma("unroll") \
    for (int i = 0; i < WC; ++i) { \
      int chunk = tid + i*256; \
      int co = chunk >> 3, kc = chunk & 7; \
      *(uint4*)&Wl[buf][co*RS + kc*8] = wr[i]; \
    } }

  LOADT(0);
  STORET(0);
  int cur = 0;
  for (int kt = 0; kt < NK; ++kt) {
    if (kt + 1 < NK) LOADT(kt + 1);
    __syncthreads();
    #pragma unroll
    for (int kf = 0; kf < 2; ++kf) {
      bf16x8 bfr[2];
      #pragma unroll
      for (int s = 0; s < 2; ++s)
        bfr[s] = *(bf16x8*)&Al[cur][(w*32 + s*16 + lm)*RS + kf*32 + lk*8];
      #pragma unroll
      for (int m = 0; m < NCF; ++m) {
        bf16x8 afr = *(bf16x8*)&Wl[cur][(m*16 + lm)*RS + kf*32 + lk*8];
        acc[m][0] = __builtin_amdgcn_mfma_f32_16x16x32_bf16(afr, bfr[0], acc[m][0], 0, 0, 0);
        acc[m][1] = __builtin_amdgcn_mfma_f32_16x16x32_bf16(afr, bfr[1], acc[m][1], 0, 0, 0);
      }
    }
    if (kt + 1 < NK) STORET(cur ^ 1);
    cur ^= 1;
  }

  #pragma unroll
  for (int m = 0; m < NCF; ++m) {
    float s1[4] = {0,0,0,0}, s2[4] = {0,0,0,0};
    #pragma unroll
    for (int s = 0; s < 2; ++s) {
      f32x4 v = acc[m][s];
      int sp = sp0 + w*32 + s*16 + lm;
      int n = sp / (HI*WI), rem = sp % (HI*WI);
      int y = 2*(rem / WI) + py, x = 2*(rem % WI) + px;
      size_t ob = (((size_t)n*HO + y)*WO + x)*CO + m*16 + lk*4;
      union { ushort u[4]; uint2 q; } pk;
      #pragma unroll
      for (int j = 0; j < 4; ++j) {
        pk.u[j] = bfbits(v[j]);
        s1[j] += v[j];
        s2[j] += v[j]*v[j];
      }
      *(uint2*)&out[ob] = pk.q;
    }
    #pragma unroll
    for (int j = 0; j < 4; ++j) {
      float a = s1[j], b = s2[j];
      #pragma unroll
      for (int o = 1; o < 16; o <<= 1) { a += __shfl_xor(a, o); b += __shfl_xor(b, o); }
      if (lm == 0) {
        atomicAdd(&s_sum[m*16 + lk*4 + j], a);
        atomicAdd(&s_sq [m*16 + lk*4 + j], b);
      }
    }
  }
  __syncthreads();
  for (int cc = tid; cc < CO; cc += 256) {
    atomicAdd(&gsum[cc], s_sum[cc]);
    atomicAdd(&gsq[cc],  s_sq[cc]);
  }
  #undef LOADT
  #undef STORET
}

// ---------------- image-resident MFMA deconv (stages 1 & 2); BN finalize of the
// PREVIOUS stage computed in-prologue from gsum/gsq.
template<int CI, int CO, int HI>
__global__ __launch_bounds__(512) void k_dcvim(
    const ushort* __restrict__ in, const ushort* __restrict__ wp,
    const float* __restrict__ gsumP, const float* __restrict__ gsqP,
    const float* __restrict__ gP, const float* __restrict__ beP, float invNP,
    ushort* __restrict__ out, float* __restrict__ gsum, float* __restrict__ gsq)
{
  constexpr int WI = HI, HO = 2*HI, WO = 2*WI;
  constexpr int K = 4*CI;
  constexpr int KF = K/32;
  constexpr int PAD = HI + 2;
  constexpr int CICH = CI/8;
  constexpr int AU4 = PAD*PAD*CICH;
  constexpr int SFT = HI*WI/16;
  constexpr int MMW = CO/32;

  __shared__ __align__(16) ushort Ain[PAD*PAD*CI];
  __shared__ float s_sum[CO], s_sq[CO];
  __shared__ float s_scale[CI], s_shift[CI];

  const int tid = threadIdx.x;
  const int n = blockIdx.x;
  const int w = tid >> 6, l = tid & 63, lm = l & 15, lk = l >> 4;
  const int p = w >> 1, py = p >> 1, px = p & 1, mh = w & 1;

  if (tid < CO) { s_sum[tid] = 0.f; s_sq[tid] = 0.f; }
  if (tid >= 512-CI) {
    int c = tid - (512-CI);
    float m = gsumP[c]*invNP;
    float v = gsqP[c]*invNP - m*m;
    float sc = gP[c]*rsqrtf(v + 1e-5f);
    s_scale[c] = sc;
    s_shift[c] = beP[c] - m*sc;
  }

  uint4 zz = make_uint4(0,0,0,0);
  for (int i = tid; i < AU4; i += 512) ((uint4*)Ain)[i] = zz;
  __syncthreads();

  const ushort* inb = in + (size_t)n * HI * WI * CI;
  constexpr int NCHK = HI*WI*CICH;
  for (int e = tid; e < NCHK; e += 512) {
    int ci8 = e % CICH; int sp = e / CICH;
    int ix = sp % WI, iy = sp / WI;
    uint4 u = *(const uint4*)&inb[(size_t)sp*CI + ci8*8];
    int ci0 = ci8*8;
    float4 sc0 = *(const float4*)&s_scale[ci0];
    float4 sc1 = *(const float4*)&s_scale[ci0+4];
    float4 sh0 = *(const float4*)&s_shift[ci0];
    float4 sh1 = *(const float4*)&s_shift[ci0+4];
    float v0 = LRELU(fmaf(bflo(u.x), sc0.x, sh0.x));
    float v1 = LRELU(fmaf(bfhi(u.x), sc0.y, sh0.y));
    float v2 = LRELU(fmaf(bflo(u.y), sc0.z, sh0.z));
    float v3 = LRELU(fmaf(bfhi(u.y), sc0.w, sh0.w));
    float v4 = LRELU(fmaf(bflo(u.z), sc1.x, sh1.x));
    float v5 = LRELU(fmaf(bfhi(u.z), sc1.y, sh1.y));
    float v6 = LRELU(fmaf(bflo(u.w), sc1.z, sh1.z));
    float v7 = LRELU(fmaf(bfhi(u.w), sc1.w, sh1.w));
    uint4 o;
    o.x = (uint)bfbits(v0) | ((uint)bfbits(v1) << 16);
    o.y = (uint)bfbits(v2) | ((uint)bfbits(v3) << 16);
    o.z = (uint)bfbits(v4) | ((uint)bfbits(v5) << 16);
    o.w = (uint)bfbits(v6) | ((uint)bfbits(v7) << 16);
    int r = iy + 1, c = ix + 1;
    int chS = ci8 ^ (c & 7);
    ((uint4*)Ain)[(r*PAD + c)*CICH + chS] = o;
  }
  __syncthreads();

  f32x4 acc[MMW][SFT];
  #pragma unroll
  for (int m = 0; m < MMW; ++m)
    #pragma unroll
    for (int sf = 0; sf < SFT; ++sf)
      acc[m][sf] = (f32x4){0.f,0.f,0.f,0.f};

  const ushort* wpb = wp + ((size_t)p*CO + mh*(CO/2))*K;
  #pragma unroll
  for (int kf = 0; kf < KF; ++kf) {
    const int t = (kf*32)/CI, cib = (kf*32)%CI;
    const int dy = t >> 1, dx = t & 1;
    bf16x8 afr[MMW];
    #pragma unroll
    for (int m = 0; m < MMW; ++m)
      afr[m] = *(const bf16x8*)&wpb[(size_t)(m*16 + lm)*K + kf*32 + lk*8];
    const int ch = (cib >> 3) + lk;
    #pragma unroll
    for (int sf = 0; sf < SFT; ++sf) {
      int s = sf*16 + lm;
      int y = s / WI, x = s % WI;
      int r = y + py - dy + 1, c = x + px - dx + 1;
      bf16x8 bfr = *(const bf16x8*)&Ain[((r*PAD + c)*CICH + (ch ^ (c & 7)))*8];
      #pragma unroll
      for (int m = 0; m < MMW; ++m)
        acc[m][sf] = __builtin_amdgcn_mfma_f32_16x16x32_bf16(afr[m], bfr, acc[m][sf], 0, 0, 0);
    }
  }

  #pragma unroll
  for (int m = 0; m < MMW; ++m) {
    int co0 = mh*(CO/2) + m*16 + lk*4;
    float s1[4] = {0,0,0,0}, s2[4] = {0,0,0,0};
    #pragma unroll
    for (int sf = 0; sf < SFT; ++sf) {
      f32x4 v = acc[m][sf];
      int s = sf*16 + lm;
      int y = 2*(s / WI) + py, x = 2*(s % WI) + px;
      size_t ob = (((size_t)n*HO + y)*WO + x)*CO + co0;
      union { ushort u[4]; uint2 q; } pk;
      #pragma unroll
      for (int j = 0; j < 4; ++j) {
        pk.u[j] = bfbits(v[j]);
        s1[j] += v[j];
        s2[j] += v[j]*v[j];
      }
      *(uint2*)&out[ob] = pk.q;
    }
    #pragma unroll
    for (int j = 0; j < 4; ++j) {
      float a = s1[j], b = s2[j];
      #pragma unroll
      for (int o = 1; o < 16; o <<= 1) { a += __shfl_xor(a, o); b += __shfl_xor(b, o); }
      if (lm == 0) {
        atomicAdd(&s_sum[co0 + j], a);
        atomicAdd(&s_sq [co0 + j], b);
      }
    }
  }
  __syncthreads();
  for (int cc = tid; cc < CO; cc += 512) {
    atomicAdd(&gsum[cc], s_sum[cc]);
    atomicAdd(&gsq[cc],  s_sq[cc]);
  }
}

// ---------------- final deconv 32->1 + sigmoid; BN finalize inline
__global__ __launch_bounds__(256) void k_final(
    const ushort* __restrict__ in, const float* __restrict__ wfo,
    const float* __restrict__ gsumP, const float* __restrict__ gsqP,
    const float* __restrict__ gP, const float* __restrict__ beP, float invNP,
    const float* __restrict__ bfb, float* __restrict__ outp)
{
  constexpr int CI=32, HI=32, WI=32, HO=64, WO=64, SPLIT=8, HOq=HO/SPLIT;
  constexpr int ROWW = 32*36 + 8;
  __shared__ __align__(8) ushort As[6 * ROWW];
  __shared__ float s_scale[CI], s_shift[CI];

  const int tid = threadIdx.x, bid = blockIdx.x;
  const int n = bid / SPLIT, q = bid % SPLIT;
  const int y0 = q * HOq;
  const int rows_lo = max(0, y0/2 - 1);
  const int rows_hi = min(HI-1, (y0 + HOq)/2);
  const int nrows = rows_hi - rows_lo + 1;

  if (tid < CI) {
    float m = gsumP[tid]*invNP;
    float v = gsqP[tid]*invNP - m*m;
    float sc = gP[tid]*rsqrtf(v + 1e-5f);
    s_scale[tid] = sc;
    s_shift[tid] = beP[tid] - m*sc;
  }
  __syncthreads();

  const ushort* inb = in + (size_t)n * HI * WI * CI;
  const int NC = nrows * WI * (CI/4);
  for (int e = tid; e < NC; e += 256) {
    int c2 = e & 7;
    int sp = e >> 3;
    int rl = sp >> 5, ix = sp & 31;
    uint2 u = *(const uint2*)&inb[(((rows_lo + rl)*WI + ix)*CI) + c2*4];
    float4 sc = *(const float4*)&s_scale[c2*4];
    float4 sh = *(const float4*)&s_shift[c2*4];
    float v0 = LRELU(fmaf(bflo(u.x), sc.x, sh.x));
    float v1 = LRELU(fmaf(bfhi(u.x), sc.y, sh.y));
    float v2 = LRELU(fmaf(bflo(u.y), sc.z, sh.z));
    float v3 = LRELU(fmaf(bfhi(u.y), sc.w, sh.w));
    uint2 o;
    o.x = (uint)bfbits(v0) | ((uint)bfbits(v1) << 16);
    o.y = (uint)bfbits(v2) | ((uint)bfbits(v3) << 16);
    *(uint2*)&As[rl*ROWW + ix*36 + c2*4] = o;
  }
  __syncthreads();

  const int w = tid >> 6, l = tid & 63;
  const int py = w >> 1, px = w & 1;
  const int ky0 = 1 - py, kx0 = 1 - px;
  const float b0 = bfb[0];
  const int xi = l & 31;
  const int x = 2*xi + px;

  for (int rowi = (l >> 5); rowi < 4; rowi += 2) {
    int y = y0 + 2*rowi + py;
    float acc = b0;
    #pragma unroll
    for (int t = 0; t < 4; ++t) {
      int ky = ky0 + 2*(t >> 1), kx = kx0 + 2*(t & 1);
      int iy = (y + 1 - ky) >> 1, ix = (x + 1 - kx) >> 1;
      if (iy < 0 || iy >= HI || ix < 0 || ix >= WI) continue;
      const float* __restrict__ wv = &wfo[(ky*4 + kx)*CI];
      const ushort* __restrict__ arow = &As[(iy - rows_lo)*ROWW + ix*36];
      #pragma unroll
      for (int c2 = 0; c2 < 8; ++c2) {
        uint2 v = *(const uint2*)&arow[c2*4];
        acc = fmaf(bflo(v.x), wv[c2*4+0], acc);
        acc = fmaf(bfhi(v.x), wv[c2*4+1], acc);
        acc = fmaf(bflo(v.y), wv[c2*4+2], acc);
        acc = fmaf(bfhi(v.y), wv[c2*4+3], acc);
      }
    }
    outp[(size_t)n*HO*WO + y*WO + x] = 1.f/(1.f + __expf(-acc));
  }
}

extern "C" void kernel_launch(void* const* d_in, const int* in_sizes, int n_in,
                              void* d_out, int out_size, void* d_ws, size_t ws_size,
                              hipStream_t stream) {
  const float* z_content = (const float*)d_in[0];
  const float* z_motion  = (const float*)d_in[1];
  const float* W_h  = (const float*)d_in[2];
  const float* b_h  = (const float*)d_in[3];
  const float* W_c  = (const float*)d_in[4];
  const float* b_c  = (const float*)d_in[5];
  const float* W_ih = (const float*)d_in[6];
  const float* W_hh = (const float*)d_in[7];
  const float* b_ih = (const float*)d_in[8];
  const float* b_hh = (const float*)d_in[9];
  const float* W_f  = (const float*)d_in[10];
  const float* b_f  = (const float*)d_in[11];
  const float* init_in = (const float*)d_in[12];
  const float* fc_W = (const float*)d_in[13];
  const float* fc_b = (const float*)d_in[14];
  const float* w0 = (const float*)d_in[15];
  const float* g0 = (const float*)d_in[16];
  const float* be0 = (const float*)d_in[17];
  const float* w1 = (const float*)d_in[18];
  const float* g1 = (const float*)d_in[19];
  const float* be1 = (const float*)d_in[20];
  const float* w2 = (const float*)d_in[21];
  const float* g2 = (const float*)d_in[22];
  const float* be2 = (const float*)d_in[23];
  const float* wf = (const float*)d_in[24];
  const float* bf_ = (const float*)d_in[25];

  const size_t P_BYTES = 10631168;
  const size_t X_OFF   = P_BYTES;
  const size_t X_BYTES = 83886080;
  const size_t Y_OFF   = X_OFF + X_BYTES;
  const size_t NEED    = Y_OFF + 41943040;
  if (ws_size < NEED) return;

  float* ws = (float*)d_ws;
  char*  wsb = (char*)d_ws;
  float* sum0 = ws + 0;        float* sq0 = ws + 128;
  float* sum1 = ws + 256;      float* sq1 = ws + 320;
  float* sum2 = ws + 384;      float* sq2 = ws + 416;
  float4* xg4   = (float4*)(ws + 1024);
  float4* bias4 = (float4*)(ws + 2048);
  float* h    = ws + 3072;                  // 16384
  float* c    = ws + 19456;                 // 16384
  ushort* outsb = (ushort*)(ws + 35840);    // 327680 bf16
  float* WhT  = ws + 199680;                // 65536
  float* WcT  = ws + 265216;                // 65536
  uint4* W4hhq = (uint4*)(ws + 330752);     // 32768 uint4 = 131072 f32 slots
  uint4* W4sq  = (uint4*)(ws + 592896);     // 32768 uint4
  ushort* wp0 = (ushort*)(ws + 855040);     // 524288 bf16
  ushort* wp1 = (ushort*)(ws + 1117184);    // 131072 bf16
  ushort* wp2 = (ushort*)(ws + 1182720);    // 32768 bf16
  float* wfT  = ws + 1199104;               // 512 f32
  ushort* wpff = (ushort*)(ws + 1199616);   // 131072 bf16
  ushort* featb = (ushort*)(ws + 1265152);  // 819200 bf16

  ushort* wpfc = (ushort*)(wsb + X_OFF);   // 2,621,440 bf16 (dead after gemm)
  ushort* out0 = (ushort*)(wsb + X_OFF);   // NHWC bf16 [1280][8][8][128]
  ushort* out2 = (ushort*)(wsb + X_OFF);   // NHWC bf16 [1280][32][32][32]
  ushort* h1   = (ushort*)(wsb + Y_OFF);   // NHWC bf16 [1280][4][4][256]
  ushort* out1 = (ushort*)(wsb + Y_OFF);   // NHWC bf16 [1280][16][16][64]

  dim3 tb(32,8);
  k_transpose<<<dim3(8,8),   tb, 0, stream>>>(W_h,  WhT, 256, 256);
  k_transpose<<<dim3(8,8),   tb, 0, stream>>>(W_c,  WcT, 256, 256);
  k_tobf16<<<10240, 256, 0, stream>>>(fc_W, wpfc, 2621440);
  k_tobf16<<<512, 256, 0, stream>>>(W_f, wpff, 131072);
  k_w4prep<<<128, 256, 0, stream>>>(W_ih, W_hh, W4hhq, W4sq, ws);
  k_xgbias<<<256, 256, 0, stream>>>(W_ih, b_ih, b_hh, init_in, xg4, bias4);
  k_h0c0<<<64, 256, 0, stream>>>(z_content, z_motion, WhT, WcT, b_h, b_c, h, c);
  k_wprep<256,128><<<2048, 256, 0, stream>>>(w0, wp0);
  k_wprep<128,64><<<512, 256, 0, stream>>>(w1, wp1);
  k_wprep<64,32><<<128, 256, 0, stream>>>(w2, wp2);
  k_wfperm<<<2, 256, 0, stream>>>(wf, wfT);

  // ---- whole LSTM in one launch (1024 threads, 4-way K split, uint4 bf16 weights)
  k_lstm_all<<<64, 1024, 0, stream>>>(W4hhq, W4sq, xg4, bias4, h, c, outsb);

  // ---- ff (MFMA) + concat + fc (MFMA)
  k_ff_m<<<dim3(8, 10), 256, 0, stream>>>(outsb, wpff, b_f, featb);
  k_zc<<<640, 256, 0, stream>>>(z_content, featb);
  k_gemm_fc_m<<<dim3(64, 10), 256, 0, stream>>>(featb, wpfc, fc_b, h1);

  // ---- deconv pipeline (BN finalize folded into consumers)
  k_dcv<256,128,4><<<dim3(160,4), 256, 0, stream>>>(h1, wp0, out0, sum0, sq0);
  k_dcvim<128,64,8><<<1280, 512, 0, stream>>>(out0, wp1, sum0, sq0, g0, be0, 1.f/81920.f, out1, sum1, sq1);
  k_dcvim<64,32,16><<<1280, 512, 0, stream>>>(out1, wp2, sum1, sq1, g1, be1, 1.f/327680.f, out2, sum2, sq2);
  k_final<<<10240, 256, 0, stream>>>(out2, wfT, sum2, sq2, g2, be2, 1.f/1310720.f, bf_, (float*)d_out);
}